// Round 4
// baseline (4860.087 us; speedup 1.0000x reference)
//
// Round 3 resubmit: identical to round-1 source. Rounds 2-3 were infra
// failures (container failed twice; GPU acquisition timeout) — no kernel
// signal, so the experiment is not mutated.
#include <hip/hip_runtime.h>
#include <hip/hip_bf16.h>

#define T_LEN 2048
#define NHEAD 8
#define DHEAD 128
#define NBLK 128     // W
#define BS 16
#define NSEL 16
#define WIN 128
#define NMEM 1
#define SCALE 0.12f
#define NEG -1e9f

// ---------------- generic tiled GEMM: C[m,n] = sum_k A[m,k]*B[n,k] ----------------
// M,N multiples of 64; K multiple of 16. EPI: 0 = plain, 1 = relu^2
template <int EPI>
__global__ __launch_bounds__(256) void gemm_tn(const float* __restrict__ A,
                                               const float* __restrict__ B,
                                               float* __restrict__ C,
                                               int M, int N, int K) {
    __shared__ float As[16][68];
    __shared__ float Bs[16][68];
    const int bm = blockIdx.y * 64, bn = blockIdx.x * 64;
    const int tid = threadIdx.x;
    const int tx = tid & 15, ty = tid >> 4;
    const int lr = tid >> 2;          // 0..63 (row within tile)
    const int lc = (tid & 3) << 2;    // 0,4,8,12 (k-offset)
    float acc[4][4] = {};
    const float* pa = A + (size_t)(bm + lr) * K + lc;
    const float* pb = B + (size_t)(bn + lr) * K + lc;
    for (int kt = 0; kt < K; kt += 16) {
        const float4 a4 = *reinterpret_cast<const float4*>(pa + kt);
        const float4 b4 = *reinterpret_cast<const float4*>(pb + kt);
        As[lc + 0][lr] = a4.x; As[lc + 1][lr] = a4.y;
        As[lc + 2][lr] = a4.z; As[lc + 3][lr] = a4.w;
        Bs[lc + 0][lr] = b4.x; Bs[lc + 1][lr] = b4.y;
        Bs[lc + 2][lr] = b4.z; Bs[lc + 3][lr] = b4.w;
        __syncthreads();
#pragma unroll
        for (int kk = 0; kk < 16; ++kk) {
            const float4 av = *reinterpret_cast<const float4*>(&As[kk][ty * 4]);
            const float4 bv = *reinterpret_cast<const float4*>(&Bs[kk][tx * 4]);
            acc[0][0] += av.x * bv.x; acc[0][1] += av.x * bv.y; acc[0][2] += av.x * bv.z; acc[0][3] += av.x * bv.w;
            acc[1][0] += av.y * bv.x; acc[1][1] += av.y * bv.y; acc[1][2] += av.y * bv.z; acc[1][3] += av.y * bv.w;
            acc[2][0] += av.z * bv.x; acc[2][1] += av.z * bv.y; acc[2][2] += av.z * bv.z; acc[2][3] += av.z * bv.w;
            acc[3][0] += av.w * bv.x; acc[3][1] += av.w * bv.y; acc[3][2] += av.w * bv.z; acc[3][3] += av.w * bv.w;
        }
        __syncthreads();
    }
#pragma unroll
    for (int i = 0; i < 4; ++i) {
        float4 o;
        float* op = &o.x;
#pragma unroll
        for (int j = 0; j < 4; ++j) {
            float v = acc[i][j];
            if (EPI == 1) { v = v > 0.f ? v : 0.f; v = v * v; }
            op[j] = v;
        }
        *reinterpret_cast<float4*>(&C[(size_t)(bm + ty * 4 + i) * N + bn + tx * 4]) = o;
    }
}

// ---------------- per-(h,t): rms-norm q,k; rotary; scale v ----------------
__global__ __launch_bounds__(128) void prep_qkv(const float* __restrict__ qkvbuf,
                                                const float* __restrict__ lambdas,
                                                float* __restrict__ q, float* __restrict__ k,
                                                float* __restrict__ v) {
    const int t = blockIdx.x, h = blockIdx.y, d = threadIdx.x;
    __shared__ float sq[128], sk[128], red[128];
    const float* row = qkvbuf + (size_t)t * 3072 + h * 128;
    float qv = row[d], kv = row[1024 + d], vv = row[2048 + d];

    red[d] = qv * qv; __syncthreads();
    for (int s = 64; s; s >>= 1) { if (d < s) red[d] += red[d + s]; __syncthreads(); }
    float qr = rsqrtf(red[0] / 128.f + 1e-6f); __syncthreads();
    red[d] = kv * kv; __syncthreads();
    for (int s = 64; s; s >>= 1) { if (d < s) red[d] += red[d + s]; __syncthreads(); }
    float kr = rsqrtf(red[0] / 128.f + 1e-6f); __syncthreads();

    sq[d] = qv * qr; sk[d] = kv * kr; __syncthreads();

    const int j = d & 63;
    const float ang = (j < 32) ? powf(1.0f / 1024.0f, (float)j / 31.0f) : 0.0f;
    const float th = ang * (float)t;
    const float c = cosf(th), s = sinf(th);
    float qo, ko;
    if (d < 64) { qo = sq[d] * c + sq[d + 64] * s; ko = sk[d] * c + sk[d + 64] * s; }
    else        { qo = -sq[d - 64] * s + sq[d] * c; ko = -sk[d - 64] * s + sk[d] * c; }

    const size_t idx = ((size_t)h * T_LEN + t) * 128 + d;
    q[idx] = qo;
    k[idx] = ko;
    v[idx] = lambdas[0] * vv;
}

// ---------------- build compress-MLP inputs: (k + kpos), (v + vpos) ----------------
__global__ void build_cin(const float* __restrict__ k, const float* __restrict__ v,
                          const float* __restrict__ kpos, const float* __restrict__ vpos,
                          float* __restrict__ kc, float* __restrict__ vc) {
    int idx = blockIdx.x * 256 + threadIdx.x;
    if (idx >= NHEAD * NBLK * BS * DHEAD) return;
    const int d = idx & 127, i = (idx >> 7) & 15, w = (idx >> 11) & 127, h = idx >> 18;
    const int t = w * 16 + i;
    const size_t src = ((size_t)h * T_LEN + t) * 128 + d;
    const int pos = (h * 16 + i) * 128 + d;
    kc[idx] = k[src] + kpos[pos];
    vc[idx] = v[src] + vpos[pos];
}

// ---------------- assemble ck/cv with mem slot ----------------
__global__ void scatter_ckcv(const float* __restrict__ ckb, const float* __restrict__ cvb,
                             const float* __restrict__ memkv,
                             float* __restrict__ ck, float* __restrict__ cv) {
    int idx = blockIdx.x * 256 + threadIdx.x;
    if (idx >= NHEAD * (NBLK + NMEM) * DHEAD) return;
    const int d = idx & 127;
    const int j = (idx >> 7) % (NBLK + NMEM);
    const int h = idx / ((NBLK + NMEM) * DHEAD);
    if (j == 0) {
        ck[idx] = memkv[h * 128 + d];
        cv[idx] = memkv[NHEAD * 128 + h * 128 + d];
    } else {
        const size_t b = ((size_t)h * NBLK + (j - 1)) * 128 + d;
        ck[idx] = ckb[b];
        cv[idx] = cvb[b];
    }
}

// ---------------- compressed similarities (masked, scaled) ----------------
__global__ __launch_bounds__(256) void csim_kern(const float* __restrict__ q,
                                                 const float* __restrict__ ck,
                                                 float* __restrict__ csim) {
    const int t = blockIdx.x, h = blockIdx.y, tid = threadIdx.x;
    __shared__ float qs[128];
    if (tid < 128) qs[tid] = q[((size_t)h * T_LEN + t) * 128 + tid];
    __syncthreads();
    if (tid < NBLK + NMEM) {
        const float* ckr = ck + ((size_t)h * (NBLK + NMEM) + tid) * 128;
        float s = 0.f;
        for (int d = 0; d < 128; ++d) s += qs[d] * ckr[d];
        const int seq = (tid == 0) ? -1 : tid * 16 - 1;
        csim[((size_t)h * T_LEN + t) * (NBLK + NMEM) + tid] = (seq < t) ? s * SCALE : NEG;
    }
}

// ---------------- compressed attention softmax + PV ----------------
__global__ __launch_bounds__(256) void comp_att(const float* __restrict__ csim,
                                                const float* __restrict__ cv,
                                                float* __restrict__ out) {
    const int t = blockIdx.x, h = blockIdx.y, tid = threadIdx.x;
    const int NJ = NBLK + NMEM;
    __shared__ float p[NBLK + NMEM];
    __shared__ float red[256];
    float v = (tid < NJ) ? csim[((size_t)h * T_LEN + t) * NJ + tid] : -INFINITY;
    red[tid] = v; __syncthreads();
    for (int s = 128; s; s >>= 1) { if (tid < s) red[tid] = fmaxf(red[tid], red[tid + s]); __syncthreads(); }
    const float mx = red[0]; __syncthreads();
    float e = (tid < NJ) ? expf(v - mx) : 0.f;
    if (tid < NJ) p[tid] = e;
    red[tid] = e; __syncthreads();
    for (int s = 128; s; s >>= 1) { if (tid < s) red[tid] += red[tid + s]; __syncthreads(); }
    const float sum = red[0];
    if (tid < 128) {
        const float* cvh = cv + (size_t)h * NJ * 128;
        float o = 0.f;
        for (int j = 0; j < NJ; ++j) o += p[j] * cvh[j * 128 + tid];
        out[((size_t)h * T_LEN + t) * 128 + tid] = o / sum;
    }
}

// ---------------- importance: mean over heads of csim[...,1:] ----------------
__global__ void imp_kern(const float* __restrict__ csim, float* __restrict__ imp) {
    int idx = blockIdx.x * 256 + threadIdx.x;
    if (idx >= T_LEN * NBLK) return;
    const int w = idx & 127, t = idx >> 7;
    float s = 0.f;
    for (int h = 0; h < NHEAD; ++h)
        s += csim[((size_t)h * T_LEN + t) * (NBLK + NMEM) + 1 + w];
    imp[idx] = s * 0.125f;
}

// ---------------- top-16 block selection per t ----------------
__global__ void topk_kern(const float* __restrict__ imp, unsigned long long* __restrict__ selbits) {
    const int t = blockIdx.x * blockDim.x + threadIdx.x;
    if (t >= T_LEN) return;
    const float* row = imp + (size_t)t * NBLK;
    unsigned long long b0 = 0, b1 = 0;
    for (int s = 0; s < NSEL; ++s) {
        float best = -INFINITY; int bi = 0;
        for (int w = 0; w < NBLK; ++w) {
            const bool used = (w < 64) ? ((b0 >> w) & 1ull) : ((b1 >> (w - 64)) & 1ull);
            const float vv = row[w];
            if (!used && vv > best) { best = vv; bi = w; }
        }
        if (bi < 64) b0 |= 1ull << bi; else b1 |= 1ull << (bi - 64);
    }
    selbits[2 * t] = b0; selbits[2 * t + 1] = b1;
}

// ---------------- fine block-sparse attention ----------------
__global__ __launch_bounds__(256) void fine_att(const float* __restrict__ q,
                                                const float* __restrict__ k,
                                                const float* __restrict__ v,
                                                const unsigned long long* __restrict__ selbits,
                                                float* __restrict__ out) {
    const int t = blockIdx.x, h = blockIdx.y, tid = threadIdx.x;
    __shared__ float qs[128];
    __shared__ unsigned short keys[(NSEL + 1) * BS];
    __shared__ float sc[(NSEL + 1) * BS];
    __shared__ float red[256];
    __shared__ int nk_s;
    if (tid < 128) qs[tid] = q[((size_t)h * T_LEN + t) * 128 + tid];
    if (tid == 0) {
        const unsigned long long b0 = selbits[2 * t], b1 = selbits[2 * t + 1];
        const int cur = t >> 4;
        int nk = 0;
        for (int w = 0; w < NBLK; ++w) {
            bool s = (w < 64) ? ((b0 >> w) & 1ull) : ((b1 >> (w - 64)) & 1ull);
            if (w == cur) s = true;
            if (!s) continue;
            const int j0 = w << 4;
            const int j1 = min(j0 + 15, t);
            for (int j = j0; j <= j1; ++j) keys[nk++] = (unsigned short)j;
        }
        nk_s = nk;
    }
    __syncthreads();
    const int nk = nk_s;
    for (int i = tid; i < nk; i += 256) {
        const float* kr = k + ((size_t)h * T_LEN + keys[i]) * 128;
        float s = 0.f;
        for (int d = 0; d < 128; ++d) s += qs[d] * kr[d];
        sc[i] = s * SCALE;
    }
    __syncthreads();
    float lm = -INFINITY;
    for (int i = tid; i < nk; i += 256) lm = fmaxf(lm, sc[i]);
    red[tid] = lm; __syncthreads();
    for (int s = 128; s; s >>= 1) { if (tid < s) red[tid] = fmaxf(red[tid], red[tid + s]); __syncthreads(); }
    const float mx = red[0]; __syncthreads();
    float ls = 0.f;
    for (int i = tid; i < nk; i += 256) { const float e = expf(sc[i] - mx); sc[i] = e; ls += e; }
    red[tid] = ls; __syncthreads();
    for (int s = 128; s; s >>= 1) { if (tid < s) red[tid] += red[tid + s]; __syncthreads(); }
    const float sum = red[0];
    if (tid < 128) {
        float o = 0.f;
        for (int i = 0; i < nk; ++i) o += sc[i] * v[((size_t)h * T_LEN + keys[i]) * 128 + tid];
        out[((size_t)h * T_LEN + t) * 128 + tid] = o / sum;
    }
}

// ---------------- sliding-window attention ----------------
__global__ __launch_bounds__(256) void slide_att(const float* __restrict__ q,
                                                 const float* __restrict__ k,
                                                 const float* __restrict__ v,
                                                 float* __restrict__ out) {
    const int t = blockIdx.x, h = blockIdx.y, tid = threadIdx.x;
    __shared__ float qs[128];
    __shared__ float sc[WIN];
    __shared__ float red[256];
    if (tid < 128) qs[tid] = q[((size_t)h * T_LEN + t) * 128 + tid];
    __syncthreads();
    const int j0 = max(0, t - (WIN - 1));
    const int nk = t - j0 + 1;
    for (int i = tid; i < nk; i += 256) {
        const float* kr = k + ((size_t)h * T_LEN + j0 + i) * 128;
        float s = 0.f;
        for (int d = 0; d < 128; ++d) s += qs[d] * kr[d];
        sc[i] = s * SCALE;
    }
    __syncthreads();
    float lm = -INFINITY;
    for (int i = tid; i < nk; i += 256) lm = fmaxf(lm, sc[i]);
    red[tid] = lm; __syncthreads();
    for (int s = 128; s; s >>= 1) { if (tid < s) red[tid] = fmaxf(red[tid], red[tid + s]); __syncthreads(); }
    const float mx = red[0]; __syncthreads();
    float ls = 0.f;
    for (int i = tid; i < nk; i += 256) { const float e = expf(sc[i] - mx); sc[i] = e; ls += e; }
    red[tid] = ls; __syncthreads();
    for (int s = 128; s; s >>= 1) { if (tid < s) red[tid] += red[tid + s]; __syncthreads(); }
    const float sum = red[0];
    if (tid < 128) {
        float o = 0.f;
        for (int i = 0; i < nk; ++i) o += sc[i] * v[((size_t)h * T_LEN + j0 + i) * 128 + tid];
        out[((size_t)h * T_LEN + t) * 128 + tid] = o / sum;
    }
}

// ---------------- per-(t,i) strategy gate: sigmoid(x . w_i + b_i) ----------------
__global__ __launch_bounds__(64) void strat_kern(const float* __restrict__ x,
                                                 const float* __restrict__ w,
                                                 const float* __restrict__ b,
                                                 float* __restrict__ strat) {
    const int i = blockIdx.x;   // 0..23
    const int t = blockIdx.y;
    const int lane = threadIdx.x;
    const float* xr = x + (size_t)t * 1024;
    const float* wr = w + (size_t)i * 1024;
    float s = 0.f;
    for (int c = lane; c < 1024; c += 64)
        s += xr[c] * wr[c];
    for (int off = 32; off; off >>= 1) s += __shfl_down(s, off);
    if (lane == 0) {
        const float z = s + b[i];
        strat[t * 24 + i] = 1.f / (1.f + expf(-z));
    }
}

// ---------------- combine three attention branches ----------------
__global__ __launch_bounds__(256) void combine_kern(const float* __restrict__ strat,
                                                    const float* __restrict__ comp,
                                                    const float* __restrict__ fine,
                                                    const float* __restrict__ slide,
                                                    float* __restrict__ mix) {
    const int t = blockIdx.x;
    for (int hd = threadIdx.x; hd < 1024; hd += 256) {
        const int h = hd >> 7, d = hd & 127;
        const float* st = strat + t * 24 + h * 3;
        const size_t idx = ((size_t)h * T_LEN + t) * 128 + d;
        mix[(size_t)t * 1024 + hd] = st[0] * comp[idx] + st[1] * fine[idx] + st[2] * slide[idx];
    }
}

extern "C" void kernel_launch(void* const* d_in, const int* in_sizes, int n_in,
                              void* d_out, int out_size, void* d_ws, size_t ws_size,
                              hipStream_t stream) {
    const float* x        = (const float*)d_in[0];
    const float* qkv_w    = (const float*)d_in[1];
    const float* lambdas  = (const float*)d_in[2];
    const float* c_proj_w = (const float*)d_in[3];
    const float* k_fc_w   = (const float*)d_in[4];
    const float* k_pj_w   = (const float*)d_in[5];
    const float* v_fc_w   = (const float*)d_in[6];
    const float* v_pj_w   = (const float*)d_in[7];
    const float* mem_kv   = (const float*)d_in[8];
    const float* k_pos    = (const float*)d_in[9];
    const float* v_pos    = (const float*)d_in[10];
    const float* strat_w  = (const float*)d_in[11];
    const float* strat_b  = (const float*)d_in[12];
    float* out = (float*)d_out;

    char* ws = (char*)d_ws;
    size_t off = 0;
    auto alloc = [&](size_t bytes) -> void* {
        void* p = ws + off;
        off += (bytes + 255) & ~(size_t)255;
        return p;
    };

    // region0 (33.6MB): buf_qkv f32 [2048][3072] (25.2MB, dead after prep_qkv),
    //                   then hidden f32 [1024][8192] (33.6MB, dead after pj GEMMs),
    //                   then mix f32 [2048][1024] (8.4MB)
    char* region0  = (char*)alloc((size_t)1024 * 8192 * 4);
    float* buf_qkv = (float*)region0;
    float* hidden  = (float*)region0;
    float* mix     = (float*)region0;

    float* q     = (float*)alloc((size_t)NHEAD * T_LEN * 128 * 4);
    float* k     = (float*)alloc((size_t)NHEAD * T_LEN * 128 * 4);
    float* v     = (float*)alloc((size_t)NHEAD * T_LEN * 128 * 4);
    float* kc_in = (float*)alloc((size_t)1024 * 2048 * 4);   // dead after fc-k GEMM; comp aliases
    float* vc_in = (float*)alloc((size_t)1024 * 2048 * 4);   // dead after fc-v GEMM; fine aliases
    float* comp  = kc_in;
    float* fine  = vc_in;
    float* slide = (float*)alloc((size_t)NHEAD * T_LEN * 128 * 4);
    float* ckb   = (float*)alloc((size_t)1024 * 128 * 4);
    float* cvb   = (float*)alloc((size_t)1024 * 128 * 4);
    float* ck    = (float*)alloc((size_t)NHEAD * (NBLK + NMEM) * 128 * 4);
    float* cv    = (float*)alloc((size_t)NHEAD * (NBLK + NMEM) * 128 * 4);
    float* csim  = (float*)alloc((size_t)NHEAD * T_LEN * (NBLK + NMEM) * 4);
    float* imp   = (float*)alloc((size_t)T_LEN * NBLK * 4);
    float* strat = (float*)alloc((size_t)T_LEN * 24 * 4);
    unsigned long long* selbits = (unsigned long long*)alloc((size_t)T_LEN * 2 * 8);

    // 1. QKV projection: [2048,1024] x [3072,1024]^T -> [2048,3072]
    gemm_tn<0><<<dim3(3072 / 64, T_LEN / 64), 256, 0, stream>>>(
        x, qkv_w, buf_qkv, T_LEN, 3072, 1024);

    // 2. rms + rotary + v-scale -> q,k,v [H,T,D]
    prep_qkv<<<dim3(T_LEN, NHEAD), 128, 0, stream>>>(buf_qkv, lambdas, q, k, v);

    // 3. compress-MLP inputs
    build_cin<<<(NHEAD * NBLK * BS * DHEAD + 255) / 256, 256, 0, stream>>>(
        k, v, k_pos, v_pos, kc_in, vc_in);

    // 4-7. compress MLPs (k then v, reusing hidden)
    gemm_tn<1><<<dim3(8192 / 64, 1024 / 64), 256, 0, stream>>>(
        kc_in, k_fc_w, hidden, 1024, 8192, 2048);
    gemm_tn<0><<<dim3(128 / 64, 1024 / 64), 256, 0, stream>>>(
        hidden, k_pj_w, ckb, 1024, 128, 8192);
    gemm_tn<1><<<dim3(8192 / 64, 1024 / 64), 256, 0, stream>>>(
        vc_in, v_fc_w, hidden, 1024, 8192, 2048);
    gemm_tn<0><<<dim3(128 / 64, 1024 / 64), 256, 0, stream>>>(
        hidden, v_pj_w, cvb, 1024, 128, 8192);

    // 8. assemble ck/cv with mem slot
    scatter_ckcv<<<(NHEAD * (NBLK + NMEM) * DHEAD + 255) / 256, 256, 0, stream>>>(
        ckb, cvb, mem_kv, ck, cv);

    // 9. compressed similarities
    csim_kern<<<dim3(T_LEN, NHEAD), 256, 0, stream>>>(q, ck, csim);

    // 10. compressed attention output
    comp_att<<<dim3(T_LEN, NHEAD), 256, 0, stream>>>(csim, cv, comp);

    // 11. importance + 12. top-k selection
    imp_kern<<<(T_LEN * NBLK + 255) / 256, 256, 0, stream>>>(csim, imp);
    topk_kern<<<(T_LEN + 255) / 256, 256, 0, stream>>>(imp, selbits);

    // 13. fine block-sparse attention
    fine_att<<<dim3(T_LEN, NHEAD), 256, 0, stream>>>(q, k, v, selbits, fine);

    // 14. sliding-window attention
    slide_att<<<dim3(T_LEN, NHEAD), 256, 0, stream>>>(q, k, v, slide);

    // 15. strategy gates
    strat_kern<<<dim3(24, T_LEN), 64, 0, stream>>>(x, strat_w, strat_b, strat);

    // 16. combine
    combine_kern<<<T_LEN, 256, 0, stream>>>(strat, comp, fine, slide, mix);

    // 17. output projection -> d_out
    gemm_tn<0><<<dim3(1024 / 64, T_LEN / 64), 256, 0, stream>>>(
        mix, c_proj_w, out, T_LEN, 1024, 1024);
}

// Round 5
// 3257.999 us; speedup vs baseline: 1.4917x; 1.4917x over previous
//
// Round 5: attention-path rewrite (fine/slide/comp) — wave-cooperative
// coalesced scores + parallel PV + fused csim/comp. GEMMs unchanged
// (next round: bf16 MFMA).
#include <hip/hip_runtime.h>
#include <hip/hip_bf16.h>

#define T_LEN 2048
#define NHEAD 8
#define DHEAD 128
#define NBLK 128     // W
#define BS 16
#define NSEL 16
#define WIN 128
#define NMEM 1
#define SCALE 0.12f
#define NEG -1e9f

// full-wave dot product over 128 floats: lanes hold 2 elems each, shuffle-reduce.
__device__ __forceinline__ float wave_dot(const float* __restrict__ kr,
                                          const float* __restrict__ qs, int lane) {
    const float2 kv = *reinterpret_cast<const float2*>(kr + lane * 2);
    const float2 qv = *reinterpret_cast<const float2*>(qs + lane * 2);
    float s = kv.x * qv.x + kv.y * qv.y;
    s += __shfl_xor(s, 32); s += __shfl_xor(s, 16); s += __shfl_xor(s, 8);
    s += __shfl_xor(s, 4);  s += __shfl_xor(s, 2);  s += __shfl_xor(s, 1);
    return s;
}

// ---------------- generic tiled GEMM: C[m,n] = sum_k A[m,k]*B[n,k] ----------------
template <int EPI>
__global__ __launch_bounds__(256) void gemm_tn(const float* __restrict__ A,
                                               const float* __restrict__ B,
                                               float* __restrict__ C,
                                               int M, int N, int K) {
    __shared__ float As[16][68];
    __shared__ float Bs[16][68];
    const int bm = blockIdx.y * 64, bn = blockIdx.x * 64;
    const int tid = threadIdx.x;
    const int tx = tid & 15, ty = tid >> 4;
    const int lr = tid >> 2;
    const int lc = (tid & 3) << 2;
    float acc[4][4] = {};
    const float* pa = A + (size_t)(bm + lr) * K + lc;
    const float* pb = B + (size_t)(bn + lr) * K + lc;
    for (int kt = 0; kt < K; kt += 16) {
        const float4 a4 = *reinterpret_cast<const float4*>(pa + kt);
        const float4 b4 = *reinterpret_cast<const float4*>(pb + kt);
        As[lc + 0][lr] = a4.x; As[lc + 1][lr] = a4.y;
        As[lc + 2][lr] = a4.z; As[lc + 3][lr] = a4.w;
        Bs[lc + 0][lr] = b4.x; Bs[lc + 1][lr] = b4.y;
        Bs[lc + 2][lr] = b4.z; Bs[lc + 3][lr] = b4.w;
        __syncthreads();
#pragma unroll
        for (int kk = 0; kk < 16; ++kk) {
            const float4 av = *reinterpret_cast<const float4*>(&As[kk][ty * 4]);
            const float4 bv = *reinterpret_cast<const float4*>(&Bs[kk][tx * 4]);
            acc[0][0] += av.x * bv.x; acc[0][1] += av.x * bv.y; acc[0][2] += av.x * bv.z; acc[0][3] += av.x * bv.w;
            acc[1][0] += av.y * bv.x; acc[1][1] += av.y * bv.y; acc[1][2] += av.y * bv.z; acc[1][3] += av.y * bv.w;
            acc[2][0] += av.z * bv.x; acc[2][1] += av.z * bv.y; acc[2][2] += av.z * bv.z; acc[2][3] += av.z * bv.w;
            acc[3][0] += av.w * bv.x; acc[3][1] += av.w * bv.y; acc[3][2] += av.w * bv.z; acc[3][3] += av.w * bv.w;
        }
        __syncthreads();
    }
#pragma unroll
    for (int i = 0; i < 4; ++i) {
        float4 o;
        float* op = &o.x;
#pragma unroll
        for (int j = 0; j < 4; ++j) {
            float v = acc[i][j];
            if (EPI == 1) { v = v > 0.f ? v : 0.f; v = v * v; }
            op[j] = v;
        }
        *reinterpret_cast<float4*>(&C[(size_t)(bm + ty * 4 + i) * N + bn + tx * 4]) = o;
    }
}

// ---------------- per-(h,t): rms-norm q,k; rotary; scale v ----------------
__global__ __launch_bounds__(128) void prep_qkv(const float* __restrict__ qkvbuf,
                                                const float* __restrict__ lambdas,
                                                float* __restrict__ q, float* __restrict__ k,
                                                float* __restrict__ v) {
    const int t = blockIdx.x, h = blockIdx.y, d = threadIdx.x;
    const int lane = d & 63, wave = d >> 6;
    __shared__ float sq[128], sk[128];
    __shared__ float r2[4];
    const float* row = qkvbuf + (size_t)t * 3072 + h * 128;
    const float qv = row[d], kv = row[1024 + d], vv = row[2048 + d];

    float s2q = qv * qv, s2k = kv * kv;
#pragma unroll
    for (int off = 32; off; off >>= 1) {
        s2q += __shfl_xor(s2q, off);
        s2k += __shfl_xor(s2k, off);
    }
    if (lane == 0) { r2[wave] = s2q; r2[2 + wave] = s2k; }
    __syncthreads();
    const float qr = rsqrtf((r2[0] + r2[1]) / 128.f + 1e-6f);
    const float kr = rsqrtf((r2[2] + r2[3]) / 128.f + 1e-6f);
    sq[d] = qv * qr; sk[d] = kv * kr;
    __syncthreads();

    const int j = d & 63;
    const float ang = (j < 32) ? powf(1.0f / 1024.0f, (float)j / 31.0f) : 0.0f;
    const float th = ang * (float)t;
    const float c = cosf(th), s = sinf(th);
    float qo, ko;
    if (d < 64) { qo = sq[d] * c + sq[d + 64] * s; ko = sk[d] * c + sk[d + 64] * s; }
    else        { qo = -sq[d - 64] * s + sq[d] * c; ko = -sk[d - 64] * s + sk[d] * c; }

    const size_t idx = ((size_t)h * T_LEN + t) * 128 + d;
    q[idx] = qo;
    k[idx] = ko;
    v[idx] = lambdas[0] * vv;
}

// ---------------- build compress-MLP inputs (float4) ----------------
__global__ void build_cin(const float* __restrict__ k, const float* __restrict__ v,
                          const float* __restrict__ kpos, const float* __restrict__ vpos,
                          float* __restrict__ kc, float* __restrict__ vc) {
    const int idx = blockIdx.x * 256 + threadIdx.x;   // float4 index
    if (idx >= NHEAD * NBLK * BS * DHEAD / 4) return;
    const int d4 = idx & 31, i = (idx >> 5) & 15, w = (idx >> 9) & 127, h = idx >> 16;
    const int t = w * 16 + i;
    const size_t src = (((size_t)h * T_LEN + t) * 128 + d4 * 4) / 4;
    const int pos = ((h * 16 + i) * 128 + d4 * 4) / 4;
    const float4 kv = reinterpret_cast<const float4*>(k)[src];
    const float4 vv = reinterpret_cast<const float4*>(v)[src];
    const float4 kp = reinterpret_cast<const float4*>(kpos)[pos];
    const float4 vp = reinterpret_cast<const float4*>(vpos)[pos];
    reinterpret_cast<float4*>(kc)[idx] = make_float4(kv.x + kp.x, kv.y + kp.y, kv.z + kp.z, kv.w + kp.w);
    reinterpret_cast<float4*>(vc)[idx] = make_float4(vv.x + vp.x, vv.y + vp.y, vv.z + vp.z, vv.w + vp.w);
}

// ---------------- assemble ck/cv with mem slot ----------------
__global__ void scatter_ckcv(const float* __restrict__ ckb, const float* __restrict__ cvb,
                             const float* __restrict__ memkv,
                             float* __restrict__ ck, float* __restrict__ cv) {
    int idx = blockIdx.x * 256 + threadIdx.x;
    if (idx >= NHEAD * (NBLK + NMEM) * DHEAD) return;
    const int d = idx & 127;
    const int j = (idx >> 7) % (NBLK + NMEM);
    const int h = idx / ((NBLK + NMEM) * DHEAD);
    if (j == 0) {
        ck[idx] = memkv[h * 128 + d];
        cv[idx] = memkv[NHEAD * 128 + h * 128 + d];
    } else {
        const size_t b = ((size_t)h * NBLK + (j - 1)) * 128 + d;
        ck[idx] = ckb[b];
        cv[idx] = cvb[b];
    }
}

// ---------------- fused compressed attention: scores -> csim, softmax, PV ----------------
__global__ __launch_bounds__(256) void comp_att(const float* __restrict__ q,
                                                const float* __restrict__ ck,
                                                const float* __restrict__ cv,
                                                float* __restrict__ csim,
                                                float* __restrict__ out) {
    const int t = blockIdx.x, h = blockIdx.y, tid = threadIdx.x;
    const int lane = tid & 63, wave = tid >> 6;
    const int NJ = NBLK + NMEM;   // 129
    __shared__ float qs[128];
    __shared__ float sc[NBLK + NMEM];
    __shared__ float redm[4], reds[4];
    __shared__ float pv[2][128];
    if (tid < 128) qs[tid] = q[((size_t)h * T_LEN + t) * 128 + tid];
    __syncthreads();
    // scores: one wave per slot; slot s valid iff s <= t/16 (s=0 is mem, always valid)
    const int smax = t >> 4;
    for (int s = wave; s < NJ; s += 4) {
        float val = NEG;
        if (s <= smax)
            val = wave_dot(ck + ((size_t)h * NJ + s) * 128, qs, lane) * SCALE;
        if (lane == 0) {
            sc[s] = val;
            csim[((size_t)h * T_LEN + t) * NJ + s] = val;
        }
    }
    __syncthreads();
    // softmax
    float lm = -INFINITY;
    for (int s = tid; s < NJ; s += 256) lm = fmaxf(lm, sc[s]);
#pragma unroll
    for (int off = 32; off; off >>= 1) lm = fmaxf(lm, __shfl_xor(lm, off));
    if (lane == 0) redm[wave] = lm;
    __syncthreads();
    const float mx = fmaxf(fmaxf(redm[0], redm[1]), fmaxf(redm[2], redm[3]));
    float ls = 0.f;
    for (int s = tid; s < NJ; s += 256) { const float e = __expf(sc[s] - mx); sc[s] = e; ls += e; }
#pragma unroll
    for (int off = 32; off; off >>= 1) ls += __shfl_xor(ls, off);
    if (lane == 0) reds[wave] = ls;
    __syncthreads();
    const float inv = 1.f / (reds[0] + reds[1] + reds[2] + reds[3]);
    // PV: thread = (half, d)
    const int d = tid & 127, half = tid >> 7;
    float o = 0.f;
    for (int s = half; s < NJ; s += 2)
        o += sc[s] * cv[((size_t)h * NJ + s) * 128 + d];
    pv[half][d] = o;
    __syncthreads();
    if (tid < 128)
        out[((size_t)h * T_LEN + t) * 128 + tid] = (pv[0][tid] + pv[1][tid]) * inv;
}

// ---------------- importance: mean over heads of csim[...,1:] ----------------
__global__ void imp_kern(const float* __restrict__ csim, float* __restrict__ imp) {
    int idx = blockIdx.x * 256 + threadIdx.x;
    if (idx >= T_LEN * NBLK) return;
    const int w = idx & 127, t = idx >> 7;
    float s = 0.f;
    for (int h = 0; h < NHEAD; ++h)
        s += csim[((size_t)h * T_LEN + t) * (NBLK + NMEM) + 1 + w];
    imp[idx] = s * 0.125f;
}

// ---------------- top-16 block selection per t ----------------
__global__ void topk_kern(const float* __restrict__ imp, unsigned long long* __restrict__ selbits) {
    const int t = blockIdx.x * blockDim.x + threadIdx.x;
    if (t >= T_LEN) return;
    const float* row = imp + (size_t)t * NBLK;
    unsigned long long b0 = 0, b1 = 0;
    for (int s = 0; s < NSEL; ++s) {
        float best = -INFINITY; int bi = 0;
        for (int w = 0; w < NBLK; ++w) {
            const bool used = (w < 64) ? ((b0 >> w) & 1ull) : ((b1 >> (w - 64)) & 1ull);
            const float vv = row[w];
            if (!used && vv > best) { best = vv; bi = w; }
        }
        if (bi < 64) b0 |= 1ull << bi; else b1 |= 1ull << (bi - 64);
    }
    selbits[2 * t] = b0; selbits[2 * t + 1] = b1;
}

// ---------------- fine block-sparse attention (wave-cooperative) ----------------
__global__ __launch_bounds__(256) void fine_att(const float* __restrict__ q,
                                                const float* __restrict__ k,
                                                const float* __restrict__ v,
                                                const unsigned long long* __restrict__ selbits,
                                                float* __restrict__ out) {
    const int t = blockIdx.x, h = blockIdx.y, tid = threadIdx.x;
    const int lane = tid & 63, wave = tid >> 6;
    __shared__ float qs[128];
    __shared__ float sc[17 * 16];
    __shared__ int blks[17];
    __shared__ int nb_s;
    __shared__ float redm[4], reds[4];
    __shared__ float pv[2][128];
    if (tid < 128) qs[tid] = q[((size_t)h * T_LEN + t) * 128 + tid];
    if (tid == 0) {
        unsigned long long b0 = selbits[2 * t], b1 = selbits[2 * t + 1];
        const int cur = t >> 4;
        const bool curin = (cur < 64) ? ((b0 >> cur) & 1ull) : ((b1 >> (cur - 64)) & 1ull);
        int nb = 0;
        while (b0) { const int w = __ffsll(b0) - 1; b0 &= b0 - 1; blks[nb++] = w; }
        while (b1) { const int w = __ffsll(b1) - 1; b1 &= b1 - 1; blks[nb++] = w + 64; }
        if (!curin) blks[nb++] = cur;
        nb_s = nb;
    }
    __syncthreads();
    const int ns = nb_s * 16;
    // scores: one wave per key slot
    for (int s = wave; s < ns; s += 4) {
        const int j = blks[s >> 4] * 16 + (s & 15);
        float val = -INFINITY;
        if (j <= t)
            val = wave_dot(k + ((size_t)h * T_LEN + j) * 128, qs, lane) * SCALE;
        if (lane == 0) sc[s] = val;
    }
    __syncthreads();
    // softmax
    float lm = -INFINITY;
    for (int s = tid; s < ns; s += 256) lm = fmaxf(lm, sc[s]);
#pragma unroll
    for (int off = 32; off; off >>= 1) lm = fmaxf(lm, __shfl_xor(lm, off));
    if (lane == 0) redm[wave] = lm;
    __syncthreads();
    const float mx = fmaxf(fmaxf(redm[0], redm[1]), fmaxf(redm[2], redm[3]));
    float ls = 0.f;
    for (int s = tid; s < ns; s += 256) { const float e = __expf(sc[s] - mx); sc[s] = e; ls += e; }
#pragma unroll
    for (int off = 32; off; off >>= 1) ls += __shfl_xor(ls, off);
    if (lane == 0) reds[wave] = ls;
    __syncthreads();
    const float inv = 1.f / (reds[0] + reds[1] + reds[2] + reds[3]);
    // PV
    const int d = tid & 127, half = tid >> 7;
    float o = 0.f;
    for (int s = half; s < ns; s += 2) {
        const int j = blks[s >> 4] * 16 + (s & 15);
        o += sc[s] * v[((size_t)h * T_LEN + j) * 128 + d];
    }
    pv[half][d] = o;
    __syncthreads();
    if (tid < 128)
        out[((size_t)h * T_LEN + t) * 128 + tid] = (pv[0][tid] + pv[1][tid]) * inv;
}

// ---------------- sliding-window attention (wave-cooperative) ----------------
__global__ __launch_bounds__(256) void slide_att(const float* __restrict__ q,
                                                 const float* __restrict__ k,
                                                 const float* __restrict__ v,
                                                 float* __restrict__ out) {
    const int t = blockIdx.x, h = blockIdx.y, tid = threadIdx.x;
    const int lane = tid & 63, wave = tid >> 6;
    __shared__ float qs[128];
    __shared__ float sc[WIN];
    __shared__ float redm[4], reds[4];
    __shared__ float pv[2][128];
    if (tid < 128) qs[tid] = q[((size_t)h * T_LEN + t) * 128 + tid];
    __syncthreads();
    const int j0 = max(0, t - (WIN - 1));
    const int ns = t - j0 + 1;
    for (int s = wave; s < ns; s += 4) {
        const float val = wave_dot(k + ((size_t)h * T_LEN + j0 + s) * 128, qs, lane) * SCALE;
        if (lane == 0) sc[s] = val;
    }
    __syncthreads();
    float lm = -INFINITY;
    for (int s = tid; s < ns; s += 256) lm = fmaxf(lm, sc[s]);
#pragma unroll
    for (int off = 32; off; off >>= 1) lm = fmaxf(lm, __shfl_xor(lm, off));
    if (lane == 0) redm[wave] = lm;
    __syncthreads();
    const float mx = fmaxf(fmaxf(redm[0], redm[1]), fmaxf(redm[2], redm[3]));
    float ls = 0.f;
    for (int s = tid; s < ns; s += 256) { const float e = __expf(sc[s] - mx); sc[s] = e; ls += e; }
#pragma unroll
    for (int off = 32; off; off >>= 1) ls += __shfl_xor(ls, off);
    if (lane == 0) reds[wave] = ls;
    __syncthreads();
    const float inv = 1.f / (reds[0] + reds[1] + reds[2] + reds[3]);
    const int d = tid & 127, half = tid >> 7;
    float o = 0.f;
    for (int s = half; s < ns; s += 2)
        o += sc[s] * v[((size_t)h * T_LEN + j0 + s) * 128 + d];
    pv[half][d] = o;
    __syncthreads();
    if (tid < 128)
        out[((size_t)h * T_LEN + t) * 128 + tid] = (pv[0][tid] + pv[1][tid]) * inv;
}

// ---------------- strategy gates: one block per t, wave per i ----------------
__global__ __launch_bounds__(256) void strat_kern(const float* __restrict__ x,
                                                  const float* __restrict__ w,
                                                  const float* __restrict__ b,
                                                  float* __restrict__ strat) {
    const int t = blockIdx.x, tid = threadIdx.x;
    const int lane = tid & 63, wave = tid >> 6;
    __shared__ float xs[1024];
    for (int c = tid; c < 1024; c += 256) xs[c] = x[(size_t)t * 1024 + c];
    __syncthreads();
    for (int i = wave; i < 24; i += 4) {
        const float* wr = w + (size_t)i * 1024;
        float s = 0.f;
#pragma unroll
        for (int u = 0; u < 4; ++u) {
            const int c = u * 256 + lane * 4;
            const float4 wv = *reinterpret_cast<const float4*>(wr + c);
            const float4 xv = *reinterpret_cast<const float4*>(&xs[c]);
            s += wv.x * xv.x + wv.y * xv.y + wv.z * xv.z + wv.w * xv.w;
        }
#pragma unroll
        for (int off = 32; off; off >>= 1) s += __shfl_xor(s, off);
        if (lane == 0)
            strat[t * 24 + i] = 1.f / (1.f + __expf(-(s + b[i])));
    }
}

// ---------------- combine three attention branches ----------------
__global__ __launch_bounds__(256) void combine_kern(const float* __restrict__ strat,
                                                    const float* __restrict__ comp,
                                                    const float* __restrict__ fine,
                                                    const float* __restrict__ slide,
                                                    float* __restrict__ mix) {
    const int t = blockIdx.x;
    for (int hd = threadIdx.x; hd < 1024; hd += 256) {
        const int h = hd >> 7, d = hd & 127;
        const float* st = strat + t * 24 + h * 3;
        const size_t idx = ((size_t)h * T_LEN + t) * 128 + d;
        mix[(size_t)t * 1024 + hd] = st[0] * comp[idx] + st[1] * fine[idx] + st[2] * slide[idx];
    }
}

extern "C" void kernel_launch(void* const* d_in, const int* in_sizes, int n_in,
                              void* d_out, int out_size, void* d_ws, size_t ws_size,
                              hipStream_t stream) {
    const float* x        = (const float*)d_in[0];
    const float* qkv_w    = (const float*)d_in[1];
    const float* lambdas  = (const float*)d_in[2];
    const float* c_proj_w = (const float*)d_in[3];
    const float* k_fc_w   = (const float*)d_in[4];
    const float* k_pj_w   = (const float*)d_in[5];
    const float* v_fc_w   = (const float*)d_in[6];
    const float* v_pj_w   = (const float*)d_in[7];
    const float* mem_kv   = (const float*)d_in[8];
    const float* k_pos    = (const float*)d_in[9];
    const float* v_pos    = (const float*)d_in[10];
    const float* strat_w  = (const float*)d_in[11];
    const float* strat_b  = (const float*)d_in[12];
    float* out = (float*)d_out;

    char* ws = (char*)d_ws;
    size_t off = 0;
    auto alloc = [&](size_t bytes) -> void* {
        void* p = ws + off;
        off += (bytes + 255) & ~(size_t)255;
        return p;
    };

    // region0: buf_qkv (dead after prep_qkv) -> hidden (dead after pj) -> mix
    char* region0  = (char*)alloc((size_t)1024 * 8192 * 4);
    float* buf_qkv = (float*)region0;
    float* hidden  = (float*)region0;
    float* mix     = (float*)region0;

    float* q     = (float*)alloc((size_t)NHEAD * T_LEN * 128 * 4);
    float* k     = (float*)alloc((size_t)NHEAD * T_LEN * 128 * 4);
    float* v     = (float*)alloc((size_t)NHEAD * T_LEN * 128 * 4);
    float* kc_in = (float*)alloc((size_t)1024 * 2048 * 4);   // dead after fc-k; comp aliases
    float* vc_in = (float*)alloc((size_t)1024 * 2048 * 4);   // dead after fc-v; fine aliases
    float* comp  = kc_in;
    float* fine  = vc_in;
    float* slide = (float*)alloc((size_t)NHEAD * T_LEN * 128 * 4);
    float* ckb   = (float*)alloc((size_t)1024 * 128 * 4);
    float* cvb   = (float*)alloc((size_t)1024 * 128 * 4);
    float* ck    = (float*)alloc((size_t)NHEAD * (NBLK + NMEM) * 128 * 4);
    float* cv    = (float*)alloc((size_t)NHEAD * (NBLK + NMEM) * 128 * 4);
    float* csim  = (float*)alloc((size_t)NHEAD * T_LEN * (NBLK + NMEM) * 4);
    float* imp   = (float*)alloc((size_t)T_LEN * NBLK * 4);
    float* strat = (float*)alloc((size_t)T_LEN * 24 * 4);
    unsigned long long* selbits = (unsigned long long*)alloc((size_t)T_LEN * 2 * 8);

    // 1. QKV projection
    gemm_tn<0><<<dim3(3072 / 64, T_LEN / 64), 256, 0, stream>>>(
        x, qkv_w, buf_qkv, T_LEN, 3072, 1024);

    // 2. rms + rotary + v-scale
    prep_qkv<<<dim3(T_LEN, NHEAD), 128, 0, stream>>>(buf_qkv, lambdas, q, k, v);

    // 3. compress-MLP inputs (float4)
    build_cin<<<(NHEAD * NBLK * BS * DHEAD / 4 + 255) / 256, 256, 0, stream>>>(
        k, v, k_pos, v_pos, kc_in, vc_in);

    // 4-7. compress MLPs
    gemm_tn<1><<<dim3(8192 / 64, 1024 / 64), 256, 0, stream>>>(
        kc_in, k_fc_w, hidden, 1024, 8192, 2048);
    gemm_tn<0><<<dim3(128 / 64, 1024 / 64), 256, 0, stream>>>(
        hidden, k_pj_w, ckb, 1024, 128, 8192);
    gemm_tn<1><<<dim3(8192 / 64, 1024 / 64), 256, 0, stream>>>(
        vc_in, v_fc_w, hidden, 1024, 8192, 2048);
    gemm_tn<0><<<dim3(128 / 64, 1024 / 64), 256, 0, stream>>>(
        hidden, v_pj_w, cvb, 1024, 128, 8192);

    // 8. assemble ck/cv
    scatter_ckcv<<<(NHEAD * (NBLK + NMEM) * DHEAD + 255) / 256, 256, 0, stream>>>(
        ckb, cvb, mem_kv, ck, cv);

    // 9+10. fused compressed attention (writes csim + comp)
    comp_att<<<dim3(T_LEN, NHEAD), 256, 0, stream>>>(q, ck, cv, csim, comp);

    // 11+12. importance + top-k
    imp_kern<<<(T_LEN * NBLK + 255) / 256, 256, 0, stream>>>(csim, imp);
    topk_kern<<<(T_LEN + 255) / 256, 256, 0, stream>>>(imp, selbits);

    // 13. fine block-sparse attention
    fine_att<<<dim3(T_LEN, NHEAD), 256, 0, stream>>>(q, k, v, selbits, fine);

    // 14. sliding-window attention
    slide_att<<<dim3(T_LEN, NHEAD), 256, 0, stream>>>(q, k, v, slide);

    // 15. strategy gates
    strat_kern<<<T_LEN, 256, 0, stream>>>(x, strat_w, strat_b, strat);

    // 16. combine
    combine_kern<<<T_LEN, 256, 0, stream>>>(strat, comp, fine, slide, mix);

    // 17. output projection
    gemm_tn<0><<<dim3(1024 / 64, T_LEN / 64), 256, 0, stream>>>(
        mix, c_proj_w, out, T_LEN, 1024, 1024);
}

// Round 6
// 2346.194 us; speedup vs baseline: 2.0715x; 1.3886x over previous
//
// Round 6: (a) 128x128 8x8-register-blocked f32 GEMM (+split-K for pj),
// (b) fine/slide/comp score phase -> chunked LDS staging, 4-thr/key,
//     q in registers, XOR-swizzled LDS (kills wave_dot shuffle overhead).
// f32 kept everywhere: bf16 would perturb csim -> topk block flips vs ref.
#include <hip/hip_runtime.h>
#include <hip/hip_bf16.h>

#define T_LEN 2048
#define NHEAD 8
#define DHEAD 128
#define NBLK 128     // W
#define BS 16
#define NSEL 16
#define WIN 128
#define NMEM 1
#define SCALE 0.12f
#define NEG -1e9f
#define CHK 64       // keys staged per LDS chunk in attention kernels

// ---------------- 128x128 tiled GEMM: C[m,n] = sum_k A[m,k]*B[n,k] ----------------
// M,N multiples of 128; K multiple of 16. EPI: 0 = plain, 1 = relu^2
template <int EPI>
__global__ __launch_bounds__(256) void gemm_tn128(const float* __restrict__ A,
                                                  const float* __restrict__ B,
                                                  float* __restrict__ C,
                                                  int M, int N, int K) {
    __shared__ float As[16][132];
    __shared__ float Bs[16][132];
    const int bm = blockIdx.y * 128, bn = blockIdx.x * 128;
    const int tid = threadIdx.x;
    const int tx = tid & 15, ty = tid >> 4;
    const int lrow = tid >> 2, lcol = (tid & 3) << 2;
    float acc[8][8] = {};
    for (int kt = 0; kt < K; kt += 16) {
#pragma unroll
        for (int u = 0; u < 2; ++u) {
            const int r = lrow + u * 64;
            const float4 a4 = *(const float4*)(A + (size_t)(bm + r) * K + kt + lcol);
            const float4 b4 = *(const float4*)(B + (size_t)(bn + r) * K + kt + lcol);
            As[lcol + 0][r] = a4.x; As[lcol + 1][r] = a4.y;
            As[lcol + 2][r] = a4.z; As[lcol + 3][r] = a4.w;
            Bs[lcol + 0][r] = b4.x; Bs[lcol + 1][r] = b4.y;
            Bs[lcol + 2][r] = b4.z; Bs[lcol + 3][r] = b4.w;
        }
        __syncthreads();
#pragma unroll
        for (int kk = 0; kk < 16; ++kk) {
            float av[8], bv[8];
            *(float4*)&av[0] = *(const float4*)&As[kk][ty * 8];
            *(float4*)&av[4] = *(const float4*)&As[kk][ty * 8 + 4];
            *(float4*)&bv[0] = *(const float4*)&Bs[kk][tx * 8];
            *(float4*)&bv[4] = *(const float4*)&Bs[kk][tx * 8 + 4];
#pragma unroll
            for (int i = 0; i < 8; ++i)
#pragma unroll
                for (int j = 0; j < 8; ++j)
                    acc[i][j] += av[i] * bv[j];
        }
        __syncthreads();
    }
#pragma unroll
    for (int i = 0; i < 8; ++i) {
        float o[8];
#pragma unroll
        for (int j = 0; j < 8; ++j) {
            float v = acc[i][j];
            if (EPI == 1) { v = v > 0.f ? v : 0.f; v = v * v; }
            o[j] = v;
        }
        float* cp = &C[(size_t)(bm + ty * 8 + i) * N + bn + tx * 8];
        *(float4*)cp = *(float4*)&o[0];
        *(float4*)(cp + 4) = *(float4*)&o[4];
    }
}

// ---------------- 64x64 split-K GEMM (for pj: M=1024, N=128, K=8192) ----------------
__global__ __launch_bounds__(256) void gemm_tn64_splitk(const float* __restrict__ A,
                                                        const float* __restrict__ B,
                                                        float* __restrict__ P,
                                                        int M, int N, int K, int KC) {
    __shared__ float As[16][68];
    __shared__ float Bs[16][68];
    const int bm = blockIdx.y * 64, bn = blockIdx.x * 64;
    const int k0 = blockIdx.z * KC, k1 = k0 + KC;
    const int tid = threadIdx.x;
    const int tx = tid & 15, ty = tid >> 4;
    const int lr = tid >> 2, lc = (tid & 3) << 2;
    float acc[4][4] = {};
    const float* pa = A + (size_t)(bm + lr) * K + lc;
    const float* pb = B + (size_t)(bn + lr) * K + lc;
    for (int kt = k0; kt < k1; kt += 16) {
        const float4 a4 = *(const float4*)(pa + kt);
        const float4 b4 = *(const float4*)(pb + kt);
        As[lc + 0][lr] = a4.x; As[lc + 1][lr] = a4.y;
        As[lc + 2][lr] = a4.z; As[lc + 3][lr] = a4.w;
        Bs[lc + 0][lr] = b4.x; Bs[lc + 1][lr] = b4.y;
        Bs[lc + 2][lr] = b4.z; Bs[lc + 3][lr] = b4.w;
        __syncthreads();
#pragma unroll
        for (int kk = 0; kk < 16; ++kk) {
            const float4 av = *(const float4*)&As[kk][ty * 4];
            const float4 bv = *(const float4*)&Bs[kk][tx * 4];
            acc[0][0] += av.x * bv.x; acc[0][1] += av.x * bv.y; acc[0][2] += av.x * bv.z; acc[0][3] += av.x * bv.w;
            acc[1][0] += av.y * bv.x; acc[1][1] += av.y * bv.y; acc[1][2] += av.y * bv.z; acc[1][3] += av.y * bv.w;
            acc[2][0] += av.z * bv.x; acc[2][1] += av.z * bv.y; acc[2][2] += av.z * bv.z; acc[2][3] += av.z * bv.w;
            acc[3][0] += av.w * bv.x; acc[3][1] += av.w * bv.y; acc[3][2] += av.w * bv.z; acc[3][3] += av.w * bv.w;
        }
        __syncthreads();
    }
    float* Pz = P + (size_t)blockIdx.z * M * N;
#pragma unroll
    for (int i = 0; i < 4; ++i) {
        float4 o = make_float4(acc[i][0], acc[i][1], acc[i][2], acc[i][3]);
        *(float4*)&Pz[(size_t)(bm + ty * 4 + i) * N + bn + tx * 4] = o;
    }
}

__global__ void reduce8(const float* __restrict__ P, float* __restrict__ C, int MN) {
    const int idx = blockIdx.x * 256 + threadIdx.x;
    if (idx >= MN) return;
    float s = 0.f;
#pragma unroll
    for (int z = 0; z < 8; ++z) s += P[(size_t)z * MN + idx];
    C[idx] = s;
}

// ---------------- per-(h,t): rms-norm q,k; rotary; scale v ----------------
__global__ __launch_bounds__(128) void prep_qkv(const float* __restrict__ qkvbuf,
                                                const float* __restrict__ lambdas,
                                                float* __restrict__ q, float* __restrict__ k,
                                                float* __restrict__ v) {
    const int t = blockIdx.x, h = blockIdx.y, d = threadIdx.x;
    const int lane = d & 63, wave = d >> 6;
    __shared__ float sq[128], sk[128];
    __shared__ float r2[4];
    const float* row = qkvbuf + (size_t)t * 3072 + h * 128;
    const float qv = row[d], kv = row[1024 + d], vv = row[2048 + d];

    float s2q = qv * qv, s2k = kv * kv;
#pragma unroll
    for (int off = 32; off; off >>= 1) {
        s2q += __shfl_xor(s2q, off);
        s2k += __shfl_xor(s2k, off);
    }
    if (lane == 0) { r2[wave] = s2q; r2[2 + wave] = s2k; }
    __syncthreads();
    const float qr = rsqrtf((r2[0] + r2[1]) / 128.f + 1e-6f);
    const float kr = rsqrtf((r2[2] + r2[3]) / 128.f + 1e-6f);
    sq[d] = qv * qr; sk[d] = kv * kr;
    __syncthreads();

    const int j = d & 63;
    const float ang = (j < 32) ? powf(1.0f / 1024.0f, (float)j / 31.0f) : 0.0f;
    const float th = ang * (float)t;
    const float c = cosf(th), s = sinf(th);
    float qo, ko;
    if (d < 64) { qo = sq[d] * c + sq[d + 64] * s; ko = sk[d] * c + sk[d + 64] * s; }
    else        { qo = -sq[d - 64] * s + sq[d] * c; ko = -sk[d - 64] * s + sk[d] * c; }

    const size_t idx = ((size_t)h * T_LEN + t) * 128 + d;
    q[idx] = qo;
    k[idx] = ko;
    v[idx] = lambdas[0] * vv;
}

// ---------------- build compress-MLP inputs (float4) ----------------
__global__ void build_cin(const float* __restrict__ k, const float* __restrict__ v,
                          const float* __restrict__ kpos, const float* __restrict__ vpos,
                          float* __restrict__ kc, float* __restrict__ vc) {
    const int idx = blockIdx.x * 256 + threadIdx.x;   // float4 index
    if (idx >= NHEAD * NBLK * BS * DHEAD / 4) return;
    const int d4 = idx & 31, i = (idx >> 5) & 15, w = (idx >> 9) & 127, h = idx >> 16;
    const int t = w * 16 + i;
    const size_t src = (((size_t)h * T_LEN + t) * 128 + d4 * 4) / 4;
    const int pos = ((h * 16 + i) * 128 + d4 * 4) / 4;
    const float4 kv = reinterpret_cast<const float4*>(k)[src];
    const float4 vv = reinterpret_cast<const float4*>(v)[src];
    const float4 kp = reinterpret_cast<const float4*>(kpos)[pos];
    const float4 vp = reinterpret_cast<const float4*>(vpos)[pos];
    reinterpret_cast<float4*>(kc)[idx] = make_float4(kv.x + kp.x, kv.y + kp.y, kv.z + kp.z, kv.w + kp.w);
    reinterpret_cast<float4*>(vc)[idx] = make_float4(vv.x + vp.x, vv.y + vp.y, vv.z + vp.z, vv.w + vp.w);
}

// ---------------- assemble ck/cv with mem slot ----------------
__global__ void scatter_ckcv(const float* __restrict__ ckb, const float* __restrict__ cvb,
                             const float* __restrict__ memkv,
                             float* __restrict__ ck, float* __restrict__ cv) {
    int idx = blockIdx.x * 256 + threadIdx.x;
    if (idx >= NHEAD * (NBLK + NMEM) * DHEAD) return;
    const int d = idx & 127;
    const int j = (idx >> 7) % (NBLK + NMEM);
    const int h = idx / ((NBLK + NMEM) * DHEAD);
    if (j == 0) {
        ck[idx] = memkv[h * 128 + d];
        cv[idx] = memkv[NHEAD * 128 + h * 128 + d];
    } else {
        const size_t b = ((size_t)h * NBLK + (j - 1)) * 128 + d;
        ck[idx] = ckb[b];
        cv[idx] = cvb[b];
    }
}

// ============ shared attention helpers (chunked LDS, swizzled) ============
// buf layout: [CHK][128] floats, float c of row r stored at col c ^ ((r&7)<<2).

// ---------------- fused compressed attention ----------------
__global__ __launch_bounds__(256) void comp_att(const float* __restrict__ q,
                                                const float* __restrict__ ck,
                                                const float* __restrict__ cv,
                                                float* __restrict__ csim,
                                                float* __restrict__ out) {
    const int t = blockIdx.x, h = blockIdx.y, tid = threadIdx.x;
    const int lane = tid & 63, wave = tid >> 6;
    const int NJ = NBLK + NMEM;   // 129
    __shared__ float buf[CHK][128];
    __shared__ float qs[128];
    __shared__ float sc[NBLK + NMEM];
    __shared__ float redm[4], reds[4];
    if (tid < 128) qs[tid] = q[((size_t)h * T_LEN + t) * 128 + tid];
    __syncthreads();
    const int grp = tid & 3, keyl = tid >> 2;
    float qreg[32];
#pragma unroll
    for (int u = 0; u < 8; ++u)
        *(float4*)&qreg[u * 4] = *(const float4*)&qs[grp * 32 + u * 4];
    const int smax = t >> 4;
    const int nchunk = (NJ + CHK - 1) / CHK;  // 3
    for (int c = 0; c < nchunk; ++c) {
        __syncthreads();
#pragma unroll
        for (int u = 0; u < 8; ++u) {
            const int fidx = u * 256 + tid;
            const int row = fidx >> 5, col = (fidx & 31) << 2;
            const int s = min(c * CHK + row, NJ - 1);
            *(float4*)&buf[row][col ^ ((row & 7) << 2)] =
                *(const float4*)(ck + ((size_t)h * NJ + s) * 128 + col);
        }
        __syncthreads();
        const int s = c * CHK + keyl;
        float sum = 0.f;
#pragma unroll
        for (int u = 0; u < 8; ++u) {
            const int cb = grp * 32 + u * 4;
            const float4 kv = *(const float4*)&buf[keyl][cb ^ ((keyl & 7) << 2)];
            sum += kv.x * qreg[u * 4] + kv.y * qreg[u * 4 + 1] +
                   kv.z * qreg[u * 4 + 2] + kv.w * qreg[u * 4 + 3];
        }
        sum += __shfl_xor(sum, 1); sum += __shfl_xor(sum, 2);
        if (grp == 0 && s < NJ) {
            const float val = (s <= smax) ? sum * SCALE : NEG;
            sc[s] = val;
            csim[((size_t)h * T_LEN + t) * NJ + s] = val;
        }
    }
    __syncthreads();
    // softmax
    float lm = -INFINITY;
    for (int s = tid; s < NJ; s += 256) lm = fmaxf(lm, sc[s]);
#pragma unroll
    for (int off = 32; off; off >>= 1) lm = fmaxf(lm, __shfl_xor(lm, off));
    if (lane == 0) redm[wave] = lm;
    __syncthreads();
    const float mx = fmaxf(fmaxf(redm[0], redm[1]), fmaxf(redm[2], redm[3]));
    float ls = 0.f;
    for (int s = tid; s < NJ; s += 256) { const float e = __expf(sc[s] - mx); sc[s] = e; ls += e; }
#pragma unroll
    for (int off = 32; off; off >>= 1) ls += __shfl_xor(ls, off);
    if (lane == 0) reds[wave] = ls;
    __syncthreads();
    const float inv = 1.f / (reds[0] + reds[1] + reds[2] + reds[3]);
    // PV from staged v chunks
    const int d = tid & 127, h2 = tid >> 7;
    float o = 0.f;
    for (int c = 0; c < nchunk; ++c) {
        __syncthreads();
#pragma unroll
        for (int u = 0; u < 8; ++u) {
            const int fidx = u * 256 + tid;
            const int row = fidx >> 5, col = (fidx & 31) << 2;
            const int s = min(c * CHK + row, NJ - 1);
            *(float4*)&buf[row][col ^ ((row & 7) << 2)] =
                *(const float4*)(cv + ((size_t)h * NJ + s) * 128 + col);
        }
        __syncthreads();
#pragma unroll
        for (int r = 0; r < 32; ++r) {
            const int kk = r * 2 + h2, s = c * CHK + kk;
            if (s < NJ) o += sc[s] * buf[kk][d ^ ((kk & 7) << 2)];
        }
    }
    __syncthreads();
    ((float*)buf)[h2 * 128 + d] = o;
    __syncthreads();
    if (tid < 128)
        out[((size_t)h * T_LEN + t) * 128 + tid] =
            (((float*)buf)[tid] + ((float*)buf)[128 + tid]) * inv;
}

// ---------------- importance: mean over heads of csim[...,1:] ----------------
__global__ void imp_kern(const float* __restrict__ csim, float* __restrict__ imp) {
    int idx = blockIdx.x * 256 + threadIdx.x;
    if (idx >= T_LEN * NBLK) return;
    const int w = idx & 127, t = idx >> 7;
    float s = 0.f;
    for (int h = 0; h < NHEAD; ++h)
        s += csim[((size_t)h * T_LEN + t) * (NBLK + NMEM) + 1 + w];
    imp[idx] = s * 0.125f;
}

// ---------------- top-16 block selection per t ----------------
__global__ void topk_kern(const float* __restrict__ imp, unsigned long long* __restrict__ selbits) {
    const int t = blockIdx.x * blockDim.x + threadIdx.x;
    if (t >= T_LEN) return;
    const float* row = imp + (size_t)t * NBLK;
    unsigned long long b0 = 0, b1 = 0;
    for (int s = 0; s < NSEL; ++s) {
        float best = -INFINITY; int bi = 0;
        for (int w = 0; w < NBLK; ++w) {
            const bool used = (w < 64) ? ((b0 >> w) & 1ull) : ((b1 >> (w - 64)) & 1ull);
            const float vv = row[w];
            if (!used && vv > best) { best = vv; bi = w; }
        }
        if (bi < 64) b0 |= 1ull << bi; else b1 |= 1ull << (bi - 64);
    }
    selbits[2 * t] = b0; selbits[2 * t + 1] = b1;
}

// ---------------- fine block-sparse attention ----------------
__global__ __launch_bounds__(256) void fine_att(const float* __restrict__ q,
                                                const float* __restrict__ k,
                                                const float* __restrict__ v,
                                                const unsigned long long* __restrict__ selbits,
                                                float* __restrict__ out) {
    const int t = blockIdx.x, h = blockIdx.y, tid = threadIdx.x;
    const int lane = tid & 63, wave = tid >> 6;
    __shared__ float buf[CHK][128];
    __shared__ float qs[128];
    __shared__ float sc[17 * 16];
    __shared__ int blks[17];
    __shared__ int nb_s;
    __shared__ float redm[4], reds[4];
    if (tid < 128) qs[tid] = q[((size_t)h * T_LEN + t) * 128 + tid];
    if (tid == 0) {
        unsigned long long b0 = selbits[2 * t], b1 = selbits[2 * t + 1];
        const int cur = t >> 4;
        const bool curin = (cur < 64) ? ((b0 >> cur) & 1ull) : ((b1 >> (cur - 64)) & 1ull);
        int nb = 0;
        while (b0) { const int w = __ffsll(b0) - 1; b0 &= b0 - 1; blks[nb++] = w; }
        while (b1) { const int w = __ffsll(b1) - 1; b1 &= b1 - 1; blks[nb++] = w + 64; }
        if (!curin) blks[nb++] = cur;
        nb_s = nb;
    }
    __syncthreads();
    const int ns = nb_s * 16;
    const int nchunk = (ns + CHK - 1) / CHK;
    const int grp = tid & 3, keyl = tid >> 2;
    float qreg[32];
#pragma unroll
    for (int u = 0; u < 8; ++u)
        *(float4*)&qreg[u * 4] = *(const float4*)&qs[grp * 32 + u * 4];
    // scores
    for (int c = 0; c < nchunk; ++c) {
        __syncthreads();
#pragma unroll
        for (int u = 0; u < 8; ++u) {
            const int fidx = u * 256 + tid;
            const int row = fidx >> 5, col = (fidx & 31) << 2;
            const int ki = c * CHK + row;
            const int j = (ki < ns) ? blks[ki >> 4] * 16 + (ki & 15) : 0;
            *(float4*)&buf[row][col ^ ((row & 7) << 2)] =
                *(const float4*)(k + ((size_t)h * T_LEN + j) * 128 + col);
        }
        __syncthreads();
        const int ki = c * CHK + keyl;
        float sum = 0.f;
#pragma unroll
        for (int u = 0; u < 8; ++u) {
            const int cb = grp * 32 + u * 4;
            const float4 kv = *(const float4*)&buf[keyl][cb ^ ((keyl & 7) << 2)];
            sum += kv.x * qreg[u * 4] + kv.y * qreg[u * 4 + 1] +
                   kv.z * qreg[u * 4 + 2] + kv.w * qreg[u * 4 + 3];
        }
        sum += __shfl_xor(sum, 1); sum += __shfl_xor(sum, 2);
        if (grp == 0 && ki < ns) {
            const int j = blks[ki >> 4] * 16 + (ki & 15);
            sc[ki] = (j <= t) ? sum * SCALE : -INFINITY;
        }
    }
    __syncthreads();
    // softmax
    float lm = -INFINITY;
    for (int s = tid; s < ns; s += 256) lm = fmaxf(lm, sc[s]);
#pragma unroll
    for (int off = 32; off; off >>= 1) lm = fmaxf(lm, __shfl_xor(lm, off));
    if (lane == 0) redm[wave] = lm;
    __syncthreads();
    const float mx = fmaxf(fmaxf(redm[0], redm[1]), fmaxf(redm[2], redm[3]));
    float ls = 0.f;
    for (int s = tid; s < ns; s += 256) { const float e = __expf(sc[s] - mx); sc[s] = e; ls += e; }
#pragma unroll
    for (int off = 32; off; off >>= 1) ls += __shfl_xor(ls, off);
    if (lane == 0) reds[wave] = ls;
    __syncthreads();
    const float inv = 1.f / (reds[0] + reds[1] + reds[2] + reds[3]);
    // PV from staged v
    const int d = tid & 127, h2 = tid >> 7;
    float o = 0.f;
    for (int c = 0; c < nchunk; ++c) {
        __syncthreads();
#pragma unroll
        for (int u = 0; u < 8; ++u) {
            const int fidx = u * 256 + tid;
            const int row = fidx >> 5, col = (fidx & 31) << 2;
            const int ki = c * CHK + row;
            const int j = (ki < ns) ? blks[ki >> 4] * 16 + (ki & 15) : 0;
            *(float4*)&buf[row][col ^ ((row & 7) << 2)] =
                *(const float4*)(v + ((size_t)h * T_LEN + j) * 128 + col);
        }
        __syncthreads();
#pragma unroll
        for (int r = 0; r < 32; ++r) {
            const int kk = r * 2 + h2, ki = c * CHK + kk;
            if (ki < ns) o += sc[ki] * buf[kk][d ^ ((kk & 7) << 2)];
        }
    }
    __syncthreads();
    ((float*)buf)[h2 * 128 + d] = o;
    __syncthreads();
    if (tid < 128)
        out[((size_t)h * T_LEN + t) * 128 + tid] =
            (((float*)buf)[tid] + ((float*)buf)[128 + tid]) * inv;
}

// ---------------- sliding-window attention ----------------
__global__ __launch_bounds__(256) void slide_att(const float* __restrict__ q,
                                                 const float* __restrict__ k,
                                                 const float* __restrict__ v,
                                                 float* __restrict__ out) {
    const int t = blockIdx.x, h = blockIdx.y, tid = threadIdx.x;
    const int lane = tid & 63, wave = tid >> 6;
    __shared__ float buf[CHK][128];
    __shared__ float qs[128];
    __shared__ float sc[WIN];
    __shared__ float redm[4], reds[4];
    if (tid < 128) qs[tid] = q[((size_t)h * T_LEN + t) * 128 + tid];
    __syncthreads();
    const int j0 = max(0, t - (WIN - 1));
    const int ns = t - j0 + 1;
    const int nchunk = (ns + CHK - 1) / CHK;
    const int grp = tid & 3, keyl = tid >> 2;
    float qreg[32];
#pragma unroll
    for (int u = 0; u < 8; ++u)
        *(float4*)&qreg[u * 4] = *(const float4*)&qs[grp * 32 + u * 4];
    for (int c = 0; c < nchunk; ++c) {
        __syncthreads();
#pragma unroll
        for (int u = 0; u < 8; ++u) {
            const int fidx = u * 256 + tid;
            const int row = fidx >> 5, col = (fidx & 31) << 2;
            const int j = j0 + min(c * CHK + row, ns - 1);
            *(float4*)&buf[row][col ^ ((row & 7) << 2)] =
                *(const float4*)(k + ((size_t)h * T_LEN + j) * 128 + col);
        }
        __syncthreads();
        const int ki = c * CHK + keyl;
        float sum = 0.f;
#pragma unroll
        for (int u = 0; u < 8; ++u) {
            const int cb = grp * 32 + u * 4;
            const float4 kv = *(const float4*)&buf[keyl][cb ^ ((keyl & 7) << 2)];
            sum += kv.x * qreg[u * 4] + kv.y * qreg[u * 4 + 1] +
                   kv.z * qreg[u * 4 + 2] + kv.w * qreg[u * 4 + 3];
        }
        sum += __shfl_xor(sum, 1); sum += __shfl_xor(sum, 2);
        if (grp == 0 && ki < ns) sc[ki] = sum * SCALE;
    }
    __syncthreads();
    float lm = -INFINITY;
    for (int s = tid; s < ns; s += 256) lm = fmaxf(lm, sc[s]);
#pragma unroll
    for (int off = 32; off; off >>= 1) lm = fmaxf(lm, __shfl_xor(lm, off));
    if (lane == 0) redm[wave] = lm;
    __syncthreads();
    const float mx = fmaxf(fmaxf(redm[0], redm[1]), fmaxf(redm[2], redm[3]));
    float ls = 0.f;
    for (int s = tid; s < ns; s += 256) { const float e = __expf(sc[s] - mx); sc[s] = e; ls += e; }
#pragma unroll
    for (int off = 32; off; off >>= 1) ls += __shfl_xor(ls, off);
    if (lane == 0) reds[wave] = ls;
    __syncthreads();
    const float inv = 1.f / (reds[0] + reds[1] + reds[2] + reds[3]);
    const int d = tid & 127, h2 = tid >> 7;
    float o = 0.f;
    for (int c = 0; c < nchunk; ++c) {
        __syncthreads();
#pragma unroll
        for (int u = 0; u < 8; ++u) {
            const int fidx = u * 256 + tid;
            const int row = fidx >> 5, col = (fidx & 31) << 2;
            const int j = j0 + min(c * CHK + row, ns - 1);
            *(float4*)&buf[row][col ^ ((row & 7) << 2)] =
                *(const float4*)(v + ((size_t)h * T_LEN + j) * 128 + col);
        }
        __syncthreads();
#pragma unroll
        for (int r = 0; r < 32; ++r) {
            const int kk = r * 2 + h2, ki = c * CHK + kk;
            if (ki < ns) o += sc[ki] * buf[kk][d ^ ((kk & 7) << 2)];
        }
    }
    __syncthreads();
    ((float*)buf)[h2 * 128 + d] = o;
    __syncthreads();
    if (tid < 128)
        out[((size_t)h * T_LEN + t) * 128 + tid] =
            (((float*)buf)[tid] + ((float*)buf)[128 + tid]) * inv;
}

// ---------------- strategy gates: one block per t, wave per i ----------------
__global__ __launch_bounds__(256) void strat_kern(const float* __restrict__ x,
                                                  const float* __restrict__ w,
                                                  const float* __restrict__ b,
                                                  float* __restrict__ strat) {
    const int t = blockIdx.x, tid = threadIdx.x;
    const int lane = tid & 63, wave = tid >> 6;
    __shared__ float xs[1024];
    for (int c = tid; c < 1024; c += 256) xs[c] = x[(size_t)t * 1024 + c];
    __syncthreads();
    for (int i = wave; i < 24; i += 4) {
        const float* wr = w + (size_t)i * 1024;
        float s = 0.f;
#pragma unroll
        for (int u = 0; u < 4; ++u) {
            const int c = u * 256 + lane * 4;
            const float4 wv = *reinterpret_cast<const float4*>(wr + c);
            const float4 xv = *reinterpret_cast<const float4*>(&xs[c]);
            s += wv.x * xv.x + wv.y * xv.y + wv.z * xv.z + wv.w * xv.w;
        }
#pragma unroll
        for (int off = 32; off; off >>= 1) s += __shfl_xor(s, off);
        if (lane == 0)
            strat[t * 24 + i] = 1.f / (1.f + __expf(-(s + b[i])));
    }
}

// ---------------- combine three attention branches ----------------
__global__ __launch_bounds__(256) void combine_kern(const float* __restrict__ strat,
                                                    const float* __restrict__ comp,
                                                    const float* __restrict__ fine,
                                                    const float* __restrict__ slide,
                                                    float* __restrict__ mix) {
    const int t = blockIdx.x;
    for (int hd = threadIdx.x; hd < 1024; hd += 256) {
        const int h = hd >> 7, d = hd & 127;
        const float* st = strat + t * 24 + h * 3;
        const size_t idx = ((size_t)h * T_LEN + t) * 128 + d;
        mix[(size_t)t * 1024 + hd] = st[0] * comp[idx] + st[1] * fine[idx] + st[2] * slide[idx];
    }
}

extern "C" void kernel_launch(void* const* d_in, const int* in_sizes, int n_in,
                              void* d_out, int out_size, void* d_ws, size_t ws_size,
                              hipStream_t stream) {
    const float* x        = (const float*)d_in[0];
    const float* qkv_w    = (const float*)d_in[1];
    const float* lambdas  = (const float*)d_in[2];
    const float* c_proj_w = (const float*)d_in[3];
    const float* k_fc_w   = (const float*)d_in[4];
    const float* k_pj_w   = (const float*)d_in[5];
    const float* v_fc_w   = (const float*)d_in[6];
    const float* v_pj_w   = (const float*)d_in[7];
    const float* mem_kv   = (const float*)d_in[8];
    const float* k_pos    = (const float*)d_in[9];
    const float* v_pos    = (const float*)d_in[10];
    const float* strat_w  = (const float*)d_in[11];
    const float* strat_b  = (const float*)d_in[12];
    float* out = (float*)d_out;

    char* ws = (char*)d_ws;
    size_t off = 0;
    auto alloc = [&](size_t bytes) -> void* {
        void* p = ws + off;
        off += (bytes + 255) & ~(size_t)255;
        return p;
    };

    // region0: buf_qkv (dead after prep_qkv) -> hidden (dead after pj) -> mix
    char* region0  = (char*)alloc((size_t)1024 * 8192 * 4);
    float* buf_qkv = (float*)region0;
    float* hidden  = (float*)region0;
    float* mix     = (float*)region0;

    float* q     = (float*)alloc((size_t)NHEAD * T_LEN * 128 * 4);
    float* k     = (float*)alloc((size_t)NHEAD * T_LEN * 128 * 4);
    float* v     = (float*)alloc((size_t)NHEAD * T_LEN * 128 * 4);
    float* kc_in = (float*)alloc((size_t)1024 * 2048 * 4);   // dead after fc-k; comp aliases
    float* vc_in = (float*)alloc((size_t)1024 * 2048 * 4);   // dead after fc-v; fine aliases
    float* comp  = kc_in;
    float* fine  = vc_in;
    float* slide = (float*)alloc((size_t)NHEAD * T_LEN * 128 * 4);
    float* ckb   = (float*)alloc((size_t)1024 * 128 * 4);
    float* cvb   = (float*)alloc((size_t)1024 * 128 * 4);
    float* ck    = (float*)alloc((size_t)NHEAD * (NBLK + NMEM) * 128 * 4);
    float* cv    = (float*)alloc((size_t)NHEAD * (NBLK + NMEM) * 128 * 4);
    float* csim  = (float*)alloc((size_t)NHEAD * T_LEN * (NBLK + NMEM) * 4);
    float* imp   = (float*)alloc((size_t)T_LEN * NBLK * 4);
    float* strat = (float*)alloc((size_t)T_LEN * 24 * 4);
    float* partials = (float*)alloc((size_t)8 * 1024 * 128 * 4);   // pj split-K
    unsigned long long* selbits = (unsigned long long*)alloc((size_t)T_LEN * 2 * 8);

    // 1. QKV projection [2048,3072] = x @ qkv_w^T
    gemm_tn128<0><<<dim3(3072 / 128, T_LEN / 128), 256, 0, stream>>>(
        x, qkv_w, buf_qkv, T_LEN, 3072, 1024);

    // 2. rms + rotary + v-scale
    prep_qkv<<<dim3(T_LEN, NHEAD), 128, 0, stream>>>(buf_qkv, lambdas, q, k, v);

    // 3. compress-MLP inputs
    build_cin<<<(NHEAD * NBLK * BS * DHEAD / 4 + 255) / 256, 256, 0, stream>>>(
        k, v, k_pos, v_pos, kc_in, vc_in);

    // 4-7. compress MLPs: fc (128-tile) + pj (split-K 8 + reduce)
    gemm_tn128<1><<<dim3(8192 / 128, 1024 / 128), 256, 0, stream>>>(
        kc_in, k_fc_w, hidden, 1024, 8192, 2048);
    gemm_tn64_splitk<<<dim3(2, 16, 8), 256, 0, stream>>>(
        hidden, k_pj_w, partials, 1024, 128, 8192, 1024);
    reduce8<<<(1024 * 128 + 255) / 256, 256, 0, stream>>>(partials, ckb, 1024 * 128);
    gemm_tn128<1><<<dim3(8192 / 128, 1024 / 128), 256, 0, stream>>>(
        vc_in, v_fc_w, hidden, 1024, 8192, 2048);
    gemm_tn64_splitk<<<dim3(2, 16, 8), 256, 0, stream>>>(
        hidden, v_pj_w, partials, 1024, 128, 8192, 1024);
    reduce8<<<(1024 * 128 + 255) / 256, 256, 0, stream>>>(partials, cvb, 1024 * 128);

    // 8. assemble ck/cv
    scatter_ckcv<<<(NHEAD * (NBLK + NMEM) * DHEAD + 255) / 256, 256, 0, stream>>>(
        ckb, cvb, mem_kv, ck, cv);

    // 9+10. fused compressed attention (writes csim + comp)
    comp_att<<<dim3(T_LEN, NHEAD), 256, 0, stream>>>(q, ck, cv, csim, comp);

    // 11+12. importance + top-k
    imp_kern<<<(T_LEN * NBLK + 255) / 256, 256, 0, stream>>>(csim, imp);
    topk_kern<<<(T_LEN + 255) / 256, 256, 0, stream>>>(imp, selbits);

    // 13. fine block-sparse attention
    fine_att<<<dim3(T_LEN, NHEAD), 256, 0, stream>>>(q, k, v, selbits, fine);

    // 14. sliding-window attention
    slide_att<<<dim3(T_LEN, NHEAD), 256, 0, stream>>>(q, k, v, slide);

    // 15. strategy gates
    strat_kern<<<T_LEN, 256, 0, stream>>>(x, strat_w, strat_b, strat);

    // 16. combine
    combine_kern<<<T_LEN, 256, 0, stream>>>(strat, comp, fine, slide, mix);

    // 17. output projection
    gemm_tn128<0><<<dim3(1024 / 128, T_LEN / 128), 256, 0, stream>>>(
        mix, c_proj_w, out, T_LEN, 1024, 1024);
}

// Round 8
// 1697.579 us; speedup vs baseline: 2.8630x; 1.3821x over previous
//
// Round 8 resubmit of round-7 source (round-7 was GPUAcquisitionTimeout —
// no kernel signal; experiment not mutated).
// Round 7: (a) attention kernels -> direct-global 8-thr/key scores, no LDS
// staging (8 blocks/CU, zero score-phase barriers); (b) bf16 MFMA for the
// topk-INSENSITIVE GEMMs only (fc-v, pj-v split-K, c_proj). The topk path
// (qkv, fc-k, pj-k, csim) stays f32: bf16 noise ~0.002 vs rank-16/17 imp
// gaps ~0.03 would flip block selections vs the exact reference.
#include <hip/hip_runtime.h>
#include <hip/hip_bf16.h>

#define T_LEN 2048
#define NHEAD 8
#define DHEAD 128
#define NBLK 128     // W
#define BS 16
#define NSEL 16
#define WIN 128
#define NMEM 1
#define NJ (NBLK + NMEM)   // 129
#define SCALE 0.12f
#define NEG -1e9f

typedef __attribute__((ext_vector_type(8))) short bf16x8;
typedef __attribute__((ext_vector_type(4))) float f32x4;

__device__ __forceinline__ unsigned short bfbits(float x) {
    __hip_bfloat16 h = __float2bfloat16(x);
    return *reinterpret_cast<unsigned short*>(&h);
}
__device__ __forceinline__ void stc(float* p, float v) { *p = v; }
__device__ __forceinline__ void stc(unsigned short* p, float v) { *p = bfbits(v); }

// ---------------- f32 128x128 tiled GEMM (topk-sensitive path) ----------------
template <int EPI>
__global__ __launch_bounds__(256) void gemm_tn128(const float* __restrict__ A,
                                                  const float* __restrict__ B,
                                                  float* __restrict__ C,
                                                  int M, int N, int K) {
    __shared__ float As[16][132];
    __shared__ float Bs[16][132];
    const int bm = blockIdx.y * 128, bn = blockIdx.x * 128;
    const int tid = threadIdx.x;
    const int tx = tid & 15, ty = tid >> 4;
    const int lrow = tid >> 2, lcol = (tid & 3) << 2;
    float acc[8][8] = {};
    for (int kt = 0; kt < K; kt += 16) {
#pragma unroll
        for (int u = 0; u < 2; ++u) {
            const int r = lrow + u * 64;
            const float4 a4 = *(const float4*)(A + (size_t)(bm + r) * K + kt + lcol);
            const float4 b4 = *(const float4*)(B + (size_t)(bn + r) * K + kt + lcol);
            As[lcol + 0][r] = a4.x; As[lcol + 1][r] = a4.y;
            As[lcol + 2][r] = a4.z; As[lcol + 3][r] = a4.w;
            Bs[lcol + 0][r] = b4.x; Bs[lcol + 1][r] = b4.y;
            Bs[lcol + 2][r] = b4.z; Bs[lcol + 3][r] = b4.w;
        }
        __syncthreads();
#pragma unroll
        for (int kk = 0; kk < 16; ++kk) {
            float av[8], bv[8];
            *(float4*)&av[0] = *(const float4*)&As[kk][ty * 8];
            *(float4*)&av[4] = *(const float4*)&As[kk][ty * 8 + 4];
            *(float4*)&bv[0] = *(const float4*)&Bs[kk][tx * 8];
            *(float4*)&bv[4] = *(const float4*)&Bs[kk][tx * 8 + 4];
#pragma unroll
            for (int i = 0; i < 8; ++i)
#pragma unroll
                for (int j = 0; j < 8; ++j)
                    acc[i][j] += av[i] * bv[j];
        }
        __syncthreads();
    }
#pragma unroll
    for (int i = 0; i < 8; ++i) {
        float o[8];
#pragma unroll
        for (int j = 0; j < 8; ++j) {
            float v = acc[i][j];
            if (EPI == 1) { v = v > 0.f ? v : 0.f; v = v * v; }
            o[j] = v;
        }
        float* cp = &C[(size_t)(bm + ty * 8 + i) * N + bn + tx * 8];
        *(float4*)cp = *(float4*)&o[0];
        *(float4*)(cp + 4) = *(float4*)&o[4];
    }
}

// ---------------- f32 64x64 split-K GEMM (pj-k) ----------------
__global__ __launch_bounds__(256) void gemm_tn64_splitk(const float* __restrict__ A,
                                                        const float* __restrict__ B,
                                                        float* __restrict__ P,
                                                        int M, int N, int K, int KC) {
    __shared__ float As[16][68];
    __shared__ float Bs[16][68];
    const int bm = blockIdx.y * 64, bn = blockIdx.x * 64;
    const int k0 = blockIdx.z * KC, k1 = k0 + KC;
    const int tid = threadIdx.x;
    const int tx = tid & 15, ty = tid >> 4;
    const int lr = tid >> 2, lc = (tid & 3) << 2;
    float acc[4][4] = {};
    const float* pa = A + (size_t)(bm + lr) * K + lc;
    const float* pb = B + (size_t)(bn + lr) * K + lc;
    for (int kt = k0; kt < k1; kt += 16) {
        const float4 a4 = *(const float4*)(pa + kt);
        const float4 b4 = *(const float4*)(pb + kt);
        As[lc + 0][lr] = a4.x; As[lc + 1][lr] = a4.y;
        As[lc + 2][lr] = a4.z; As[lc + 3][lr] = a4.w;
        Bs[lc + 0][lr] = b4.x; Bs[lc + 1][lr] = b4.y;
        Bs[lc + 2][lr] = b4.z; Bs[lc + 3][lr] = b4.w;
        __syncthreads();
#pragma unroll
        for (int kk = 0; kk < 16; ++kk) {
            const float4 av = *(const float4*)&As[kk][ty * 4];
            const float4 bv = *(const float4*)&Bs[kk][tx * 4];
            acc[0][0] += av.x * bv.x; acc[0][1] += av.x * bv.y; acc[0][2] += av.x * bv.z; acc[0][3] += av.x * bv.w;
            acc[1][0] += av.y * bv.x; acc[1][1] += av.y * bv.y; acc[1][2] += av.y * bv.z; acc[1][3] += av.y * bv.w;
            acc[2][0] += av.z * bv.x; acc[2][1] += av.z * bv.y; acc[2][2] += av.z * bv.z; acc[2][3] += av.z * bv.w;
            acc[3][0] += av.w * bv.x; acc[3][1] += av.w * bv.y; acc[3][2] += av.w * bv.z; acc[3][3] += av.w * bv.w;
        }
        __syncthreads();
    }
    float* Pz = P + (size_t)blockIdx.z * M * N;
#pragma unroll
    for (int i = 0; i < 4; ++i) {
        float4 o = make_float4(acc[i][0], acc[i][1], acc[i][2], acc[i][3]);
        *(float4*)&Pz[(size_t)(bm + ty * 4 + i) * N + bn + tx * 4] = o;
    }
}

__global__ void reduce8(const float* __restrict__ P, float* __restrict__ C, int MN) {
    const int idx = blockIdx.x * 256 + threadIdx.x;
    if (idx >= MN) return;
    float s = 0.f;
#pragma unroll
    for (int z = 0; z < 8; ++z) s += P[(size_t)z * MN + idx];
    C[idx] = s;
}

// ---------------- bf16 MFMA GEMM: C[m,n]=sum_k A[m,k]B[n,k] ----------------
// 128x128 tile, BK=32, 4 waves (2x2 of 64x64), mfma_f32_16x16x32_bf16.
// A/B frag: lane l -> row (l&15), k-offset (l>>4)*8 (16B contiguous).
// C/D: col=lane&15, row=(lane>>4)*4+r (m89-verified). blockIdx.z = split-K.
template <int EPI, typename OUT_T>
__global__ __launch_bounds__(256) void gemm_mfma(const unsigned short* __restrict__ A,
                                                 const unsigned short* __restrict__ B,
                                                 OUT_T* __restrict__ C,
                                                 int M, int N, int K, int KS) {
    __shared__ short As[128][32];
    __shared__ short Bs[128][32];
    const int bm = blockIdx.y * 128, bn = blockIdx.x * 128;
    const int k0 = blockIdx.z * KS;
    const int tid = threadIdx.x;
    const int lane = tid & 63, wave = tid >> 6;
    const int wm = (wave >> 1) * 64, wn = (wave & 1) * 64;
    const int l16 = lane & 15, lq = lane >> 4;
    f32x4 acc[4][4];
#pragma unroll
    for (int i = 0; i < 4; ++i)
#pragma unroll
        for (int j = 0; j < 4; ++j) acc[i][j] = (f32x4){0.f, 0.f, 0.f, 0.f};

    const int srow = tid >> 1;            // 0..127
    const int skq = (tid & 1) * 16;       // bf16 offset 0 / 16
    for (int kt = k0; kt < k0 + KS; kt += 32) {
        __syncthreads();
        const unsigned short* ga = A + (size_t)(bm + srow) * K + kt + skq;
        const unsigned short* gb = B + (size_t)(bn + srow) * K + kt + skq;
        const float4 a0 = *(const float4*)ga;
        const float4 a1 = *(const float4*)(ga + 8);
        const float4 b0 = *(const float4*)gb;
        const float4 b1 = *(const float4*)(gb + 8);
        *(float4*)&As[srow][skq] = a0;
        *(float4*)&As[srow][skq + 8] = a1;
        *(float4*)&Bs[srow][skq] = b0;
        *(float4*)&Bs[srow][skq + 8] = b1;
        __syncthreads();
        bf16x8 af[4], bfr[4];
#pragma unroll
        for (int i = 0; i < 4; ++i) {
            af[i]  = *(bf16x8*)&As[wm + i * 16 + l16][lq * 8];
            bfr[i] = *(bf16x8*)&Bs[wn + i * 16 + l16][lq * 8];
        }
#pragma unroll
        for (int i = 0; i < 4; ++i)
#pragma unroll
            for (int j = 0; j < 4; ++j)
                acc[i][j] = __builtin_amdgcn_mfma_f32_16x16x32_bf16(af[i], bfr[j], acc[i][j], 0, 0, 0);
    }
    OUT_T* Cz = C + (size_t)blockIdx.z * M * N;
#pragma unroll
    for (int i = 0; i < 4; ++i)
#pragma unroll
        for (int j = 0; j < 4; ++j)
#pragma unroll
            for (int r = 0; r < 4; ++r) {
                float vv = acc[i][j][r];
                if (EPI == 1) { vv = vv > 0.f ? vv : 0.f; vv = vv * vv; }
                const int row = bm + wm + i * 16 + lq * 4 + r;
                const int col = bn + wn + j * 16 + l16;
                stc(&Cz[(size_t)row * N + col], vv);
            }
}

// ---------------- f32 -> bf16 cast ----------------
__global__ void cast_bf16(const float* __restrict__ src, unsigned short* __restrict__ dst, int n4) {
    const int i = blockIdx.x * 256 + threadIdx.x;
    if (i >= n4) return;
    const float4 v = ((const float4*)src)[i];
    ushort4 o;
    o.x = bfbits(v.x); o.y = bfbits(v.y); o.z = bfbits(v.z); o.w = bfbits(v.w);
    ((ushort4*)dst)[i] = o;
}

// ---------------- per-(h,t): rms-norm q,k; rotary; scale v ----------------
__global__ __launch_bounds__(128) void prep_qkv(const float* __restrict__ qkvbuf,
                                                const float* __restrict__ lambdas,
                                                float* __restrict__ q, float* __restrict__ k,
                                                float* __restrict__ v) {
    const int t = blockIdx.x, h = blockIdx.y, d = threadIdx.x;
    const int lane = d & 63, wave = d >> 6;
    __shared__ float sq[128], sk[128];
    __shared__ float r2[4];
    const float* row = qkvbuf + (size_t)t * 3072 + h * 128;
    const float qv = row[d], kv = row[1024 + d], vv = row[2048 + d];

    float s2q = qv * qv, s2k = kv * kv;
#pragma unroll
    for (int off = 32; off; off >>= 1) {
        s2q += __shfl_xor(s2q, off);
        s2k += __shfl_xor(s2k, off);
    }
    if (lane == 0) { r2[wave] = s2q; r2[2 + wave] = s2k; }
    __syncthreads();
    const float qr = rsqrtf((r2[0] + r2[1]) / 128.f + 1e-6f);
    const float kr = rsqrtf((r2[2] + r2[3]) / 128.f + 1e-6f);
    sq[d] = qv * qr; sk[d] = kv * kr;
    __syncthreads();

    const int j = d & 63;
    const float ang = (j < 32) ? powf(1.0f / 1024.0f, (float)j / 31.0f) : 0.0f;
    const float th = ang * (float)t;
    const float c = cosf(th), s = sinf(th);
    float qo, ko;
    if (d < 64) { qo = sq[d] * c + sq[d + 64] * s; ko = sk[d] * c + sk[d + 64] * s; }
    else        { qo = -sq[d - 64] * s + sq[d] * c; ko = -sk[d - 64] * s + sk[d] * c; }

    const size_t idx = ((size_t)h * T_LEN + t) * 128 + d;
    q[idx] = qo;
    k[idx] = ko;
    v[idx] = lambdas[0] * vv;
}

// ---------------- build compress-MLP inputs: kc f32, vc bf16 ----------------
__global__ void build_cin(const float* __restrict__ k, const float* __restrict__ v,
                          const float* __restrict__ kpos, const float* __restrict__ vpos,
                          float* __restrict__ kc, unsigned short* __restrict__ vc) {
    const int idx = blockIdx.x * 256 + threadIdx.x;   // float4 index
    if (idx >= NHEAD * NBLK * BS * DHEAD / 4) return;
    const int d4 = idx & 31, i = (idx >> 5) & 15, w = (idx >> 9) & 127, h = idx >> 16;
    const int t = w * 16 + i;
    const size_t src = (((size_t)h * T_LEN + t) * 128 + d4 * 4) / 4;
    const int pos = ((h * 16 + i) * 128 + d4 * 4) / 4;
    const float4 kv = reinterpret_cast<const float4*>(k)[src];
    const float4 vv = reinterpret_cast<const float4*>(v)[src];
    const float4 kp = reinterpret_cast<const float4*>(kpos)[pos];
    const float4 vp = reinterpret_cast<const float4*>(vpos)[pos];
    reinterpret_cast<float4*>(kc)[idx] = make_float4(kv.x + kp.x, kv.y + kp.y, kv.z + kp.z, kv.w + kp.w);
    ushort4 o;
    o.x = bfbits(vv.x + vp.x); o.y = bfbits(vv.y + vp.y);
    o.z = bfbits(vv.z + vp.z); o.w = bfbits(vv.w + vp.w);
    ((ushort4*)vc)[idx] = o;
}

// ---------------- assemble ck/cv with mem slot ----------------
__global__ void scatter_ckcv(const float* __restrict__ ckb, const float* __restrict__ cvb,
                             const float* __restrict__ memkv,
                             float* __restrict__ ck, float* __restrict__ cv) {
    int idx = blockIdx.x * 256 + threadIdx.x;
    if (idx >= NHEAD * NJ * DHEAD) return;
    const int d = idx & 127;
    const int j = (idx >> 7) % NJ;
    const int h = idx / (NJ * DHEAD);
    if (j == 0) {
        ck[idx] = memkv[h * 128 + d];
        cv[idx] = memkv[NHEAD * 128 + h * 128 + d];
    } else {
        const size_t b = ((size_t)h * NBLK + (j - 1)) * 128 + d;
        ck[idx] = ckb[b];
        cv[idx] = cvb[b];
    }
}

// ============ attention: direct-global 8-thr/key scores, global PV ============

// ---------------- fused compressed attention (writes csim f32 + comp) --------
__global__ __launch_bounds__(256) void comp_att(const float* __restrict__ q,
                                                const float* __restrict__ ck,
                                                const float* __restrict__ cv,
                                                float* __restrict__ csim,
                                                float* __restrict__ out) {
    const int t = blockIdx.x, h = blockIdx.y, tid = threadIdx.x;
    const int lane = tid & 63, wave = tid >> 6;
    __shared__ float qs[128];
    __shared__ float sc[NJ];
    __shared__ float red[4];
    __shared__ float pvb[256];
    if (tid < 128) qs[tid] = q[((size_t)h * T_LEN + t) * 128 + tid];
    __syncthreads();
    const int grp = tid & 7, key0 = tid >> 3;   // 32 key-threads x 8
    float qreg[16];
#pragma unroll
    for (int u = 0; u < 4; ++u)
        *(float4*)&qreg[u * 4] = *(const float4*)&qs[grp * 16 + u * 4];
    const int smax = t >> 4;
    for (int s = key0; s < NJ; s += 32) {
        float sum = 0.f;
        if (s <= smax) {
            const float* kr = ck + ((size_t)h * NJ + s) * 128 + grp * 16;
#pragma unroll
            for (int u = 0; u < 4; ++u) {
                const float4 kv = *(const float4*)(kr + u * 4);
                sum += kv.x * qreg[u * 4] + kv.y * qreg[u * 4 + 1] +
                       kv.z * qreg[u * 4 + 2] + kv.w * qreg[u * 4 + 3];
            }
        }
        sum += __shfl_xor(sum, 1); sum += __shfl_xor(sum, 2); sum += __shfl_xor(sum, 4);
        if (grp == 0) {
            const float val = (s <= smax) ? sum * SCALE : NEG;
            sc[s] = val;
            csim[((size_t)h * T_LEN + t) * NJ + s] = val;
        }
    }
    __syncthreads();
    // softmax over 129
    float lm = (tid < NJ) ? sc[tid] : -INFINITY;
#pragma unroll
    for (int off = 32; off; off >>= 1) lm = fmaxf(lm, __shfl_xor(lm, off));
    if (lane == 0) red[wave] = lm;
    __syncthreads();
    const float mx = fmaxf(fmaxf(red[0], red[1]), fmaxf(red[2], red[3]));
    __syncthreads();
    float e = 0.f;
    if (tid < NJ) { e = __expf(sc[tid] - mx); sc[tid] = e; }
#pragma unroll
    for (int off = 32; off; off >>= 1) e += __shfl_xor(e, off);
    if (lane == 0) red[wave] = e;
    __syncthreads();
    const float inv = 1.f / (red[0] + red[1] + red[2] + red[3]);
    // PV from global cv (coalesced across d)
    const int d = tid & 127, h2 = tid >> 7;
    float o = 0.f;
    for (int s = h2; s < NJ; s += 2)
        o += sc[s] * cv[((size_t)h * NJ + s) * 128 + d];
    pvb[tid] = o;
    __syncthreads();
    if (tid < 128)
        out[((size_t)h * T_LEN + t) * 128 + tid] = (pvb[tid] + pvb[tid + 128]) * inv;
}

// ---------------- importance: mean over heads of csim[...,1:] ----------------
__global__ void imp_kern(const float* __restrict__ csim, float* __restrict__ imp) {
    int idx = blockIdx.x * 256 + threadIdx.x;
    if (idx >= T_LEN * NBLK) return;
    const int w = idx & 127, t = idx >> 7;
    float s = 0.f;
    for (int h = 0; h < NHEAD; ++h)
        s += csim[((size_t)h * T_LEN + t) * NJ + 1 + w];
    imp[idx] = s * 0.125f;
}

// ---------------- top-16 block selection per t ----------------
__global__ void topk_kern(const float* __restrict__ imp, unsigned long long* __restrict__ selbits) {
    const int t = blockIdx.x * blockDim.x + threadIdx.x;
    if (t >= T_LEN) return;
    const float* row = imp + (size_t)t * NBLK;
    unsigned long long b0 = 0, b1 = 0;
    for (int s = 0; s < NSEL; ++s) {
        float best = -INFINITY; int bi = 0;
        for (int w = 0; w < NBLK; ++w) {
            const bool used = (w < 64) ? ((b0 >> w) & 1ull) : ((b1 >> (w - 64)) & 1ull);
            const float vv = row[w];
            if (!used && vv > best) { best = vv; bi = w; }
        }
        if (bi < 64) b0 |= 1ull << bi; else b1 |= 1ull << (bi - 64);
    }
    selbits[2 * t] = b0; selbits[2 * t + 1] = b1;
}

// ---------------- fine block-sparse attention ----------------
__global__ __launch_bounds__(256) void fine_att(const float* __restrict__ q,
                                                const float* __restrict__ k,
                                                const float* __restrict__ v,
                                                const unsigned long long* __restrict__ selbits,
                                                float* __restrict__ out) {
    const int t = blockIdx.x, h = blockIdx.y, tid = threadIdx.x;
    const int lane = tid & 63, wave = tid >> 6;
    __shared__ float qs[128];
    __shared__ float sc[17 * 16];
    __shared__ int blks[17];
    __shared__ int nb_s;
    __shared__ float red[4];
    __shared__ float pvb[256];
    if (tid < 128) qs[tid] = q[((size_t)h * T_LEN + t) * 128 + tid];
    if (tid == 0) {
        unsigned long long b0 = selbits[2 * t], b1 = selbits[2 * t + 1];
        const int cur = t >> 4;
        const bool curin = (cur < 64) ? ((b0 >> cur) & 1ull) : ((b1 >> (cur - 64)) & 1ull);
        int nb = 0;
        while (b0) { const int w = __ffsll(b0) - 1; b0 &= b0 - 1; blks[nb++] = w; }
        while (b1) { const int w = __ffsll(b1) - 1; b1 &= b1 - 1; blks[nb++] = w + 64; }
        if (!curin) blks[nb++] = cur;
        nb_s = nb;
    }
    __syncthreads();
    const int ns = nb_s * 16;
    const int grp = tid & 7, key0 = tid >> 3;
    float qreg[16];
#pragma unroll
    for (int u = 0; u < 4; ++u)
        *(float4*)&qreg[u * 4] = *(const float4*)&qs[grp * 16 + u * 4];
    // scores: no barriers, direct global K
    for (int s = key0; s < ns; s += 32) {
        const int j = blks[s >> 4] * 16 + (s & 15);
        float sum = 0.f;
        if (j <= t) {
            const float* kr = k + ((size_t)h * T_LEN + j) * 128 + grp * 16;
#pragma unroll
            for (int u = 0; u < 4; ++u) {
                const float4 kv = *(const float4*)(kr + u * 4);
                sum += kv.x * qreg[u * 4] + kv.y * qreg[u * 4 + 1] +
                       kv.z * qreg[u * 4 + 2] + kv.w * qreg[u * 4 + 3];
            }
        }
        sum += __shfl_xor(sum, 1); sum += __shfl_xor(sum, 2); sum += __shfl_xor(sum, 4);
        if (grp == 0) sc[s] = (j <= t) ? sum * SCALE : -INFINITY;
    }
    __syncthreads();
    // softmax
    float lm = -INFINITY;
    for (int s = tid; s < ns; s += 256) lm = fmaxf(lm, sc[s]);
#pragma unroll
    for (int off = 32; off; off >>= 1) lm = fmaxf(lm, __shfl_xor(lm, off));
    if (lane == 0) red[wave] = lm;
    __syncthreads();
    const float mx = fmaxf(fmaxf(red[0], red[1]), fmaxf(red[2], red[3]));
    __syncthreads();
    float ls = 0.f;
    for (int s = tid; s < ns; s += 256) { const float e = __expf(sc[s] - mx); sc[s] = e; ls += e; }
#pragma unroll
    for (int off = 32; off; off >>= 1) ls += __shfl_xor(ls, off);
    if (lane == 0) red[wave] = ls;
    __syncthreads();
    const float inv = 1.f / (red[0] + red[1] + red[2] + red[3]);
    // PV from global v
    const int d = tid & 127, h2 = tid >> 7;
    float o = 0.f;
    for (int s = h2; s < ns; s += 2) {
        const int j = blks[s >> 4] * 16 + (s & 15);
        o += sc[s] * v[((size_t)h * T_LEN + j) * 128 + d];
    }
    pvb[tid] = o;
    __syncthreads();
    if (tid < 128)
        out[((size_t)h * T_LEN + t) * 128 + tid] = (pvb[tid] + pvb[tid + 128]) * inv;
}

// ---------------- sliding-window attention ----------------
__global__ __launch_bounds__(256) void slide_att(const float* __restrict__ q,
                                                 const float* __restrict__ k,
                                                 const float* __restrict__ v,
                                                 float* __restrict__ out) {
    const int t = blockIdx.x, h = blockIdx.y, tid = threadIdx.x;
    const int lane = tid & 63, wave = tid >> 6;
    __shared__ float qs[128];
    __shared__ float sc[WIN];
    __shared__ float red[4];
    __shared__ float pvb[256];
    if (tid < 128) qs[tid] = q[((size_t)h * T_LEN + t) * 128 + tid];
    __syncthreads();
    const int j0 = max(0, t - (WIN - 1));
    const int ns = t - j0 + 1;
    const int grp = tid & 7, key0 = tid >> 3;
    float qreg[16];
#pragma unroll
    for (int u = 0; u < 4; ++u)
        *(float4*)&qreg[u * 4] = *(const float4*)&qs[grp * 16 + u * 4];
    for (int s = key0; s < ns; s += 32) {
        const float* kr = k + ((size_t)h * T_LEN + j0 + s) * 128 + grp * 16;
        float sum = 0.f;
#pragma unroll
        for (int u = 0; u < 4; ++u) {
            const float4 kv = *(const float4*)(kr + u * 4);
            sum += kv.x * qreg[u * 4] + kv.y * qreg[u * 4 + 1] +
                   kv.z * qreg[u * 4 + 2] + kv.w * qreg[u * 4 + 3];
        }
        sum += __shfl_xor(sum, 1); sum += __shfl_xor(sum, 2); sum += __shfl_xor(sum, 4);
        if (grp == 0) sc[s] = sum * SCALE;
    }
    __syncthreads();
    float lm = (tid < ns) ? sc[tid] : -INFINITY;
#pragma unroll
    for (int off = 32; off; off >>= 1) lm = fmaxf(lm, __shfl_xor(lm, off));
    if (lane == 0) red[wave] = lm;
    __syncthreads();
    const float mx = fmaxf(fmaxf(red[0], red[1]), fmaxf(red[2], red[3]));
    __syncthreads();
    float e = 0.f;
    if (tid < ns) { e = __expf(sc[tid] - mx); sc[tid] = e; }
#pragma unroll
    for (int off = 32; off; off >>= 1) e += __shfl_xor(e, off);
    if (lane == 0) red[wave] = e;
    __syncthreads();
    const float inv = 1.f / (red[0] + red[1] + red[2] + red[3]);
    const int d = tid & 127, h2 = tid >> 7;
    float o = 0.f;
    for (int s = h2; s < ns; s += 2)
        o += sc[s] * v[((size_t)h * T_LEN + j0 + s) * 128 + d];
    pvb[tid] = o;
    __syncthreads();
    if (tid < 128)
        out[((size_t)h * T_LEN + t) * 128 + tid] = (pvb[tid] + pvb[tid + 128]) * inv;
}

// ---------------- strategy gates ----------------
__global__ __launch_bounds__(256) void strat_kern(const float* __restrict__ x,
                                                  const float* __restrict__ w,
                                                  const float* __restrict__ b,
                                                  float* __restrict__ strat) {
    const int t = blockIdx.x, tid = threadIdx.x;
    const int lane = tid & 63, wave = tid >> 6;
    __shared__ float xs[1024];
    for (int c = tid; c < 1024; c += 256) xs[c] = x[(size_t)t * 1024 + c];
    __syncthreads();
    for (int i = wave; i < 24; i += 4) {
        const float* wr = w + (size_t)i * 1024;
        float s = 0.f;
#pragma unroll
        for (int u = 0; u < 4; ++u) {
            const int c = u * 256 + lane * 4;
            const float4 wv = *reinterpret_cast<const float4*>(wr + c);
            const float4 xv = *reinterpret_cast<const float4*>(&xs[c]);
            s += wv.x * xv.x + wv.y * xv.y + wv.z * xv.z + wv.w * xv.w;
        }
#pragma unroll
        for (int off = 32; off; off >>= 1) s += __shfl_xor(s, off);
        if (lane == 0)
            strat[t * 24 + i] = 1.f / (1.f + __expf(-(s + b[i])));
    }
}

// ---------------- combine -> bf16 mix ----------------
__global__ __launch_bounds__(256) void combine_kern(const float* __restrict__ strat,
                                                    const float* __restrict__ comp,
                                                    const float* __restrict__ fine,
                                                    const float* __restrict__ slide,
                                                    unsigned short* __restrict__ mixb) {
    const int t = blockIdx.x, tid = threadIdx.x;
    const int hh = tid >> 5, d0 = (tid & 31) * 4;
    const float* st = strat + t * 24 + hh * 3;
    const size_t idx = (((size_t)hh * T_LEN + t) * 128 + d0) / 4;
    const float4 c4 = ((const float4*)comp)[idx];
    const float4 f4 = ((const float4*)fine)[idx];
    const float4 s4 = ((const float4*)slide)[idx];
    ushort4 o;
    o.x = bfbits(st[0] * c4.x + st[1] * f4.x + st[2] * s4.x);
    o.y = bfbits(st[0] * c4.y + st[1] * f4.y + st[2] * s4.y);
    o.z = bfbits(st[0] * c4.z + st[1] * f4.z + st[2] * s4.z);
    o.w = bfbits(st[0] * c4.w + st[1] * f4.w + st[2] * s4.w);
    ((ushort4*)mixb)[(size_t)t * 256 + tid] = o;
}

extern "C" void kernel_launch(void* const* d_in, const int* in_sizes, int n_in,
                              void* d_out, int out_size, void* d_ws, size_t ws_size,
                              hipStream_t stream) {
    const float* x        = (const float*)d_in[0];
    const float* qkv_w    = (const float*)d_in[1];
    const float* lambdas  = (const float*)d_in[2];
    const float* c_proj_w = (const float*)d_in[3];
    const float* k_fc_w   = (const float*)d_in[4];
    const float* k_pj_w   = (const float*)d_in[5];
    const float* v_fc_w   = (const float*)d_in[6];
    const float* v_pj_w   = (const float*)d_in[7];
    const float* mem_kv   = (const float*)d_in[8];
    const float* k_pos    = (const float*)d_in[9];
    const float* v_pos    = (const float*)d_in[10];
    const float* strat_w  = (const float*)d_in[11];
    const float* strat_b  = (const float*)d_in[12];
    float* out = (float*)d_out;

    char* ws = (char*)d_ws;
    size_t off = 0;
    auto alloc = [&](size_t bytes) -> void* {
        void* p = ws + off;
        off += (bytes + 255) & ~(size_t)255;
        return p;
    };

    // region0 (33.6MB): buf_qkv f32 -> hidden_k f32 -> hidden_v bf16 -> mix bf16
    char* region0   = (char*)alloc((size_t)1024 * 8192 * 4);
    float* buf_qkv  = (float*)region0;
    float* hidden_k = (float*)region0;
    unsigned short* hidden_v = (unsigned short*)region0;
    unsigned short* mixb     = (unsigned short*)region0;

    float* q     = (float*)alloc((size_t)NHEAD * T_LEN * 128 * 4);
    float* k     = (float*)alloc((size_t)NHEAD * T_LEN * 128 * 4);
    float* v     = (float*)alloc((size_t)NHEAD * T_LEN * 128 * 4);
    float* kc_in = (float*)alloc((size_t)1024 * 2048 * 4);     // dead after fc-k; comp aliases
    float* comp  = kc_in;
    unsigned short* vc_in = (unsigned short*)alloc((size_t)1024 * 2048 * 2);
    float* fine  = (float*)alloc((size_t)NHEAD * T_LEN * 128 * 4);
    float* slide = (float*)alloc((size_t)NHEAD * T_LEN * 128 * 4);
    float* ckb   = (float*)alloc((size_t)1024 * 128 * 4);
    float* cvb   = (float*)alloc((size_t)1024 * 128 * 4);
    float* ck    = (float*)alloc((size_t)NHEAD * NJ * 128 * 4);
    float* cv    = (float*)alloc((size_t)NHEAD * NJ * 128 * 4);
    float* csim  = (float*)alloc((size_t)NHEAD * T_LEN * NJ * 4);
    float* imp   = (float*)alloc((size_t)T_LEN * NBLK * 4);
    float* strat = (float*)alloc((size_t)T_LEN * 24 * 4);
    float* partials = (float*)alloc((size_t)8 * 1024 * 128 * 4);
    unsigned long long* selbits = (unsigned long long*)alloc((size_t)T_LEN * 2 * 8);
    unsigned short* wfc_b = (unsigned short*)alloc((size_t)8192 * 2048 * 2);
    unsigned short* wpj_b = (unsigned short*)alloc((size_t)128 * 8192 * 2);
    unsigned short* wcp_b = (unsigned short*)alloc((size_t)1024 * 1024 * 2);

    // 0. weight casts (v-branch + c_proj only)
    cast_bf16<<<(8192 * 2048 / 4 + 255) / 256, 256, 0, stream>>>(v_fc_w, wfc_b, 8192 * 2048 / 4);
    cast_bf16<<<(128 * 8192 / 4 + 255) / 256, 256, 0, stream>>>(v_pj_w, wpj_b, 128 * 8192 / 4);
    cast_bf16<<<(1024 * 1024 / 4 + 255) / 256, 256, 0, stream>>>(c_proj_w, wcp_b, 1024 * 1024 / 4);

    // 1. QKV projection (f32 — topk-sensitive)
    gemm_tn128<0><<<dim3(3072 / 128, T_LEN / 128), 256, 0, stream>>>(
        x, qkv_w, buf_qkv, T_LEN, 3072, 1024);

    // 2. rms + rotary + v-scale
    prep_qkv<<<dim3(T_LEN, NHEAD), 128, 0, stream>>>(buf_qkv, lambdas, q, k, v);

    // 3. compress-MLP inputs (kc f32, vc bf16)
    build_cin<<<(NHEAD * NBLK * BS * DHEAD / 4 + 255) / 256, 256, 0, stream>>>(
        k, v, k_pos, v_pos, kc_in, vc_in);

    // 4-5. k-branch MLP (f32 — topk-sensitive)
    gemm_tn128<1><<<dim3(8192 / 128, 1024 / 128), 256, 0, stream>>>(
        kc_in, k_fc_w, hidden_k, 1024, 8192, 2048);
    gemm_tn64_splitk<<<dim3(2, 16, 8), 256, 0, stream>>>(
        hidden_k, k_pj_w, partials, 1024, 128, 8192, 1024);
    reduce8<<<(1024 * 128 + 255) / 256, 256, 0, stream>>>(partials, ckb, 1024 * 128);

    // 6-7. v-branch MLP (bf16 MFMA — tolerant)
    gemm_mfma<1, unsigned short><<<dim3(8192 / 128, 1024 / 128, 1), 256, 0, stream>>>(
        vc_in, wfc_b, hidden_v, 1024, 8192, 2048, 2048);
    gemm_mfma<0, float><<<dim3(1, 1024 / 128, 8), 256, 0, stream>>>(
        hidden_v, wpj_b, partials, 1024, 128, 8192, 1024);
    reduce8<<<(1024 * 128 + 255) / 256, 256, 0, stream>>>(partials, cvb, 1024 * 128);

    // 8. assemble ck/cv
    scatter_ckcv<<<(NHEAD * NJ * DHEAD + 255) / 256, 256, 0, stream>>>(
        ckb, cvb, mem_kv, ck, cv);

    // 9+10. fused compressed attention (csim f32 + comp)
    comp_att<<<dim3(T_LEN, NHEAD), 256, 0, stream>>>(q, ck, cv, csim, comp);

    // 11+12. importance + top-k
    imp_kern<<<(T_LEN * NBLK + 255) / 256, 256, 0, stream>>>(csim, imp);
    topk_kern<<<(T_LEN + 255) / 256, 256, 0, stream>>>(imp, selbits);

    // 13. fine block-sparse attention
    fine_att<<<dim3(T_LEN, NHEAD), 256, 0, stream>>>(q, k, v, selbits, fine);

    // 14. sliding-window attention
    slide_att<<<dim3(T_LEN, NHEAD), 256, 0, stream>>>(q, k, v, slide);

    // 15. strategy gates
    strat_kern<<<T_LEN, 256, 0, stream>>>(x, strat_w, strat_b, strat);

    // 16. combine -> bf16 mix
    combine_kern<<<T_LEN, 256, 0, stream>>>(strat, comp, fine, slide, mixb);

    // 17. output projection (bf16 MFMA)
    gemm_mfma<0, float><<<dim3(1024 / 128, T_LEN / 128, 1), 256, 0, stream>>>(
        mixb, wcp_b, out, T_LEN, 1024, 1024, 1024);
}

// Round 9
// 1263.152 us; speedup vs baseline: 3.8476x; 1.3439x over previous
//
// Round 9: k-branch (qkv, fc-k, pj-k) -> bf16x3 "split-bf16" MFMA
// (A ~= Ah+Al, B ~= Bh+Bl; AhBh+AhBl+AlBh, f32 accum; rel err ~3e-5 so
// top-k ranking is preserved exactly vs f32 gaps ~1e-2). Padded LDS rows
// (40 shorts) kill the stride-64B bank alias. v-branch/c_proj stay plain
// bf16 MFMA (round-8 verified). Attention kernels unchanged (round-8).
#include <hip/hip_runtime.h>
#include <hip/hip_bf16.h>

#define T_LEN 2048
#define NHEAD 8
#define DHEAD 128
#define NBLK 128     // W
#define BS 16
#define NSEL 16
#define WIN 128
#define NMEM 1
#define NJ (NBLK + NMEM)   // 129
#define SCALE 0.12f
#define NEG -1e9f

typedef __attribute__((ext_vector_type(8))) short bf16x8;
typedef __attribute__((ext_vector_type(4))) float f32x4;

__device__ __forceinline__ unsigned short bfbits(float x) {
    __hip_bfloat16 h = __float2bfloat16(x);
    return *reinterpret_cast<unsigned short*>(&h);
}
__device__ __forceinline__ float bf2f(unsigned short h) {
    return __uint_as_float(((unsigned)h) << 16);
}
__device__ __forceinline__ void stc(float* p, float v) { *p = v; }
__device__ __forceinline__ void stc(unsigned short* p, float v) { *p = bfbits(v); }

// ---------------- f32 -> (hi, lo) bf16 split ----------------
__global__ void split_pair(const float* __restrict__ src, unsigned short* __restrict__ hi,
                           unsigned short* __restrict__ lo, int n4) {
    const int i = blockIdx.x * 256 + threadIdx.x;
    if (i >= n4) return;
    const float4 v = ((const float4*)src)[i];
    ushort4 H, L;
    H.x = bfbits(v.x); L.x = bfbits(v.x - bf2f(H.x));
    H.y = bfbits(v.y); L.y = bfbits(v.y - bf2f(H.y));
    H.z = bfbits(v.z); L.z = bfbits(v.z - bf2f(H.z));
    H.w = bfbits(v.w); L.w = bfbits(v.w - bf2f(H.w));
    ((ushort4*)hi)[i] = H;
    ((ushort4*)lo)[i] = L;
}

// ---------------- f32 -> bf16 cast ----------------
__global__ void cast_bf16(const float* __restrict__ src, unsigned short* __restrict__ dst, int n4) {
    const int i = blockIdx.x * 256 + threadIdx.x;
    if (i >= n4) return;
    const float4 v = ((const float4*)src)[i];
    ushort4 o;
    o.x = bfbits(v.x); o.y = bfbits(v.y); o.z = bfbits(v.z); o.w = bfbits(v.w);
    ((ushort4*)dst)[i] = o;
}

// ---------------- bf16x3 MFMA GEMM: C[m,n]=sum_k A[m,k]B[n,k], ~fp32 acc ----
// 128x128 tile, BK=32, 4 waves (2x2 of 64x64). Per fragment pair:
// acc += AhBh + AhBl + AlBh. LDS rows padded to 40 shorts (2-way max alias).
// OUTM 0: f32 out (+split-K via blockIdx.z); OUTM 1: (hi,lo) bf16 pair out.
template <int EPI, int OUTM>
__global__ __launch_bounds__(256) void gemm_mfma3(
    const unsigned short* __restrict__ Ah, const unsigned short* __restrict__ Al,
    const unsigned short* __restrict__ Bh, const unsigned short* __restrict__ Bl,
    float* __restrict__ C, unsigned short* __restrict__ Chi, unsigned short* __restrict__ Clo,
    int M, int N, int K, int KS) {
    __shared__ short Ash[128][40];
    __shared__ short Asl[128][40];
    __shared__ short Bsh[128][40];
    __shared__ short Bsl[128][40];
    const int bm = blockIdx.y * 128, bn = blockIdx.x * 128;
    const int k0 = blockIdx.z * KS;
    const int tid = threadIdx.x;
    const int lane = tid & 63, wave = tid >> 6;
    const int wm = (wave >> 1) * 64, wn = (wave & 1) * 64;
    const int l16 = lane & 15, lq = lane >> 4;
    f32x4 acc[4][4];
#pragma unroll
    for (int i = 0; i < 4; ++i)
#pragma unroll
        for (int j = 0; j < 4; ++j) acc[i][j] = (f32x4){0.f, 0.f, 0.f, 0.f};

    const int srow = tid >> 1;           // 0..127
    const int skq = (tid & 1) * 16;      // short offset 0 / 16
    for (int kt = k0; kt < k0 + KS; kt += 32) {
        __syncthreads();
        const size_t oa = (size_t)(bm + srow) * K + kt + skq;
        const size_t ob = (size_t)(bn + srow) * K + kt + skq;
        {
            const float4 t0 = *(const float4*)(Ah + oa);
            const float4 t1 = *(const float4*)(Ah + oa + 8);
            *(float4*)&Ash[srow][skq] = t0;
            *(float4*)&Ash[srow][skq + 8] = t1;
        }
        {
            const float4 t0 = *(const float4*)(Al + oa);
            const float4 t1 = *(const float4*)(Al + oa + 8);
            *(float4*)&Asl[srow][skq] = t0;
            *(float4*)&Asl[srow][skq + 8] = t1;
        }
        {
            const float4 t0 = *(const float4*)(Bh + ob);
            const float4 t1 = *(const float4*)(Bh + ob + 8);
            *(float4*)&Bsh[srow][skq] = t0;
            *(float4*)&Bsh[srow][skq + 8] = t1;
        }
        {
            const float4 t0 = *(const float4*)(Bl + ob);
            const float4 t1 = *(const float4*)(Bl + ob + 8);
            *(float4*)&Bsl[srow][skq] = t0;
            *(float4*)&Bsl[srow][skq + 8] = t1;
        }
        __syncthreads();
        bf16x8 afh[4], afl[4], bfh[4], bfl[4];
#pragma unroll
        for (int i = 0; i < 4; ++i) {
            afh[i] = *(bf16x8*)&Ash[wm + i * 16 + l16][lq * 8];
            afl[i] = *(bf16x8*)&Asl[wm + i * 16 + l16][lq * 8];
            bfh[i] = *(bf16x8*)&Bsh[wn + i * 16 + l16][lq * 8];
            bfl[i] = *(bf16x8*)&Bsl[wn + i * 16 + l16][lq * 8];
        }
#pragma unroll
        for (int i = 0; i < 4; ++i)
#pragma unroll
            for (int j = 0; j < 4; ++j) {
                acc[i][j] = __builtin_amdgcn_mfma_f32_16x16x32_bf16(afh[i], bfh[j], acc[i][j], 0, 0, 0);
                acc[i][j] = __builtin_amdgcn_mfma_f32_16x16x32_bf16(afh[i], bfl[j], acc[i][j], 0, 0, 0);
                acc[i][j] = __builtin_amdgcn_mfma_f32_16x16x32_bf16(afl[i], bfh[j], acc[i][j], 0, 0, 0);
            }
    }
#pragma unroll
    for (int i = 0; i < 4; ++i)
#pragma unroll
        for (int j = 0; j < 4; ++j)
#pragma unroll
            for (int r = 0; r < 4; ++r) {
                float vv = acc[i][j][r];
                if (EPI == 1) { vv = vv > 0.f ? vv : 0.f; vv = vv * vv; }
                const int row = bm + wm + i * 16 + lq * 4 + r;
                const int col = bn + wn + j * 16 + l16;
                if (OUTM == 0) {
                    (C + (size_t)blockIdx.z * M * N)[(size_t)row * N + col] = vv;
                } else {
                    const unsigned short h = bfbits(vv);
                    Chi[(size_t)row * N + col] = h;
                    Clo[(size_t)row * N + col] = bfbits(vv - bf2f(h));
                }
            }
}

// ---------------- plain bf16 MFMA GEMM (v-branch, c_proj) ----------------
template <int EPI, typename OUT_T>
__global__ __launch_bounds__(256) void gemm_mfma(const unsigned short* __restrict__ A,
                                                 const unsigned short* __restrict__ B,
                                                 OUT_T* __restrict__ C,
                                                 int M, int N, int K, int KS) {
    __shared__ short As[128][40];
    __shared__ short Bs[128][40];
    const int bm = blockIdx.y * 128, bn = blockIdx.x * 128;
    const int k0 = blockIdx.z * KS;
    const int tid = threadIdx.x;
    const int lane = tid & 63, wave = tid >> 6;
    const int wm = (wave >> 1) * 64, wn = (wave & 1) * 64;
    const int l16 = lane & 15, lq = lane >> 4;
    f32x4 acc[4][4];
#pragma unroll
    for (int i = 0; i < 4; ++i)
#pragma unroll
        for (int j = 0; j < 4; ++j) acc[i][j] = (f32x4){0.f, 0.f, 0.f, 0.f};

    const int srow = tid >> 1;
    const int skq = (tid & 1) * 16;
    for (int kt = k0; kt < k0 + KS; kt += 32) {
        __syncthreads();
        const unsigned short* ga = A + (size_t)(bm + srow) * K + kt + skq;
        const unsigned short* gb = B + (size_t)(bn + srow) * K + kt + skq;
        const float4 a0 = *(const float4*)ga;
        const float4 a1 = *(const float4*)(ga + 8);
        const float4 b0 = *(const float4*)gb;
        const float4 b1 = *(const float4*)(gb + 8);
        *(float4*)&As[srow][skq] = a0;
        *(float4*)&As[srow][skq + 8] = a1;
        *(float4*)&Bs[srow][skq] = b0;
        *(float4*)&Bs[srow][skq + 8] = b1;
        __syncthreads();
        bf16x8 af[4], bfr[4];
#pragma unroll
        for (int i = 0; i < 4; ++i) {
            af[i]  = *(bf16x8*)&As[wm + i * 16 + l16][lq * 8];
            bfr[i] = *(bf16x8*)&Bs[wn + i * 16 + l16][lq * 8];
        }
#pragma unroll
        for (int i = 0; i < 4; ++i)
#pragma unroll
            for (int j = 0; j < 4; ++j)
                acc[i][j] = __builtin_amdgcn_mfma_f32_16x16x32_bf16(af[i], bfr[j], acc[i][j], 0, 0, 0);
    }
    OUT_T* Cz = C + (size_t)blockIdx.z * M * N;
#pragma unroll
    for (int i = 0; i < 4; ++i)
#pragma unroll
        for (int j = 0; j < 4; ++j)
#pragma unroll
            for (int r = 0; r < 4; ++r) {
                float vv = acc[i][j][r];
                if (EPI == 1) { vv = vv > 0.f ? vv : 0.f; vv = vv * vv; }
                const int row = bm + wm + i * 16 + lq * 4 + r;
                const int col = bn + wn + j * 16 + l16;
                stc(&Cz[(size_t)row * N + col], vv);
            }
}

__global__ void reduce8(const float* __restrict__ P, float* __restrict__ C, int MN) {
    const int idx = blockIdx.x * 256 + threadIdx.x;
    if (idx >= MN) return;
    float s = 0.f;
#pragma unroll
    for (int z = 0; z < 8; ++z) s += P[(size_t)z * MN + idx];
    C[idx] = s;
}

// ---------------- per-(h,t): rms-norm q,k; rotary; scale v ----------------
__global__ __launch_bounds__(128) void prep_qkv(const float* __restrict__ qkvbuf,
                                                const float* __restrict__ lambdas,
                                                float* __restrict__ q, float* __restrict__ k,
                                                float* __restrict__ v) {
    const int t = blockIdx.x, h = blockIdx.y, d = threadIdx.x;
    const int lane = d & 63, wave = d >> 6;
    __shared__ float sq[128], sk[128];
    __shared__ float r2[4];
    const float* row = qkvbuf + (size_t)t * 3072 + h * 128;
    const float qv = row[d], kv = row[1024 + d], vv = row[2048 + d];

    float s2q = qv * qv, s2k = kv * kv;
#pragma unroll
    for (int off = 32; off; off >>= 1) {
        s2q += __shfl_xor(s2q, off);
        s2k += __shfl_xor(s2k, off);
    }
    if (lane == 0) { r2[wave] = s2q; r2[2 + wave] = s2k; }
    __syncthreads();
    const float qr = rsqrtf((r2[0] + r2[1]) / 128.f + 1e-6f);
    const float kr = rsqrtf((r2[2] + r2[3]) / 128.f + 1e-6f);
    sq[d] = qv * qr; sk[d] = kv * kr;
    __syncthreads();

    const int j = d & 63;
    const float ang = (j < 32) ? powf(1.0f / 1024.0f, (float)j / 31.0f) : 0.0f;
    const float th = ang * (float)t;
    const float c = cosf(th), s = sinf(th);
    float qo, ko;
    if (d < 64) { qo = sq[d] * c + sq[d + 64] * s; ko = sk[d] * c + sk[d + 64] * s; }
    else        { qo = -sq[d - 64] * s + sq[d] * c; ko = -sk[d - 64] * s + sk[d] * c; }

    const size_t idx = ((size_t)h * T_LEN + t) * 128 + d;
    q[idx] = qo;
    k[idx] = ko;
    v[idx] = lambdas[0] * vv;
}

// ---------------- build compress-MLP inputs: kc (hi,lo) bf16, vc bf16 ------
__global__ void build_cin(const float* __restrict__ k, const float* __restrict__ v,
                          const float* __restrict__ kpos, const float* __restrict__ vpos,
                          unsigned short* __restrict__ kc_hi, unsigned short* __restrict__ kc_lo,
                          unsigned short* __restrict__ vc) {
    const int idx = blockIdx.x * 256 + threadIdx.x;   // float4 index
    if (idx >= NHEAD * NBLK * BS * DHEAD / 4) return;
    const int d4 = idx & 31, i = (idx >> 5) & 15, w = (idx >> 9) & 127, h = idx >> 16;
    const int t = w * 16 + i;
    const size_t src = (((size_t)h * T_LEN + t) * 128 + d4 * 4) / 4;
    const int pos = ((h * 16 + i) * 128 + d4 * 4) / 4;
    const float4 kv = reinterpret_cast<const float4*>(k)[src];
    const float4 vv = reinterpret_cast<const float4*>(v)[src];
    const float4 kp = reinterpret_cast<const float4*>(kpos)[pos];
    const float4 vp = reinterpret_cast<const float4*>(vpos)[pos];
    const float kc0 = kv.x + kp.x, kc1 = kv.y + kp.y, kc2 = kv.z + kp.z, kc3 = kv.w + kp.w;
    ushort4 H, L;
    H.x = bfbits(kc0); L.x = bfbits(kc0 - bf2f(H.x));
    H.y = bfbits(kc1); L.y = bfbits(kc1 - bf2f(H.y));
    H.z = bfbits(kc2); L.z = bfbits(kc2 - bf2f(H.z));
    H.w = bfbits(kc3); L.w = bfbits(kc3 - bf2f(H.w));
    ((ushort4*)kc_hi)[idx] = H;
    ((ushort4*)kc_lo)[idx] = L;
    ushort4 o;
    o.x = bfbits(vv.x + vp.x); o.y = bfbits(vv.y + vp.y);
    o.z = bfbits(vv.z + vp.z); o.w = bfbits(vv.w + vp.w);
    ((ushort4*)vc)[idx] = o;
}

// ---------------- assemble ck/cv with mem slot ----------------
__global__ void scatter_ckcv(const float* __restrict__ ckb, const float* __restrict__ cvb,
                             const float* __restrict__ memkv,
                             float* __restrict__ ck, float* __restrict__ cv) {
    int idx = blockIdx.x * 256 + threadIdx.x;
    if (idx >= NHEAD * NJ * DHEAD) return;
    const int d = idx & 127;
    const int j = (idx >> 7) % NJ;
    const int h = idx / (NJ * DHEAD);
    if (j == 0) {
        ck[idx] = memkv[h * 128 + d];
        cv[idx] = memkv[NHEAD * 128 + h * 128 + d];
    } else {
        const size_t b = ((size_t)h * NBLK + (j - 1)) * 128 + d;
        ck[idx] = ckb[b];
        cv[idx] = cvb[b];
    }
}

// ============ attention: direct-global 8-thr/key scores, global PV ============

__global__ __launch_bounds__(256) void comp_att(const float* __restrict__ q,
                                                const float* __restrict__ ck,
                                                const float* __restrict__ cv,
                                                float* __restrict__ csim,
                                                float* __restrict__ out) {
    const int t = blockIdx.x, h = blockIdx.y, tid = threadIdx.x;
    const int lane = tid & 63, wave = tid >> 6;
    __shared__ float qs[128];
    __shared__ float sc[NJ];
    __shared__ float red[4];
    __shared__ float pvb[256];
    if (tid < 128) qs[tid] = q[((size_t)h * T_LEN + t) * 128 + tid];
    __syncthreads();
    const int grp = tid & 7, key0 = tid >> 3;   // 32 key-threads x 8
    float qreg[16];
#pragma unroll
    for (int u = 0; u < 4; ++u)
        *(float4*)&qreg[u * 4] = *(const float4*)&qs[grp * 16 + u * 4];
    const int smax = t >> 4;
    for (int s = key0; s < NJ; s += 32) {
        float sum = 0.f;
        if (s <= smax) {
            const float* kr = ck + ((size_t)h * NJ + s) * 128 + grp * 16;
#pragma unroll
            for (int u = 0; u < 4; ++u) {
                const float4 kv = *(const float4*)(kr + u * 4);
                sum += kv.x * qreg[u * 4] + kv.y * qreg[u * 4 + 1] +
                       kv.z * qreg[u * 4 + 2] + kv.w * qreg[u * 4 + 3];
            }
        }
        sum += __shfl_xor(sum, 1); sum += __shfl_xor(sum, 2); sum += __shfl_xor(sum, 4);
        if (grp == 0) {
            const float val = (s <= smax) ? sum * SCALE : NEG;
            sc[s] = val;
            csim[((size_t)h * T_LEN + t) * NJ + s] = val;
        }
    }
    __syncthreads();
    float lm = (tid < NJ) ? sc[tid] : -INFINITY;
#pragma unroll
    for (int off = 32; off; off >>= 1) lm = fmaxf(lm, __shfl_xor(lm, off));
    if (lane == 0) red[wave] = lm;
    __syncthreads();
    const float mx = fmaxf(fmaxf(red[0], red[1]), fmaxf(red[2], red[3]));
    __syncthreads();
    float e = 0.f;
    if (tid < NJ) { e = __expf(sc[tid] - mx); sc[tid] = e; }
#pragma unroll
    for (int off = 32; off; off >>= 1) e += __shfl_xor(e, off);
    if (lane == 0) red[wave] = e;
    __syncthreads();
    const float inv = 1.f / (red[0] + red[1] + red[2] + red[3]);
    const int d = tid & 127, h2 = tid >> 7;
    float o = 0.f;
    for (int s = h2; s < NJ; s += 2)
        o += sc[s] * cv[((size_t)h * NJ + s) * 128 + d];
    pvb[tid] = o;
    __syncthreads();
    if (tid < 128)
        out[((size_t)h * T_LEN + t) * 128 + tid] = (pvb[tid] + pvb[tid + 128]) * inv;
}

__global__ void imp_kern(const float* __restrict__ csim, float* __restrict__ imp) {
    int idx = blockIdx.x * 256 + threadIdx.x;
    if (idx >= T_LEN * NBLK) return;
    const int w = idx & 127, t = idx >> 7;
    float s = 0.f;
    for (int h = 0; h < NHEAD; ++h)
        s += csim[((size_t)h * T_LEN + t) * NJ + 1 + w];
    imp[idx] = s * 0.125f;
}

__global__ void topk_kern(const float* __restrict__ imp, unsigned long long* __restrict__ selbits) {
    const int t = blockIdx.x * blockDim.x + threadIdx.x;
    if (t >= T_LEN) return;
    const float* row = imp + (size_t)t * NBLK;
    unsigned long long b0 = 0, b1 = 0;
    for (int s = 0; s < NSEL; ++s) {
        float best = -INFINITY; int bi = 0;
        for (int w = 0; w < NBLK; ++w) {
            const bool used = (w < 64) ? ((b0 >> w) & 1ull) : ((b1 >> (w - 64)) & 1ull);
            const float vv = row[w];
            if (!used && vv > best) { best = vv; bi = w; }
        }
        if (bi < 64) b0 |= 1ull << bi; else b1 |= 1ull << (bi - 64);
    }
    selbits[2 * t] = b0; selbits[2 * t + 1] = b1;
}

__global__ __launch_bounds__(256) void fine_att(const float* __restrict__ q,
                                                const float* __restrict__ k,
                                                const float* __restrict__ v,
                                                const unsigned long long* __restrict__ selbits,
                                                float* __restrict__ out) {
    const int t = blockIdx.x, h = blockIdx.y, tid = threadIdx.x;
    const int lane = tid & 63, wave = tid >> 6;
    __shared__ float qs[128];
    __shared__ float sc[17 * 16];
    __shared__ int blks[17];
    __shared__ int nb_s;
    __shared__ float red[4];
    __shared__ float pvb[256];
    if (tid < 128) qs[tid] = q[((size_t)h * T_LEN + t) * 128 + tid];
    if (tid == 0) {
        unsigned long long b0 = selbits[2 * t], b1 = selbits[2 * t + 1];
        const int cur = t >> 4;
        const bool curin = (cur < 64) ? ((b0 >> cur) & 1ull) : ((b1 >> (cur - 64)) & 1ull);
        int nb = 0;
        while (b0) { const int w = __ffsll(b0) - 1; b0 &= b0 - 1; blks[nb++] = w; }
        while (b1) { const int w = __ffsll(b1) - 1; b1 &= b1 - 1; blks[nb++] = w + 64; }
        if (!curin) blks[nb++] = cur;
        nb_s = nb;
    }
    __syncthreads();
    const int ns = nb_s * 16;
    const int grp = tid & 7, key0 = tid >> 3;
    float qreg[16];
#pragma unroll
    for (int u = 0; u < 4; ++u)
        *(float4*)&qreg[u * 4] = *(const float4*)&qs[grp * 16 + u * 4];
    for (int s = key0; s < ns; s += 32) {
        const int j = blks[s >> 4] * 16 + (s & 15);
        float sum = 0.f;
        if (j <= t) {
            const float* kr = k + ((size_t)h * T_LEN + j) * 128 + grp * 16;
#pragma unroll
            for (int u = 0; u < 4; ++u) {
                const float4 kv = *(const float4*)(kr + u * 4);
                sum += kv.x * qreg[u * 4] + kv.y * qreg[u * 4 + 1] +
                       kv.z * qreg[u * 4 + 2] + kv.w * qreg[u * 4 + 3];
            }
        }
        sum += __shfl_xor(sum, 1); sum += __shfl_xor(sum, 2); sum += __shfl_xor(sum, 4);
        if (grp == 0) sc[s] = (j <= t) ? sum * SCALE : -INFINITY;
    }
    __syncthreads();
    float lm = -INFINITY;
    for (int s = tid; s < ns; s += 256) lm = fmaxf(lm, sc[s]);
#pragma unroll
    for (int off = 32; off; off >>= 1) lm = fmaxf(lm, __shfl_xor(lm, off));
    if (lane == 0) red[wave] = lm;
    __syncthreads();
    const float mx = fmaxf(fmaxf(red[0], red[1]), fmaxf(red[2], red[3]));
    __syncthreads();
    float ls = 0.f;
    for (int s = tid; s < ns; s += 256) { const float e = __expf(sc[s] - mx); sc[s] = e; ls += e; }
#pragma unroll
    for (int off = 32; off; off >>= 1) ls += __shfl_xor(ls, off);
    if (lane == 0) red[wave] = ls;
    __syncthreads();
    const float inv = 1.f / (red[0] + red[1] + red[2] + red[3]);
    const int d = tid & 127, h2 = tid >> 7;
    float o = 0.f;
    for (int s = h2; s < ns; s += 2) {
        const int j = blks[s >> 4] * 16 + (s & 15);
        o += sc[s] * v[((size_t)h * T_LEN + j) * 128 + d];
    }
    pvb[tid] = o;
    __syncthreads();
    if (tid < 128)
        out[((size_t)h * T_LEN + t) * 128 + tid] = (pvb[tid] + pvb[tid + 128]) * inv;
}

__global__ __launch_bounds__(256) void slide_att(const float* __restrict__ q,
                                                 const float* __restrict__ k,
                                                 const float* __restrict__ v,
                                                 float* __restrict__ out) {
    const int t = blockIdx.x, h = blockIdx.y, tid = threadIdx.x;
    const int lane = tid & 63, wave = tid >> 6;
    __shared__ float qs[128];
    __shared__ float sc[WIN];
    __shared__ float red[4];
    __shared__ float pvb[256];
    if (tid < 128) qs[tid] = q[((size_t)h * T_LEN + t) * 128 + tid];
    __syncthreads();
    const int j0 = max(0, t - (WIN - 1));
    const int ns = t - j0 + 1;
    const int grp = tid & 7, key0 = tid >> 3;
    float qreg[16];
#pragma unroll
    for (int u = 0; u < 4; ++u)
        *(float4*)&qreg[u * 4] = *(const float4*)&qs[grp * 16 + u * 4];
    for (int s = key0; s < ns; s += 32) {
        const float* kr = k + ((size_t)h * T_LEN + j0 + s) * 128 + grp * 16;
        float sum = 0.f;
#pragma unroll
        for (int u = 0; u < 4; ++u) {
            const float4 kv = *(const float4*)(kr + u * 4);
            sum += kv.x * qreg[u * 4] + kv.y * qreg[u * 4 + 1] +
                   kv.z * qreg[u * 4 + 2] + kv.w * qreg[u * 4 + 3];
        }
        sum += __shfl_xor(sum, 1); sum += __shfl_xor(sum, 2); sum += __shfl_xor(sum, 4);
        if (grp == 0) sc[s] = sum * SCALE;
    }
    __syncthreads();
    float lm = (tid < ns) ? sc[tid] : -INFINITY;
#pragma unroll
    for (int off = 32; off; off >>= 1) lm = fmaxf(lm, __shfl_xor(lm, off));
    if (lane == 0) red[wave] = lm;
    __syncthreads();
    const float mx = fmaxf(fmaxf(red[0], red[1]), fmaxf(red[2], red[3]));
    __syncthreads();
    float e = 0.f;
    if (tid < ns) { e = __expf(sc[tid] - mx); sc[tid] = e; }
#pragma unroll
    for (int off = 32; off; off >>= 1) e += __shfl_xor(e, off);
    if (lane == 0) red[wave] = e;
    __syncthreads();
    const float inv = 1.f / (red[0] + red[1] + red[2] + red[3]);
    const int d = tid & 127, h2 = tid >> 7;
    float o = 0.f;
    for (int s = h2; s < ns; s += 2)
        o += sc[s] * v[((size_t)h * T_LEN + j0 + s) * 128 + d];
    pvb[tid] = o;
    __syncthreads();
    if (tid < 128)
        out[((size_t)h * T_LEN + t) * 128 + tid] = (pvb[tid] + pvb[tid + 128]) * inv;
}

__global__ __launch_bounds__(256) void strat_kern(const float* __restrict__ x,
                                                  const float* __restrict__ w,
                                                  const float* __restrict__ b,
                                                  float* __restrict__ strat) {
    const int t = blockIdx.x, tid = threadIdx.x;
    const int lane = tid & 63, wave = tid >> 6;
    __shared__ float xs[1024];
    for (int c = tid; c < 1024; c += 256) xs[c] = x[(size_t)t * 1024 + c];
    __syncthreads();
    for (int i = wave; i < 24; i += 4) {
        const float* wr = w + (size_t)i * 1024;
        float s = 0.f;
#pragma unroll
        for (int u = 0; u < 4; ++u) {
            const int c = u * 256 + lane * 4;
            const float4 wv = *reinterpret_cast<const float4*>(wr + c);
            const float4 xv = *reinterpret_cast<const float4*>(&xs[c]);
            s += wv.x * xv.x + wv.y * xv.y + wv.z * xv.z + wv.w * xv.w;
        }
#pragma unroll
        for (int off = 32; off; off >>= 1) s += __shfl_xor(s, off);
        if (lane == 0)
            strat[t * 24 + i] = 1.f / (1.f + __expf(-(s + b[i])));
    }
}

__global__ __launch_bounds__(256) void combine_kern(const float* __restrict__ strat,
                                                    const float* __restrict__ comp,
                                                    const float* __restrict__ fine,
                                                    const float* __restrict__ slide,
                                                    unsigned short* __restrict__ mixb) {
    const int t = blockIdx.x, tid = threadIdx.x;
    const int hh = tid >> 5, d0 = (tid & 31) * 4;
    const float* st = strat + t * 24 + hh * 3;
    const size_t idx = (((size_t)hh * T_LEN + t) * 128 + d0) / 4;
    const float4 c4 = ((const float4*)comp)[idx];
    const float4 f4 = ((const float4*)fine)[idx];
    const float4 s4 = ((const float4*)slide)[idx];
    ushort4 o;
    o.x = bfbits(st[0] * c4.x + st[1] * f4.x + st[2] * s4.x);
    o.y = bfbits(st[0] * c4.y + st[1] * f4.y + st[2] * s4.y);
    o.z = bfbits(st[0] * c4.z + st[1] * f4.z + st[2] * s4.z);
    o.w = bfbits(st[0] * c4.w + st[1] * f4.w + st[2] * s4.w);
    ((ushort4*)mixb)[(size_t)t * 256 + tid] = o;
}

extern "C" void kernel_launch(void* const* d_in, const int* in_sizes, int n_in,
                              void* d_out, int out_size, void* d_ws, size_t ws_size,
                              hipStream_t stream) {
    const float* x        = (const float*)d_in[0];
    const float* qkv_w    = (const float*)d_in[1];
    const float* lambdas  = (const float*)d_in[2];
    const float* c_proj_w = (const float*)d_in[3];
    const float* k_fc_w   = (const float*)d_in[4];
    const float* k_pj_w   = (const float*)d_in[5];
    const float* v_fc_w   = (const float*)d_in[6];
    const float* v_pj_w   = (const float*)d_in[7];
    const float* mem_kv   = (const float*)d_in[8];
    const float* k_pos    = (const float*)d_in[9];
    const float* v_pos    = (const float*)d_in[10];
    const float* strat_w  = (const float*)d_in[11];
    const float* strat_b  = (const float*)d_in[12];
    float* out = (float*)d_out;

    char* ws = (char*)d_ws;
    size_t off = 0;
    auto alloc = [&](size_t bytes) -> void* {
        void* p = ws + off;
        off += (bytes + 255) & ~(size_t)255;
        return p;
    };

    const size_t MB_HID = (size_t)1024 * 8192 * 2;      // 16.78 MB (bf16 hidden)
    const size_t MB_FCW = (size_t)8192 * 2048 * 2;      // 33.55 MB (bf16 fc weight)

    // region A (33.6 MB): buf_qkv f32 -> (hid_hi | hid_lo) -> (hidden_v | mixb)
    char* A = (char*)alloc(2 * MB_HID);
    float* buf_qkv = (float*)A;                               // 25.2 MB, dead after prep
    unsigned short* hid_hi = (unsigned short*)A;              // fc-k out, dead after pj-k
    unsigned short* hid_lo = (unsigned short*)(A + MB_HID);
    unsigned short* hidden_v = (unsigned short*)A;            // fc-v out
    unsigned short* mixb = (unsigned short*)(A + MB_HID);     // combine out

    // region B (67.1 MB): (kfcw_hi | kfcw_lo) -> (wfc_b | fine+slide+partials+wpj_b+wcp_b)
    char* B = (char*)alloc(2 * MB_FCW);
    unsigned short* kfcw_hi = (unsigned short*)B;             // dead after fc-k
    unsigned short* kfcw_lo = (unsigned short*)(B + MB_FCW);
    unsigned short* wfc_b = (unsigned short*)B;               // v_fc_w bf16 (after fc-k)
    char* B2 = B + MB_FCW;
    float* fine  = (float*)B2;                                // 8.39 MB
    float* slide = (float*)(B2 + 8388608);                    // 8.39 MB
    float* partials = (float*)(B2 + 2 * 8388608);             // 4.19 MB
    unsigned short* wpj_b = (unsigned short*)(B2 + 2 * 8388608 + 4194304);  // 2.1 MB
    unsigned short* wcp_b = (unsigned short*)(B2 + 2 * 8388608 + 4194304 + 2097152);

    // region D (21 MB): (x_hi|x_lo|qw_hi|qw_lo) -> (kpjw_hi|kpjw_lo)
    char* D = (char*)alloc((size_t)2048 * 1024 * 4 + (size_t)3072 * 1024 * 4);
    unsigned short* x_hi = (unsigned short*)D;                          // 4.19 MB
    unsigned short* x_lo = (unsigned short*)(D + 4194304);
    unsigned short* qw_hi = (unsigned short*)(D + 2 * 4194304);         // 6.29 MB
    unsigned short* qw_lo = (unsigned short*)(D + 2 * 4194304 + 6291456);
    unsigned short* kpjw_hi = (unsigned short*)D;             // after qkv
    unsigned short* kpjw_lo = (unsigned short*)(D + 2097152);

    // persistent
    float* q = (float*)alloc((size_t)NHEAD * T_LEN * 128 * 4);
    float* k = (float*)alloc((size_t)NHEAD * T_LEN * 128 * 4);
    float* v = (float*)alloc((size_t)NHEAD * T_LEN * 128 * 4);
    char* KC = (char*)alloc((size_t)1024 * 2048 * 4);         // kc pair; comp aliases after fc-k
    unsigned short* kc_hi = (unsigned short*)KC;
    unsigned short* kc_lo = (unsigned short*)(KC + 4194304);
    float* comp = (float*)KC;
    unsigned short* vc = (unsigned short*)alloc((size_t)1024 * 2048 * 2);
    float* csim = (float*)alloc((size_t)NHEAD * T_LEN * NJ * 4);
    float* imp  = (float*)alloc((size_t)T_LEN * NBLK * 4);
    float* strat = (float*)alloc((size_t)T_LEN * 24 * 4);
    float* ckb = (float*)alloc((size_t)1024 * 128 * 4);
    float* cvb = (float*)alloc((size_t)1024 * 128 * 4);
    float* ck  = (float*)alloc((size_t)NHEAD * NJ * 128 * 4);
    float* cv  = (float*)alloc((size_t)NHEAD * NJ * 128 * 4);
    unsigned long long* selbits = (unsigned long long*)alloc((size_t)T_LEN * 2 * 8);

    // 0. splits for qkv
    split_pair<<<2048, 256, 0, stream>>>(x, x_hi, x_lo, 2048 * 1024 / 4);
    split_pair<<<3072, 256, 0, stream>>>(qkv_w, qw_hi, qw_lo, 3072 * 1024 / 4);

    // 1. QKV projection (bf16x3 MFMA, ~fp32 accurate)
    gemm_mfma3<0, 0><<<dim3(3072 / 128, T_LEN / 128, 1), 256, 0, stream>>>(
        x_hi, x_lo, qw_hi, qw_lo, buf_qkv, nullptr, nullptr, T_LEN, 3072, 1024, 1024);

    // 2. rms + rotary + v-scale
    prep_qkv<<<dim3(T_LEN, NHEAD), 128, 0, stream>>>(buf_qkv, lambdas, q, k, v);

    // 3. k-branch weight splits (D region free after qkv; B region)
    split_pair<<<16384, 256, 0, stream>>>(k_fc_w, kfcw_hi, kfcw_lo, 8192 * 2048 / 4);
    split_pair<<<1024, 256, 0, stream>>>(k_pj_w, kpjw_hi, kpjw_lo, 128 * 8192 / 4);

    // 4. compress-MLP inputs (kc hi/lo, vc bf16)
    build_cin<<<(NHEAD * NBLK * BS * DHEAD / 4 + 255) / 256, 256, 0, stream>>>(
        k, v, k_pos, v_pos, kc_hi, kc_lo, vc);

    // 5. fc-k (bf16x3, relu^2, split-pair output)
    gemm_mfma3<1, 1><<<dim3(8192 / 128, 1024 / 128, 1), 256, 0, stream>>>(
        kc_hi, kc_lo, kfcw_hi, kfcw_lo, nullptr, hid_hi, hid_lo, 1024, 8192, 2048, 2048);

    // 6. pj-k (bf16x3, split-K=8) + reduce
    gemm_mfma3<0, 0><<<dim3(1, 1024 / 128, 8), 256, 0, stream>>>(
        hid_hi, hid_lo, kpjw_hi, kpjw_lo, partials, nullptr, nullptr, 1024, 128, 8192, 1024);
    reduce8<<<(1024 * 128 + 255) / 256, 256, 0, stream>>>(partials, ckb, 1024 * 128);

    // 7. v-branch weight casts (B region free after fc-k)
    cast_bf16<<<(8192 * 2048 / 4 + 255) / 256, 256, 0, stream>>>(v_fc_w, wfc_b, 8192 * 2048 / 4);
    cast_bf16<<<(128 * 8192 / 4 + 255) / 256, 256, 0, stream>>>(v_pj_w, wpj_b, 128 * 8192 / 4);
    cast_bf16<<<(1024 * 1024 / 4 + 255) / 256, 256, 0, stream>>>(c_proj_w, wcp_b, 1024 * 1024 / 4);

    // 8. v-branch MLP (plain bf16 MFMA)
    gemm_mfma<1, unsigned short><<<dim3(8192 / 128, 1024 / 128, 1), 256, 0, stream>>>(
        vc, wfc_b, hidden_v, 1024, 8192, 2048, 2048);
    gemm_mfma<0, float><<<dim3(1, 1024 / 128, 8), 256, 0, stream>>>(
        hidden_v, wpj_b, partials, 1024, 128, 8192, 1024);
    reduce8<<<(1024 * 128 + 255) / 256, 256, 0, stream>>>(partials, cvb, 1024 * 128);

    // 9. assemble ck/cv
    scatter_ckcv<<<(NHEAD * NJ * DHEAD + 255) / 256, 256, 0, stream>>>(
        ckb, cvb, mem_kv, ck, cv);

    // 10. fused compressed attention
    comp_att<<<dim3(T_LEN, NHEAD), 256, 0, stream>>>(q, ck, cv, csim, comp);

    // 11. importance + top-k
    imp_kern<<<(T_LEN * NBLK + 255) / 256, 256, 0, stream>>>(csim, imp);
    topk_kern<<<(T_LEN + 255) / 256, 256, 0, stream>>>(imp, selbits);

    // 12. fine + sliding attention
    fine_att<<<dim3(T_LEN, NHEAD), 256, 0, stream>>>(q, k, v, selbits, fine);
    slide_att<<<dim3(T_LEN, NHEAD), 256, 0, stream>>>(q, k, v, slide);

    // 13. strategy gates + combine
    strat_kern<<<T_LEN, 256, 0, stream>>>(x, strat_w, strat_b, strat);
    combine_kern<<<T_LEN, 256, 0, stream>>>(strat, comp, fine, slide, mixb);

    // 14. output projection (plain bf16 MFMA)
    gemm_mfma<0, float><<<dim3(1024 / 128, T_LEN / 128, 1), 256, 0, stream>>>(
        mixb, wcp_b, out, T_LEN, 1024, 1024, 1024);
}

// Round 10
// 1002.273 us; speedup vs baseline: 4.8491x; 1.2603x over previous
//
// Round 10: PV-phase float4 vectorization in fine/slide/comp attention
// (round-9 counters: fine_att 351us top, VALU-bound, PV loop = 3x score
// cost at 1 scalar v-element/thread/key). 8 key-groups x 32 float4
// d-slices, LDS float4 partials, 8-way reduce. Everything else unchanged.
#include <hip/hip_runtime.h>
#include <hip/hip_bf16.h>

#define T_LEN 2048
#define NHEAD 8
#define DHEAD 128
#define NBLK 128     // W
#define BS 16
#define NSEL 16
#define WIN 128
#define NMEM 1
#define NJ (NBLK + NMEM)   // 129
#define SCALE 0.12f
#define NEG -1e9f

typedef __attribute__((ext_vector_type(8))) short bf16x8;
typedef __attribute__((ext_vector_type(4))) float f32x4;

__device__ __forceinline__ unsigned short bfbits(float x) {
    __hip_bfloat16 h = __float2bfloat16(x);
    return *reinterpret_cast<unsigned short*>(&h);
}
__device__ __forceinline__ float bf2f(unsigned short h) {
    return __uint_as_float(((unsigned)h) << 16);
}
__device__ __forceinline__ void stc(float* p, float v) { *p = v; }
__device__ __forceinline__ void stc(unsigned short* p, float v) { *p = bfbits(v); }

// ---------------- f32 -> (hi, lo) bf16 split ----------------
__global__ void split_pair(const float* __restrict__ src, unsigned short* __restrict__ hi,
                           unsigned short* __restrict__ lo, int n4) {
    const int i = blockIdx.x * 256 + threadIdx.x;
    if (i >= n4) return;
    const float4 v = ((const float4*)src)[i];
    ushort4 H, L;
    H.x = bfbits(v.x); L.x = bfbits(v.x - bf2f(H.x));
    H.y = bfbits(v.y); L.y = bfbits(v.y - bf2f(H.y));
    H.z = bfbits(v.z); L.z = bfbits(v.z - bf2f(H.z));
    H.w = bfbits(v.w); L.w = bfbits(v.w - bf2f(H.w));
    ((ushort4*)hi)[i] = H;
    ((ushort4*)lo)[i] = L;
}

// ---------------- f32 -> bf16 cast ----------------
__global__ void cast_bf16(const float* __restrict__ src, unsigned short* __restrict__ dst, int n4) {
    const int i = blockIdx.x * 256 + threadIdx.x;
    if (i >= n4) return;
    const float4 v = ((const float4*)src)[i];
    ushort4 o;
    o.x = bfbits(v.x); o.y = bfbits(v.y); o.z = bfbits(v.z); o.w = bfbits(v.w);
    ((ushort4*)dst)[i] = o;
}

// ---------------- bf16x3 MFMA GEMM: C[m,n]=sum_k A[m,k]B[n,k], ~fp32 acc ----
template <int EPI, int OUTM>
__global__ __launch_bounds__(256) void gemm_mfma3(
    const unsigned short* __restrict__ Ah, const unsigned short* __restrict__ Al,
    const unsigned short* __restrict__ Bh, const unsigned short* __restrict__ Bl,
    float* __restrict__ C, unsigned short* __restrict__ Chi, unsigned short* __restrict__ Clo,
    int M, int N, int K, int KS) {
    __shared__ short Ash[128][40];
    __shared__ short Asl[128][40];
    __shared__ short Bsh[128][40];
    __shared__ short Bsl[128][40];
    const int bm = blockIdx.y * 128, bn = blockIdx.x * 128;
    const int k0 = blockIdx.z * KS;
    const int tid = threadIdx.x;
    const int lane = tid & 63, wave = tid >> 6;
    const int wm = (wave >> 1) * 64, wn = (wave & 1) * 64;
    const int l16 = lane & 15, lq = lane >> 4;
    f32x4 acc[4][4];
#pragma unroll
    for (int i = 0; i < 4; ++i)
#pragma unroll
        for (int j = 0; j < 4; ++j) acc[i][j] = (f32x4){0.f, 0.f, 0.f, 0.f};

    const int srow = tid >> 1;           // 0..127
    const int skq = (tid & 1) * 16;      // short offset 0 / 16
    for (int kt = k0; kt < k0 + KS; kt += 32) {
        __syncthreads();
        const size_t oa = (size_t)(bm + srow) * K + kt + skq;
        const size_t ob = (size_t)(bn + srow) * K + kt + skq;
        {
            const float4 t0 = *(const float4*)(Ah + oa);
            const float4 t1 = *(const float4*)(Ah + oa + 8);
            *(float4*)&Ash[srow][skq] = t0;
            *(float4*)&Ash[srow][skq + 8] = t1;
        }
        {
            const float4 t0 = *(const float4*)(Al + oa);
            const float4 t1 = *(const float4*)(Al + oa + 8);
            *(float4*)&Asl[srow][skq] = t0;
            *(float4*)&Asl[srow][skq + 8] = t1;
        }
        {
            const float4 t0 = *(const float4*)(Bh + ob);
            const float4 t1 = *(const float4*)(Bh + ob + 8);
            *(float4*)&Bsh[srow][skq] = t0;
            *(float4*)&Bsh[srow][skq + 8] = t1;
        }
        {
            const float4 t0 = *(const float4*)(Bl + ob);
            const float4 t1 = *(const float4*)(Bl + ob + 8);
            *(float4*)&Bsl[srow][skq] = t0;
            *(float4*)&Bsl[srow][skq + 8] = t1;
        }
        __syncthreads();
        bf16x8 afh[4], afl[4], bfh[4], bfl[4];
#pragma unroll
        for (int i = 0; i < 4; ++i) {
            afh[i] = *(bf16x8*)&Ash[wm + i * 16 + l16][lq * 8];
            afl[i] = *(bf16x8*)&Asl[wm + i * 16 + l16][lq * 8];
            bfh[i] = *(bf16x8*)&Bsh[wn + i * 16 + l16][lq * 8];
            bfl[i] = *(bf16x8*)&Bsl[wn + i * 16 + l16][lq * 8];
        }
#pragma unroll
        for (int i = 0; i < 4; ++i)
#pragma unroll
            for (int j = 0; j < 4; ++j) {
                acc[i][j] = __builtin_amdgcn_mfma_f32_16x16x32_bf16(afh[i], bfh[j], acc[i][j], 0, 0, 0);
                acc[i][j] = __builtin_amdgcn_mfma_f32_16x16x32_bf16(afh[i], bfl[j], acc[i][j], 0, 0, 0);
                acc[i][j] = __builtin_amdgcn_mfma_f32_16x16x32_bf16(afl[i], bfh[j], acc[i][j], 0, 0, 0);
            }
    }
#pragma unroll
    for (int i = 0; i < 4; ++i)
#pragma unroll
        for (int j = 0; j < 4; ++j)
#pragma unroll
            for (int r = 0; r < 4; ++r) {
                float vv = acc[i][j][r];
                if (EPI == 1) { vv = vv > 0.f ? vv : 0.f; vv = vv * vv; }
                const int row = bm + wm + i * 16 + lq * 4 + r;
                const int col = bn + wn + j * 16 + l16;
                if (OUTM == 0) {
                    (C + (size_t)blockIdx.z * M * N)[(size_t)row * N + col] = vv;
                } else {
                    const unsigned short h = bfbits(vv);
                    Chi[(size_t)row * N + col] = h;
                    Clo[(size_t)row * N + col] = bfbits(vv - bf2f(h));
                }
            }
}

// ---------------- plain bf16 MFMA GEMM (v-branch, c_proj) ----------------
template <int EPI, typename OUT_T>
__global__ __launch_bounds__(256) void gemm_mfma(const unsigned short* __restrict__ A,
                                                 const unsigned short* __restrict__ B,
                                                 OUT_T* __restrict__ C,
                                                 int M, int N, int K, int KS) {
    __shared__ short As[128][40];
    __shared__ short Bs[128][40];
    const int bm = blockIdx.y * 128, bn = blockIdx.x * 128;
    const int k0 = blockIdx.z * KS;
    const int tid = threadIdx.x;
    const int lane = tid & 63, wave = tid >> 6;
    const int wm = (wave >> 1) * 64, wn = (wave & 1) * 64;
    const int l16 = lane & 15, lq = lane >> 4;
    f32x4 acc[4][4];
#pragma unroll
    for (int i = 0; i < 4; ++i)
#pragma unroll
        for (int j = 0; j < 4; ++j) acc[i][j] = (f32x4){0.f, 0.f, 0.f, 0.f};

    const int srow = tid >> 1;
    const int skq = (tid & 1) * 16;
    for (int kt = k0; kt < k0 + KS; kt += 32) {
        __syncthreads();
        const unsigned short* ga = A + (size_t)(bm + srow) * K + kt + skq;
        const unsigned short* gb = B + (size_t)(bn + srow) * K + kt + skq;
        const float4 a0 = *(const float4*)ga;
        const float4 a1 = *(const float4*)(ga + 8);
        const float4 b0 = *(const float4*)gb;
        const float4 b1 = *(const float4*)(gb + 8);
        *(float4*)&As[srow][skq] = a0;
        *(float4*)&As[srow][skq + 8] = a1;
        *(float4*)&Bs[srow][skq] = b0;
        *(float4*)&Bs[srow][skq + 8] = b1;
        __syncthreads();
        bf16x8 af[4], bfr[4];
#pragma unroll
        for (int i = 0; i < 4; ++i) {
            af[i]  = *(bf16x8*)&As[wm + i * 16 + l16][lq * 8];
            bfr[i] = *(bf16x8*)&Bs[wn + i * 16 + l16][lq * 8];
        }
#pragma unroll
        for (int i = 0; i < 4; ++i)
#pragma unroll
            for (int j = 0; j < 4; ++j)
                acc[i][j] = __builtin_amdgcn_mfma_f32_16x16x32_bf16(af[i], bfr[j], acc[i][j], 0, 0, 0);
    }
    OUT_T* Cz = C + (size_t)blockIdx.z * M * N;
#pragma unroll
    for (int i = 0; i < 4; ++i)
#pragma unroll
        for (int j = 0; j < 4; ++j)
#pragma unroll
            for (int r = 0; r < 4; ++r) {
                float vv = acc[i][j][r];
                if (EPI == 1) { vv = vv > 0.f ? vv : 0.f; vv = vv * vv; }
                const int row = bm + wm + i * 16 + lq * 4 + r;
                const int col = bn + wn + j * 16 + l16;
                stc(&Cz[(size_t)row * N + col], vv);
            }
}

__global__ void reduce8(const float* __restrict__ P, float* __restrict__ C, int MN) {
    const int idx = blockIdx.x * 256 + threadIdx.x;
    if (idx >= MN) return;
    float s = 0.f;
#pragma unroll
    for (int z = 0; z < 8; ++z) s += P[(size_t)z * MN + idx];
    C[idx] = s;
}

// ---------------- per-(h,t): rms-norm q,k; rotary; scale v ----------------
__global__ __launch_bounds__(128) void prep_qkv(const float* __restrict__ qkvbuf,
                                                const float* __restrict__ lambdas,
                                                float* __restrict__ q, float* __restrict__ k,
                                                float* __restrict__ v) {
    const int t = blockIdx.x, h = blockIdx.y, d = threadIdx.x;
    const int lane = d & 63, wave = d >> 6;
    __shared__ float sq[128], sk[128];
    __shared__ float r2[4];
    const float* row = qkvbuf + (size_t)t * 3072 + h * 128;
    const float qv = row[d], kv = row[1024 + d], vv = row[2048 + d];

    float s2q = qv * qv, s2k = kv * kv;
#pragma unroll
    for (int off = 32; off; off >>= 1) {
        s2q += __shfl_xor(s2q, off);
        s2k += __shfl_xor(s2k, off);
    }
    if (lane == 0) { r2[wave] = s2q; r2[2 + wave] = s2k; }
    __syncthreads();
    const float qr = rsqrtf((r2[0] + r2[1]) / 128.f + 1e-6f);
    const float kr = rsqrtf((r2[2] + r2[3]) / 128.f + 1e-6f);
    sq[d] = qv * qr; sk[d] = kv * kr;
    __syncthreads();

    const int j = d & 63;
    const float ang = (j < 32) ? powf(1.0f / 1024.0f, (float)j / 31.0f) : 0.0f;
    const float th = ang * (float)t;
    const float c = cosf(th), s = sinf(th);
    float qo, ko;
    if (d < 64) { qo = sq[d] * c + sq[d + 64] * s; ko = sk[d] * c + sk[d + 64] * s; }
    else        { qo = -sq[d - 64] * s + sq[d] * c; ko = -sk[d - 64] * s + sk[d] * c; }

    const size_t idx = ((size_t)h * T_LEN + t) * 128 + d;
    q[idx] = qo;
    k[idx] = ko;
    v[idx] = lambdas[0] * vv;
}

// ---------------- build compress-MLP inputs: kc (hi,lo) bf16, vc bf16 ------
__global__ void build_cin(const float* __restrict__ k, const float* __restrict__ v,
                          const float* __restrict__ kpos, const float* __restrict__ vpos,
                          unsigned short* __restrict__ kc_hi, unsigned short* __restrict__ kc_lo,
                          unsigned short* __restrict__ vc) {
    const int idx = blockIdx.x * 256 + threadIdx.x;   // float4 index
    if (idx >= NHEAD * NBLK * BS * DHEAD / 4) return;
    const int d4 = idx & 31, i = (idx >> 5) & 15, w = (idx >> 9) & 127, h = idx >> 16;
    const int t = w * 16 + i;
    const size_t src = (((size_t)h * T_LEN + t) * 128 + d4 * 4) / 4;
    const int pos = ((h * 16 + i) * 128 + d4 * 4) / 4;
    const float4 kv = reinterpret_cast<const float4*>(k)[src];
    const float4 vv = reinterpret_cast<const float4*>(v)[src];
    const float4 kp = reinterpret_cast<const float4*>(kpos)[pos];
    const float4 vp = reinterpret_cast<const float4*>(vpos)[pos];
    const float kc0 = kv.x + kp.x, kc1 = kv.y + kp.y, kc2 = kv.z + kp.z, kc3 = kv.w + kp.w;
    ushort4 H, L;
    H.x = bfbits(kc0); L.x = bfbits(kc0 - bf2f(H.x));
    H.y = bfbits(kc1); L.y = bfbits(kc1 - bf2f(H.y));
    H.z = bfbits(kc2); L.z = bfbits(kc2 - bf2f(H.z));
    H.w = bfbits(kc3); L.w = bfbits(kc3 - bf2f(H.w));
    ((ushort4*)kc_hi)[idx] = H;
    ((ushort4*)kc_lo)[idx] = L;
    ushort4 o;
    o.x = bfbits(vv.x + vp.x); o.y = bfbits(vv.y + vp.y);
    o.z = bfbits(vv.z + vp.z); o.w = bfbits(vv.w + vp.w);
    ((ushort4*)vc)[idx] = o;
}

// ---------------- assemble ck/cv with mem slot ----------------
__global__ void scatter_ckcv(const float* __restrict__ ckb, const float* __restrict__ cvb,
                             const float* __restrict__ memkv,
                             float* __restrict__ ck, float* __restrict__ cv) {
    int idx = blockIdx.x * 256 + threadIdx.x;
    if (idx >= NHEAD * NJ * DHEAD) return;
    const int d = idx & 127;
    const int j = (idx >> 7) % NJ;
    const int h = idx / (NJ * DHEAD);
    if (j == 0) {
        ck[idx] = memkv[h * 128 + d];
        cv[idx] = memkv[NHEAD * 128 + h * 128 + d];
    } else {
        const size_t b = ((size_t)h * NBLK + (j - 1)) * 128 + d;
        ck[idx] = ckb[b];
        cv[idx] = cvb[b];
    }
}

// ============ attention: direct-global 8-thr/key scores, float4 PV ============

__global__ __launch_bounds__(256) void comp_att(const float* __restrict__ q,
                                                const float* __restrict__ ck,
                                                const float* __restrict__ cv,
                                                float* __restrict__ csim,
                                                float* __restrict__ out) {
    const int t = blockIdx.x, h = blockIdx.y, tid = threadIdx.x;
    const int lane = tid & 63, wave = tid >> 6;
    __shared__ float qs[128];
    __shared__ float sc[NJ];
    __shared__ float red[4];
    __shared__ float4 pv4[256];
    if (tid < 128) qs[tid] = q[((size_t)h * T_LEN + t) * 128 + tid];
    __syncthreads();
    const int grp = tid & 7, key0 = tid >> 3;   // 32 key-threads x 8
    float qreg[16];
#pragma unroll
    for (int u = 0; u < 4; ++u)
        *(float4*)&qreg[u * 4] = *(const float4*)&qs[grp * 16 + u * 4];
    const int smax = t >> 4;
    for (int s = key0; s < NJ; s += 32) {
        float sum = 0.f;
        if (s <= smax) {
            const float* kr = ck + ((size_t)h * NJ + s) * 128 + grp * 16;
#pragma unroll
            for (int u = 0; u < 4; ++u) {
                const float4 kv = *(const float4*)(kr + u * 4);
                sum += kv.x * qreg[u * 4] + kv.y * qreg[u * 4 + 1] +
                       kv.z * qreg[u * 4 + 2] + kv.w * qreg[u * 4 + 3];
            }
        }
        sum += __shfl_xor(sum, 1); sum += __shfl_xor(sum, 2); sum += __shfl_xor(sum, 4);
        if (grp == 0) {
            const float val = (s <= smax) ? sum * SCALE : NEG;
            sc[s] = val;
            csim[((size_t)h * T_LEN + t) * NJ + s] = val;
        }
    }
    __syncthreads();
    float lm = (tid < NJ) ? sc[tid] : -INFINITY;
#pragma unroll
    for (int off = 32; off; off >>= 1) lm = fmaxf(lm, __shfl_xor(lm, off));
    if (lane == 0) red[wave] = lm;
    __syncthreads();
    const float mx = fmaxf(fmaxf(red[0], red[1]), fmaxf(red[2], red[3]));
    __syncthreads();
    float e = 0.f;
    if (tid < NJ) { e = __expf(sc[tid] - mx); sc[tid] = e; }
#pragma unroll
    for (int off = 32; off; off >>= 1) e += __shfl_xor(e, off);
    if (lane == 0) red[wave] = e;
    __syncthreads();
    const float inv = 1.f / (red[0] + red[1] + red[2] + red[3]);
    // PV: 8 key-groups x 32 float4 d-slices
    const int g = tid >> 5, d4 = tid & 31;
    float4 a4 = make_float4(0.f, 0.f, 0.f, 0.f);
    for (int s = g; s < NJ; s += 8) {
        const float p = sc[s];
        const float4 vv = *(const float4*)(cv + ((size_t)h * NJ + s) * 128 + d4 * 4);
        a4.x += p * vv.x; a4.y += p * vv.y; a4.z += p * vv.z; a4.w += p * vv.w;
    }
    pv4[tid] = a4;
    __syncthreads();
    if (tid < 128) {
        const float* pf = (const float*)pv4;
        float o = 0.f;
#pragma unroll
        for (int g2 = 0; g2 < 8; ++g2) o += pf[g2 * 128 + tid];
        out[((size_t)h * T_LEN + t) * 128 + tid] = o * inv;
    }
}

__global__ void imp_kern(const float* __restrict__ csim, float* __restrict__ imp) {
    int idx = blockIdx.x * 256 + threadIdx.x;
    if (idx >= T_LEN * NBLK) return;
    const int w = idx & 127, t = idx >> 7;
    float s = 0.f;
    for (int h = 0; h < NHEAD; ++h)
        s += csim[((size_t)h * T_LEN + t) * NJ + 1 + w];
    imp[idx] = s * 0.125f;
}

__global__ void topk_kern(const float* __restrict__ imp, unsigned long long* __restrict__ selbits) {
    const int t = blockIdx.x * blockDim.x + threadIdx.x;
    if (t >= T_LEN) return;
    const float* row = imp + (size_t)t * NBLK;
    unsigned long long b0 = 0, b1 = 0;
    for (int s = 0; s < NSEL; ++s) {
        float best = -INFINITY; int bi = 0;
        for (int w = 0; w < NBLK; ++w) {
            const bool used = (w < 64) ? ((b0 >> w) & 1ull) : ((b1 >> (w - 64)) & 1ull);
            const float vv = row[w];
            if (!used && vv > best) { best = vv; bi = w; }
        }
        if (bi < 64) b0 |= 1ull << bi; else b1 |= 1ull << (bi - 64);
    }
    selbits[2 * t] = b0; selbits[2 * t + 1] = b1;
}

__global__ __launch_bounds__(256) void fine_att(const float* __restrict__ q,
                                                const float* __restrict__ k,
                                                const float* __restrict__ v,
                                                const unsigned long long* __restrict__ selbits,
                                                float* __restrict__ out) {
    const int t = blockIdx.x, h = blockIdx.y, tid = threadIdx.x;
    const int lane = tid & 63, wave = tid >> 6;
    __shared__ float qs[128];
    __shared__ float sc[17 * 16];
    __shared__ int blks[17];
    __shared__ int nb_s;
    __shared__ float red[4];
    __shared__ float4 pv4[256];
    if (tid < 128) qs[tid] = q[((size_t)h * T_LEN + t) * 128 + tid];
    if (tid == 0) {
        unsigned long long b0 = selbits[2 * t], b1 = selbits[2 * t + 1];
        const int cur = t >> 4;
        const bool curin = (cur < 64) ? ((b0 >> cur) & 1ull) : ((b1 >> (cur - 64)) & 1ull);
        int nb = 0;
        while (b0) { const int w = __ffsll(b0) - 1; b0 &= b0 - 1; blks[nb++] = w; }
        while (b1) { const int w = __ffsll(b1) - 1; b1 &= b1 - 1; blks[nb++] = w + 64; }
        if (!curin) blks[nb++] = cur;
        nb_s = nb;
    }
    __syncthreads();
    const int ns = nb_s * 16;
    const int grp = tid & 7, key0 = tid >> 3;
    float qreg[16];
#pragma unroll
    for (int u = 0; u < 4; ++u)
        *(float4*)&qreg[u * 4] = *(const float4*)&qs[grp * 16 + u * 4];
    for (int s = key0; s < ns; s += 32) {
        const int j = blks[s >> 4] * 16 + (s & 15);
        float sum = 0.f;
        if (j <= t) {
            const float* kr = k + ((size_t)h * T_LEN + j) * 128 + grp * 16;
#pragma unroll
            for (int u = 0; u < 4; ++u) {
                const float4 kv = *(const float4*)(kr + u * 4);
                sum += kv.x * qreg[u * 4] + kv.y * qreg[u * 4 + 1] +
                       kv.z * qreg[u * 4 + 2] + kv.w * qreg[u * 4 + 3];
            }
        }
        sum += __shfl_xor(sum, 1); sum += __shfl_xor(sum, 2); sum += __shfl_xor(sum, 4);
        if (grp == 0) sc[s] = (j <= t) ? sum * SCALE : -INFINITY;
    }
    __syncthreads();
    float lm = -INFINITY;
    for (int s = tid; s < ns; s += 256) lm = fmaxf(lm, sc[s]);
#pragma unroll
    for (int off = 32; off; off >>= 1) lm = fmaxf(lm, __shfl_xor(lm, off));
    if (lane == 0) red[wave] = lm;
    __syncthreads();
    const float mx = fmaxf(fmaxf(red[0], red[1]), fmaxf(red[2], red[3]));
    __syncthreads();
    float ls = 0.f;
    for (int s = tid; s < ns; s += 256) { const float e = __expf(sc[s] - mx); sc[s] = e; ls += e; }
#pragma unroll
    for (int off = 32; off; off >>= 1) ls += __shfl_xor(ls, off);
    if (lane == 0) red[wave] = ls;
    __syncthreads();
    const float inv = 1.f / (red[0] + red[1] + red[2] + red[3]);
    // PV: 8 key-groups x 32 float4 d-slices
    const int g = tid >> 5, d4 = tid & 31;
    float4 a4 = make_float4(0.f, 0.f, 0.f, 0.f);
    for (int s = g; s < ns; s += 8) {
        const int j = blks[s >> 4] * 16 + (s & 15);
        const float p = sc[s];
        const float4 vv = *(const float4*)(v + ((size_t)h * T_LEN + j) * 128 + d4 * 4);
        a4.x += p * vv.x; a4.y += p * vv.y; a4.z += p * vv.z; a4.w += p * vv.w;
    }
    pv4[tid] = a4;
    __syncthreads();
    if (tid < 128) {
        const float* pf = (const float*)pv4;
        float o = 0.f;
#pragma unroll
        for (int g2 = 0; g2 < 8; ++g2) o += pf[g2 * 128 + tid];
        out[((size_t)h * T_LEN + t) * 128 + tid] = o * inv;
    }
}

__global__ __launch_bounds__(256) void slide_att(const float* __restrict__ q,
                                                 const float* __restrict__ k,
                                                 const float* __restrict__ v,
                                                 float* __restrict__ out) {
    const int t = blockIdx.x, h = blockIdx.y, tid = threadIdx.x;
    const int lane = tid & 63, wave = tid >> 6;
    __shared__ float qs[128];
    __shared__ float sc[WIN];
    __shared__ float red[4];
    __shared__ float4 pv4[256];
    if (tid < 128) qs[tid] = q[((size_t)h * T_LEN + t) * 128 + tid];
    __syncthreads();
    const int j0 = max(0, t - (WIN - 1));
    const int ns = t - j0 + 1;
    const int grp = tid & 7, key0 = tid >> 3;
    float qreg[16];
#pragma unroll
    for (int u = 0; u < 4; ++u)
        *(float4*)&qreg[u * 4] = *(const float4*)&qs[grp * 16 + u * 4];
    for (int s = key0; s < ns; s += 32) {
        const float* kr = k + ((size_t)h * T_LEN + j0 + s) * 128 + grp * 16;
        float sum = 0.f;
#pragma unroll
        for (int u = 0; u < 4; ++u) {
            const float4 kv = *(const float4*)(kr + u * 4);
            sum += kv.x * qreg[u * 4] + kv.y * qreg[u * 4 + 1] +
                   kv.z * qreg[u * 4 + 2] + kv.w * qreg[u * 4 + 3];
        }
        sum += __shfl_xor(sum, 1); sum += __shfl_xor(sum, 2); sum += __shfl_xor(sum, 4);
        if (grp == 0) sc[s] = sum * SCALE;
    }
    __syncthreads();
    float lm = (tid < ns) ? sc[tid] : -INFINITY;
#pragma unroll
    for (int off = 32; off; off >>= 1) lm = fmaxf(lm, __shfl_xor(lm, off));
    if (lane == 0) red[wave] = lm;
    __syncthreads();
    const float mx = fmaxf(fmaxf(red[0], red[1]), fmaxf(red[2], red[3]));
    __syncthreads();
    float e = 0.f;
    if (tid < ns) { e = __expf(sc[tid] - mx); sc[tid] = e; }
#pragma unroll
    for (int off = 32; off; off >>= 1) e += __shfl_xor(e, off);
    if (lane == 0) red[wave] = e;
    __syncthreads();
    const float inv = 1.f / (red[0] + red[1] + red[2] + red[3]);
    // PV: 8 key-groups x 32 float4 d-slices
    const int g = tid >> 5, d4 = tid & 31;
    float4 a4 = make_float4(0.f, 0.f, 0.f, 0.f);
    for (int s = g; s < ns; s += 8) {
        const float p = sc[s];
        const float4 vv = *(const float4*)(v + ((size_t)h * T_LEN + j0 + s) * 128 + d4 * 4);
        a4.x += p * vv.x; a4.y += p * vv.y; a4.z += p * vv.z; a4.w += p * vv.w;
    }
    pv4[tid] = a4;
    __syncthreads();
    if (tid < 128) {
        const float* pf = (const float*)pv4;
        float o = 0.f;
#pragma unroll
        for (int g2 = 0; g2 < 8; ++g2) o += pf[g2 * 128 + tid];
        out[((size_t)h * T_LEN + t) * 128 + tid] = o * inv;
    }
}

__global__ __launch_bounds__(256) void strat_kern(const float* __restrict__ x,
                                                  const float* __restrict__ w,
                                                  const float* __restrict__ b,
                                                  float* __restrict__ strat) {
    const int t = blockIdx.x, tid = threadIdx.x;
    const int lane = tid & 63, wave = tid >> 6;
    __shared__ float xs[1024];
    for (int c = tid; c < 1024; c += 256) xs[c] = x[(size_t)t * 1024 + c];
    __syncthreads();
    for (int i = wave; i < 24; i += 4) {
        const float* wr = w + (size_t)i * 1024;
        float s = 0.f;
#pragma unroll
        for (int u = 0; u < 4; ++u) {
            const int c = u * 256 + lane * 4;
            const float4 wv = *reinterpret_cast<const float4*>(wr + c);
            const float4 xv = *reinterpret_cast<const float4*>(&xs[c]);
            s += wv.x * xv.x + wv.y * xv.y + wv.z * xv.z + wv.w * xv.w;
        }
#pragma unroll
        for (int off = 32; off; off >>= 1) s += __shfl_xor(s, off);
        if (lane == 0)
            strat[t * 24 + i] = 1.f / (1.f + __expf(-(s + b[i])));
    }
}

__global__ __launch_bounds__(256) void combine_kern(const float* __restrict__ strat,
                                                    const float* __restrict__ comp,
                                                    const float* __restrict__ fine,
                                                    const float* __restrict__ slide,
                                                    unsigned short* __restrict__ mixb) {
    const int t = blockIdx.x, tid = threadIdx.x;
    const int hh = tid >> 5, d0 = (tid & 31) * 4;
    const float* st = strat + t * 24 + hh * 3;
    const size_t idx = (((size_t)hh * T_LEN + t) * 128 + d0) / 4;
    const float4 c4 = ((const float4*)comp)[idx];
    const float4 f4 = ((const float4*)fine)[idx];
    const float4 s4 = ((const float4*)slide)[idx];
    ushort4 o;
    o.x = bfbits(st[0] * c4.x + st[1] * f4.x + st[2] * s4.x);
    o.y = bfbits(st[0] * c4.y + st[1] * f4.y + st[2] * s4.y);
    o.z = bfbits(st[0] * c4.z + st[1] * f4.z + st[2] * s4.z);
    o.w = bfbits(st[0] * c4.w + st[1] * f4.w + st[2] * s4.w);
    ((ushort4*)mixb)[(size_t)t * 256 + tid] = o;
}

extern "C" void kernel_launch(void* const* d_in, const int* in_sizes, int n_in,
                              void* d_out, int out_size, void* d_ws, size_t ws_size,
                              hipStream_t stream) {
    const float* x        = (const float*)d_in[0];
    const float* qkv_w    = (const float*)d_in[1];
    const float* lambdas  = (const float*)d_in[2];
    const float* c_proj_w = (const float*)d_in[3];
    const float* k_fc_w   = (const float*)d_in[4];
    const float* k_pj_w   = (const float*)d_in[5];
    const float* v_fc_w   = (const float*)d_in[6];
    const float* v_pj_w   = (const float*)d_in[7];
    const float* mem_kv   = (const float*)d_in[8];
    const float* k_pos    = (const float*)d_in[9];
    const float* v_pos    = (const float*)d_in[10];
    const float* strat_w  = (const float*)d_in[11];
    const float* strat_b  = (const float*)d_in[12];
    float* out = (float*)d_out;

    char* ws = (char*)d_ws;
    size_t off = 0;
    auto alloc = [&](size_t bytes) -> void* {
        void* p = ws + off;
        off += (bytes + 255) & ~(size_t)255;
        return p;
    };

    const size_t MB_HID = (size_t)1024 * 8192 * 2;      // 16.78 MB (bf16 hidden)
    const size_t MB_FCW = (size_t)8192 * 2048 * 2;      // 33.55 MB (bf16 fc weight)

    // region A (33.6 MB): buf_qkv f32 -> (hid_hi | hid_lo) -> (hidden_v | mixb)
    char* A = (char*)alloc(2 * MB_HID);
    float* buf_qkv = (float*)A;                               // 25.2 MB, dead after prep
    unsigned short* hid_hi = (unsigned short*)A;              // fc-k out, dead after pj-k
    unsigned short* hid_lo = (unsigned short*)(A + MB_HID);
    unsigned short* hidden_v = (unsigned short*)A;            // fc-v out
    unsigned short* mixb = (unsigned short*)(A + MB_HID);     // combine out

    // region B (67.1 MB): (kfcw_hi | kfcw_lo) -> (wfc_b | fine+slide+partials+wpj_b+wcp_b)
    char* B = (char*)alloc(2 * MB_FCW);
    unsigned short* kfcw_hi = (unsigned short*)B;             // dead after fc-k
    unsigned short* kfcw_lo = (unsigned short*)(B + MB_FCW);
    unsigned short* wfc_b = (unsigned short*)B;               // v_fc_w bf16 (after fc-k)
    char* B2 = B + MB_FCW;
    float* fine  = (float*)B2;                                // 8.39 MB
    float* slide = (float*)(B2 + 8388608);                    // 8.39 MB
    float* partials = (float*)(B2 + 2 * 8388608);             // 4.19 MB
    unsigned short* wpj_b = (unsigned short*)(B2 + 2 * 8388608 + 4194304);  // 2.1 MB
    unsigned short* wcp_b = (unsigned short*)(B2 + 2 * 8388608 + 4194304 + 2097152);

    // region D (21 MB): (x_hi|x_lo|qw_hi|qw_lo) -> (kpjw_hi|kpjw_lo)
    char* D = (char*)alloc((size_t)2048 * 1024 * 4 + (size_t)3072 * 1024 * 4);
    unsigned short* x_hi = (unsigned short*)D;                          // 4.19 MB
    unsigned short* x_lo = (unsigned short*)(D + 4194304);
    unsigned short* qw_hi = (unsigned short*)(D + 2 * 4194304);         // 6.29 MB
    unsigned short* qw_lo = (unsigned short*)(D + 2 * 4194304 + 6291456);
    unsigned short* kpjw_hi = (unsigned short*)D;             // after qkv
    unsigned short* kpjw_lo = (unsigned short*)(D + 2097152);

    // persistent
    float* q = (float*)alloc((size_t)NHEAD * T_LEN * 128 * 4);
    float* k = (float*)alloc((size_t)NHEAD * T_LEN * 128 * 4);
    float* v = (float*)alloc((size_t)NHEAD * T_LEN * 128 * 4);
    char* KC = (char*)alloc((size_t)1024 * 2048 * 4);         // kc pair; comp aliases after fc-k
    unsigned short* kc_hi = (unsigned short*)KC;
    unsigned short* kc_lo = (unsigned short*)(KC + 4194304);
    float* comp = (float*)KC;
    unsigned short* vc = (unsigned short*)alloc((size_t)1024 * 2048 * 2);
    float* csim = (float*)alloc((size_t)NHEAD * T_LEN * NJ * 4);
    float* imp  = (float*)alloc((size_t)T_LEN * NBLK * 4);
    float* strat = (float*)alloc((size_t)T_LEN * 24 * 4);
    float* ckb = (float*)alloc((size_t)1024 * 128 * 4);
    float* cvb = (float*)alloc((size_t)1024 * 128 * 4);
    float* ck  = (float*)alloc((size_t)NHEAD * NJ * 128 * 4);
    float* cv  = (float*)alloc((size_t)NHEAD * NJ * 128 * 4);
    unsigned long long* selbits = (unsigned long long*)alloc((size_t)T_LEN * 2 * 8);

    // 0. splits for qkv
    split_pair<<<2048, 256, 0, stream>>>(x, x_hi, x_lo, 2048 * 1024 / 4);
    split_pair<<<3072, 256, 0, stream>>>(qkv_w, qw_hi, qw_lo, 3072 * 1024 / 4);

    // 1. QKV projection (bf16x3 MFMA, ~fp32 accurate)
    gemm_mfma3<0, 0><<<dim3(3072 / 128, T_LEN / 128, 1), 256, 0, stream>>>(
        x_hi, x_lo, qw_hi, qw_lo, buf_qkv, nullptr, nullptr, T_LEN, 3072, 1024, 1024);

    // 2. rms + rotary + v-scale
    prep_qkv<<<dim3(T_LEN, NHEAD), 128, 0, stream>>>(buf_qkv, lambdas, q, k, v);

    // 3. k-branch weight splits (D region free after qkv; B region)
    split_pair<<<16384, 256, 0, stream>>>(k_fc_w, kfcw_hi, kfcw_lo, 8192 * 2048 / 4);
    split_pair<<<1024, 256, 0, stream>>>(k_pj_w, kpjw_hi, kpjw_lo, 128 * 8192 / 4);

    // 4. compress-MLP inputs (kc hi/lo, vc bf16)
    build_cin<<<(NHEAD * NBLK * BS * DHEAD / 4 + 255) / 256, 256, 0, stream>>>(
        k, v, k_pos, v_pos, kc_hi, kc_lo, vc);

    // 5. fc-k (bf16x3, relu^2, split-pair output)
    gemm_mfma3<1, 1><<<dim3(8192 / 128, 1024 / 128, 1), 256, 0, stream>>>(
        kc_hi, kc_lo, kfcw_hi, kfcw_lo, nullptr, hid_hi, hid_lo, 1024, 8192, 2048, 2048);

    // 6. pj-k (bf16x3, split-K=8) + reduce
    gemm_mfma3<0, 0><<<dim3(1, 1024 / 128, 8), 256, 0, stream>>>(
        hid_hi, hid_lo, kpjw_hi, kpjw_lo, partials, nullptr, nullptr, 1024, 128, 8192, 1024);
    reduce8<<<(1024 * 128 + 255) / 256, 256, 0, stream>>>(partials, ckb, 1024 * 128);

    // 7. v-branch weight casts (B region free after fc-k)
    cast_bf16<<<(8192 * 2048 / 4 + 255) / 256, 256, 0, stream>>>(v_fc_w, wfc_b, 8192 * 2048 / 4);
    cast_bf16<<<(128 * 8192 / 4 + 255) / 256, 256, 0, stream>>>(v_pj_w, wpj_b, 128 * 8192 / 4);
    cast_bf16<<<(1024 * 1024 / 4 + 255) / 256, 256, 0, stream>>>(c_proj_w, wcp_b, 1024 * 1024 / 4);

    // 8. v-branch MLP (plain bf16 MFMA)
    gemm_mfma<1, unsigned short><<<dim3(8192 / 128, 1024 / 128, 1), 256, 0, stream>>>(
        vc, wfc_b, hidden_v, 1024, 8192, 2048, 2048);
    gemm_mfma<0, float><<<dim3(1, 1024 / 128, 8), 256, 0, stream>>>(
        hidden_v, wpj_b, partials, 1024, 128, 8192, 1024);
    reduce8<<<(1024 * 128 + 255) / 256, 256, 0, stream>>>(partials, cvb, 1024 * 128);

    // 9. assemble ck/cv
    scatter_ckcv<<<(NHEAD * NJ * DHEAD + 255) / 256, 256, 0, stream>>>(
        ckb, cvb, mem_kv, ck, cv);

    // 10. fused compressed attention
    comp_att<<<dim3(T_LEN, NHEAD), 256, 0, stream>>>(q, ck, cv, csim, comp);

    // 11. importance + top-k
    imp_kern<<<(T_LEN * NBLK + 255) / 256, 256, 0, stream>>>(csim, imp);
    topk_kern<<<(T_LEN + 255) / 256, 256, 0, stream>>>(imp, selbits);

    // 12. fine + sliding attention
    fine_att<<<dim3(T_LEN, NHEAD), 256, 0, stream>>>(q, k, v, selbits, fine);
    slide_att<<<dim3(T_LEN, NHEAD), 256, 0, stream>>>(q, k, v, slide);

    // 13. strategy gates + combine
    strat_kern<<<T_LEN, 256, 0, stream>>>(x, strat_w, strat_b, strat);
    combine_kern<<<T_LEN, 256, 0, stream>>>(strat, comp, fine, slide, mixb);

    // 14. output projection (plain bf16 MFMA)
    gemm_mfma<0, float><<<dim3(1024 / 128, T_LEN / 128, 1), 256, 0, stream>>>(
        mixb, wcp_b, out, T_LEN, 1024, 1024, 1024);
}

// Round 12
// 920.473 us; speedup vs baseline: 5.2800x; 1.0889x over previous
//
// Round 12 resubmit of round-11 source (round-11 was GPUAcquisitionTimeout —
// no kernel signal; experiment not mutated).
// Round 11: bf16 K/V for attention score+PV paths (fine/slide kb,vb; comp
// cv_bf). Top-k chain untouched (ck, csim, q, kc-split all f32/bf16x3).
// Round-10 counters: fine_att 214us at 21.5 TB/s L2 (62% of ceiling),
// VALUBusy 49% -> byte-bound; halve the bytes.
#include <hip/hip_runtime.h>
#include <hip/hip_bf16.h>

#define T_LEN 2048
#define NHEAD 8
#define DHEAD 128
#define NBLK 128     // W
#define BS 16
#define NSEL 16
#define WIN 128
#define NMEM 1
#define NJ (NBLK + NMEM)   // 129
#define SCALE 0.12f
#define NEG -1e9f

typedef __attribute__((ext_vector_type(8))) short bf16x8;
typedef __attribute__((ext_vector_type(4))) float f32x4;

__device__ __forceinline__ unsigned short bfbits(float x) {
    __hip_bfloat16 h = __float2bfloat16(x);
    return *reinterpret_cast<unsigned short*>(&h);
}
__device__ __forceinline__ float bf2f(unsigned short h) {
    return __uint_as_float(((unsigned)h) << 16);
}
// unpack a packed pair of bf16 (low short = lower index)
__device__ __forceinline__ float2 bfpair(unsigned u) {
    return make_float2(__uint_as_float(u << 16), __uint_as_float(u & 0xffff0000u));
}
__device__ __forceinline__ void stc(float* p, float v) { *p = v; }
__device__ __forceinline__ void stc(unsigned short* p, float v) { *p = bfbits(v); }

// ---------------- f32 -> (hi, lo) bf16 split ----------------
__global__ void split_pair(const float* __restrict__ src, unsigned short* __restrict__ hi,
                           unsigned short* __restrict__ lo, int n4) {
    const int i = blockIdx.x * 256 + threadIdx.x;
    if (i >= n4) return;
    const float4 v = ((const float4*)src)[i];
    ushort4 H, L;
    H.x = bfbits(v.x); L.x = bfbits(v.x - bf2f(H.x));
    H.y = bfbits(v.y); L.y = bfbits(v.y - bf2f(H.y));
    H.z = bfbits(v.z); L.z = bfbits(v.z - bf2f(H.z));
    H.w = bfbits(v.w); L.w = bfbits(v.w - bf2f(H.w));
    ((ushort4*)hi)[i] = H;
    ((ushort4*)lo)[i] = L;
}

// ---------------- f32 -> bf16 cast ----------------
__global__ void cast_bf16(const float* __restrict__ src, unsigned short* __restrict__ dst, int n4) {
    const int i = blockIdx.x * 256 + threadIdx.x;
    if (i >= n4) return;
    const float4 v = ((const float4*)src)[i];
    ushort4 o;
    o.x = bfbits(v.x); o.y = bfbits(v.y); o.z = bfbits(v.z); o.w = bfbits(v.w);
    ((ushort4*)dst)[i] = o;
}

// ---------------- bf16x3 MFMA GEMM: C[m,n]=sum_k A[m,k]B[n,k], ~fp32 acc ----
template <int EPI, int OUTM>
__global__ __launch_bounds__(256) void gemm_mfma3(
    const unsigned short* __restrict__ Ah, const unsigned short* __restrict__ Al,
    const unsigned short* __restrict__ Bh, const unsigned short* __restrict__ Bl,
    float* __restrict__ C, unsigned short* __restrict__ Chi, unsigned short* __restrict__ Clo,
    int M, int N, int K, int KS) {
    __shared__ short Ash[128][40];
    __shared__ short Asl[128][40];
    __shared__ short Bsh[128][40];
    __shared__ short Bsl[128][40];
    const int bm = blockIdx.y * 128, bn = blockIdx.x * 128;
    const int k0 = blockIdx.z * KS;
    const int tid = threadIdx.x;
    const int lane = tid & 63, wave = tid >> 6;
    const int wm = (wave >> 1) * 64, wn = (wave & 1) * 64;
    const int l16 = lane & 15, lq = lane >> 4;
    f32x4 acc[4][4];
#pragma unroll
    for (int i = 0; i < 4; ++i)
#pragma unroll
        for (int j = 0; j < 4; ++j) acc[i][j] = (f32x4){0.f, 0.f, 0.f, 0.f};

    const int srow = tid >> 1;           // 0..127
    const int skq = (tid & 1) * 16;      // short offset 0 / 16
    for (int kt = k0; kt < k0 + KS; kt += 32) {
        __syncthreads();
        const size_t oa = (size_t)(bm + srow) * K + kt + skq;
        const size_t ob = (size_t)(bn + srow) * K + kt + skq;
        {
            const float4 t0 = *(const float4*)(Ah + oa);
            const float4 t1 = *(const float4*)(Ah + oa + 8);
            *(float4*)&Ash[srow][skq] = t0;
            *(float4*)&Ash[srow][skq + 8] = t1;
        }
        {
            const float4 t0 = *(const float4*)(Al + oa);
            const float4 t1 = *(const float4*)(Al + oa + 8);
            *(float4*)&Asl[srow][skq] = t0;
            *(float4*)&Asl[srow][skq + 8] = t1;
        }
        {
            const float4 t0 = *(const float4*)(Bh + ob);
            const float4 t1 = *(const float4*)(Bh + ob + 8);
            *(float4*)&Bsh[srow][skq] = t0;
            *(float4*)&Bsh[srow][skq + 8] = t1;
        }
        {
            const float4 t0 = *(const float4*)(Bl + ob);
            const float4 t1 = *(const float4*)(Bl + ob + 8);
            *(float4*)&Bsl[srow][skq] = t0;
            *(float4*)&Bsl[srow][skq + 8] = t1;
        }
        __syncthreads();
        bf16x8 afh[4], afl[4], bfh[4], bfl[4];
#pragma unroll
        for (int i = 0; i < 4; ++i) {
            afh[i] = *(bf16x8*)&Ash[wm + i * 16 + l16][lq * 8];
            afl[i] = *(bf16x8*)&Asl[wm + i * 16 + l16][lq * 8];
            bfh[i] = *(bf16x8*)&Bsh[wn + i * 16 + l16][lq * 8];
            bfl[i] = *(bf16x8*)&Bsl[wn + i * 16 + l16][lq * 8];
        }
#pragma unroll
        for (int i = 0; i < 4; ++i)
#pragma unroll
            for (int j = 0; j < 4; ++j) {
                acc[i][j] = __builtin_amdgcn_mfma_f32_16x16x32_bf16(afh[i], bfh[j], acc[i][j], 0, 0, 0);
                acc[i][j] = __builtin_amdgcn_mfma_f32_16x16x32_bf16(afh[i], bfl[j], acc[i][j], 0, 0, 0);
                acc[i][j] = __builtin_amdgcn_mfma_f32_16x16x32_bf16(afl[i], bfh[j], acc[i][j], 0, 0, 0);
            }
    }
#pragma unroll
    for (int i = 0; i < 4; ++i)
#pragma unroll
        for (int j = 0; j < 4; ++j)
#pragma unroll
            for (int r = 0; r < 4; ++r) {
                float vv = acc[i][j][r];
                if (EPI == 1) { vv = vv > 0.f ? vv : 0.f; vv = vv * vv; }
                const int row = bm + wm + i * 16 + lq * 4 + r;
                const int col = bn + wn + j * 16 + l16;
                if (OUTM == 0) {
                    (C + (size_t)blockIdx.z * M * N)[(size_t)row * N + col] = vv;
                } else {
                    const unsigned short h = bfbits(vv);
                    Chi[(size_t)row * N + col] = h;
                    Clo[(size_t)row * N + col] = bfbits(vv - bf2f(h));
                }
            }
}

// ---------------- plain bf16 MFMA GEMM (v-branch, c_proj) ----------------
template <int EPI, typename OUT_T>
__global__ __launch_bounds__(256) void gemm_mfma(const unsigned short* __restrict__ A,
                                                 const unsigned short* __restrict__ B,
                                                 OUT_T* __restrict__ C,
                                                 int M, int N, int K, int KS) {
    __shared__ short As[128][40];
    __shared__ short Bs[128][40];
    const int bm = blockIdx.y * 128, bn = blockIdx.x * 128;
    const int k0 = blockIdx.z * KS;
    const int tid = threadIdx.x;
    const int lane = tid & 63, wave = tid >> 6;
    const int wm = (wave >> 1) * 64, wn = (wave & 1) * 64;
    const int l16 = lane & 15, lq = lane >> 4;
    f32x4 acc[4][4];
#pragma unroll
    for (int i = 0; i < 4; ++i)
#pragma unroll
        for (int j = 0; j < 4; ++j) acc[i][j] = (f32x4){0.f, 0.f, 0.f, 0.f};

    const int srow = tid >> 1;
    const int skq = (tid & 1) * 16;
    for (int kt = k0; kt < k0 + KS; kt += 32) {
        __syncthreads();
        const unsigned short* ga = A + (size_t)(bm + srow) * K + kt + skq;
        const unsigned short* gb = B + (size_t)(bn + srow) * K + kt + skq;
        const float4 a0 = *(const float4*)ga;
        const float4 a1 = *(const float4*)(ga + 8);
        const float4 b0 = *(const float4*)gb;
        const float4 b1 = *(const float4*)(gb + 8);
        *(float4*)&As[srow][skq] = a0;
        *(float4*)&As[srow][skq + 8] = a1;
        *(float4*)&Bs[srow][skq] = b0;
        *(float4*)&Bs[srow][skq + 8] = b1;
        __syncthreads();
        bf16x8 af[4], bfr[4];
#pragma unroll
        for (int i = 0; i < 4; ++i) {
            af[i]  = *(bf16x8*)&As[wm + i * 16 + l16][lq * 8];
            bfr[i] = *(bf16x8*)&Bs[wn + i * 16 + l16][lq * 8];
        }
#pragma unroll
        for (int i = 0; i < 4; ++i)
#pragma unroll
            for (int j = 0; j < 4; ++j)
                acc[i][j] = __builtin_amdgcn_mfma_f32_16x16x32_bf16(af[i], bfr[j], acc[i][j], 0, 0, 0);
    }
    OUT_T* Cz = C + (size_t)blockIdx.z * M * N;
#pragma unroll
    for (int i = 0; i < 4; ++i)
#pragma unroll
        for (int j = 0; j < 4; ++j)
#pragma unroll
            for (int r = 0; r < 4; ++r) {
                float vv = acc[i][j][r];
                if (EPI == 1) { vv = vv > 0.f ? vv : 0.f; vv = vv * vv; }
                const int row = bm + wm + i * 16 + lq * 4 + r;
                const int col = bn + wn + j * 16 + l16;
                stc(&Cz[(size_t)row * N + col], vv);
            }
}

__global__ void reduce8(const float* __restrict__ P, float* __restrict__ C, int MN) {
    const int idx = blockIdx.x * 256 + threadIdx.x;
    if (idx >= MN) return;
    float s = 0.f;
#pragma unroll
    for (int z = 0; z < 8; ++z) s += P[(size_t)z * MN + idx];
    C[idx] = s;
}

// ------ per-(h,t): rms-norm q,k; rotary; v-scale; emit k f32 + kb,vb bf16 ----
__global__ __launch_bounds__(128) void prep_qkv(const float* __restrict__ qkvbuf,
                                                const float* __restrict__ lambdas,
                                                float* __restrict__ q, float* __restrict__ k,
                                                unsigned short* __restrict__ kb,
                                                unsigned short* __restrict__ vb) {
    const int t = blockIdx.x, h = blockIdx.y, d = threadIdx.x;
    const int lane = d & 63, wave = d >> 6;
    __shared__ float sq[128], sk[128];
    __shared__ float r2[4];
    const float* row = qkvbuf + (size_t)t * 3072 + h * 128;
    const float qv = row[d], kv = row[1024 + d], vv = row[2048 + d];

    float s2q = qv * qv, s2k = kv * kv;
#pragma unroll
    for (int off = 32; off; off >>= 1) {
        s2q += __shfl_xor(s2q, off);
        s2k += __shfl_xor(s2k, off);
    }
    if (lane == 0) { r2[wave] = s2q; r2[2 + wave] = s2k; }
    __syncthreads();
    const float qr = rsqrtf((r2[0] + r2[1]) / 128.f + 1e-6f);
    const float kr = rsqrtf((r2[2] + r2[3]) / 128.f + 1e-6f);
    sq[d] = qv * qr; sk[d] = kv * kr;
    __syncthreads();

    const int j = d & 63;
    const float ang = (j < 32) ? powf(1.0f / 1024.0f, (float)j / 31.0f) : 0.0f;
    const float th = ang * (float)t;
    const float c = cosf(th), s = sinf(th);
    float qo, ko;
    if (d < 64) { qo = sq[d] * c + sq[d + 64] * s; ko = sk[d] * c + sk[d + 64] * s; }
    else        { qo = -sq[d - 64] * s + sq[d] * c; ko = -sk[d - 64] * s + sk[d] * c; }

    const size_t idx = ((size_t)h * T_LEN + t) * 128 + d;
    q[idx] = qo;
    k[idx] = ko;
    kb[idx] = bfbits(ko);
    vb[idx] = bfbits(lambdas[0] * vv);
}

// ---------------- build compress-MLP inputs: kc (hi,lo) bf16, vc bf16 ------
__global__ void build_cin(const float* __restrict__ k, const unsigned short* __restrict__ vb,
                          const float* __restrict__ kpos, const float* __restrict__ vpos,
                          unsigned short* __restrict__ kc_hi, unsigned short* __restrict__ kc_lo,
                          unsigned short* __restrict__ vc) {
    const int idx = blockIdx.x * 256 + threadIdx.x;   // float4 index
    if (idx >= NHEAD * NBLK * BS * DHEAD / 4) return;
    const int d4 = idx & 31, i = (idx >> 5) & 15, w = (idx >> 9) & 127, h = idx >> 16;
    const int t = w * 16 + i;
    const size_t src = (((size_t)h * T_LEN + t) * 128 + d4 * 4) / 4;
    const int pos = ((h * 16 + i) * 128 + d4 * 4) / 4;
    const float4 kv = reinterpret_cast<const float4*>(k)[src];
    const ushort4 vvb = reinterpret_cast<const ushort4*>(vb)[src];
    const float4 kp = reinterpret_cast<const float4*>(kpos)[pos];
    const float4 vp = reinterpret_cast<const float4*>(vpos)[pos];
    const float kc0 = kv.x + kp.x, kc1 = kv.y + kp.y, kc2 = kv.z + kp.z, kc3 = kv.w + kp.w;
    ushort4 H, L;
    H.x = bfbits(kc0); L.x = bfbits(kc0 - bf2f(H.x));
    H.y = bfbits(kc1); L.y = bfbits(kc1 - bf2f(H.y));
    H.z = bfbits(kc2); L.z = bfbits(kc2 - bf2f(H.z));
    H.w = bfbits(kc3); L.w = bfbits(kc3 - bf2f(H.w));
    ((ushort4*)kc_hi)[idx] = H;
    ((ushort4*)kc_lo)[idx] = L;
    ushort4 o;
    o.x = bfbits(bf2f(vvb.x) + vp.x); o.y = bfbits(bf2f(vvb.y) + vp.y);
    o.z = bfbits(bf2f(vvb.z) + vp.z); o.w = bfbits(bf2f(vvb.w) + vp.w);
    ((ushort4*)vc)[idx] = o;
}

// ---------------- assemble ck (f32) / cv (bf16) with mem slot ----------------
__global__ void scatter_ckcv(const float* __restrict__ ckb, const float* __restrict__ cvb,
                             const float* __restrict__ memkv,
                             float* __restrict__ ck, unsigned short* __restrict__ cvbf) {
    int idx = blockIdx.x * 256 + threadIdx.x;
    if (idx >= NHEAD * NJ * DHEAD) return;
    const int d = idx & 127;
    const int j = (idx >> 7) % NJ;
    const int h = idx / (NJ * DHEAD);
    if (j == 0) {
        ck[idx] = memkv[h * 128 + d];
        cvbf[idx] = bfbits(memkv[NHEAD * 128 + h * 128 + d]);
    } else {
        const size_t b = ((size_t)h * NBLK + (j - 1)) * 128 + d;
        ck[idx] = ckb[b];
        cvbf[idx] = bfbits(cvb[b]);
    }
}

// ============ attention: direct-global scores, bf16 K/V, float4 PV ============

__global__ __launch_bounds__(256) void comp_att(const float* __restrict__ q,
                                                const float* __restrict__ ck,
                                                const unsigned short* __restrict__ cvbf,
                                                float* __restrict__ csim,
                                                float* __restrict__ out) {
    const int t = blockIdx.x, h = blockIdx.y, tid = threadIdx.x;
    const int lane = tid & 63, wave = tid >> 6;
    __shared__ float qs[128];
    __shared__ float sc[NJ];
    __shared__ float red[4];
    __shared__ float4 pv4[256];
    if (tid < 128) qs[tid] = q[((size_t)h * T_LEN + t) * 128 + tid];
    __syncthreads();
    const int grp = tid & 7, key0 = tid >> 3;   // 32 key-threads x 8
    float qreg[16];
#pragma unroll
    for (int u = 0; u < 4; ++u)
        *(float4*)&qreg[u * 4] = *(const float4*)&qs[grp * 16 + u * 4];
    const int smax = t >> 4;
    for (int s = key0; s < NJ; s += 32) {
        float sum = 0.f;
        if (s <= smax) {
            const float* kr = ck + ((size_t)h * NJ + s) * 128 + grp * 16;
#pragma unroll
            for (int u = 0; u < 4; ++u) {
                const float4 kv = *(const float4*)(kr + u * 4);
                sum += kv.x * qreg[u * 4] + kv.y * qreg[u * 4 + 1] +
                       kv.z * qreg[u * 4 + 2] + kv.w * qreg[u * 4 + 3];
            }
        }
        sum += __shfl_xor(sum, 1); sum += __shfl_xor(sum, 2); sum += __shfl_xor(sum, 4);
        if (grp == 0) {
            const float val = (s <= smax) ? sum * SCALE : NEG;
            sc[s] = val;
            csim[((size_t)h * T_LEN + t) * NJ + s] = val;
        }
    }
    __syncthreads();
    float lm = (tid < NJ) ? sc[tid] : -INFINITY;
#pragma unroll
    for (int off = 32; off; off >>= 1) lm = fmaxf(lm, __shfl_xor(lm, off));
    if (lane == 0) red[wave] = lm;
    __syncthreads();
    const float mx = fmaxf(fmaxf(red[0], red[1]), fmaxf(red[2], red[3]));
    __syncthreads();
    float e = 0.f;
    if (tid < NJ) { e = __expf(sc[tid] - mx); sc[tid] = e; }
#pragma unroll
    for (int off = 32; off; off >>= 1) e += __shfl_xor(e, off);
    if (lane == 0) red[wave] = e;
    __syncthreads();
    const float inv = 1.f / (red[0] + red[1] + red[2] + red[3]);
    // PV: 8 key-groups x 32 d-slices, bf16 V
    const int g = tid >> 5, d4 = tid & 31;
    float4 a4 = make_float4(0.f, 0.f, 0.f, 0.f);
    for (int s = g; s < NJ; s += 8) {
        const float p = sc[s];
        const ushort4 vv = *(const ushort4*)(cvbf + ((size_t)h * NJ + s) * 128 + d4 * 4);
        a4.x += p * bf2f(vv.x); a4.y += p * bf2f(vv.y);
        a4.z += p * bf2f(vv.z); a4.w += p * bf2f(vv.w);
    }
    pv4[tid] = a4;
    __syncthreads();
    if (tid < 128) {
        const float* pf = (const float*)pv4;
        float o = 0.f;
#pragma unroll
        for (int g2 = 0; g2 < 8; ++g2) o += pf[g2 * 128 + tid];
        out[((size_t)h * T_LEN + t) * 128 + tid] = o * inv;
    }
}

__global__ void imp_kern(const float* __restrict__ csim, float* __restrict__ imp) {
    int idx = blockIdx.x * 256 + threadIdx.x;
    if (idx >= T_LEN * NBLK) return;
    const int w = idx & 127, t = idx >> 7;
    float s = 0.f;
    for (int h = 0; h < NHEAD; ++h)
        s += csim[((size_t)h * T_LEN + t) * NJ + 1 + w];
    imp[idx] = s * 0.125f;
}

__global__ void topk_kern(const float* __restrict__ imp, unsigned long long* __restrict__ selbits) {
    const int t = blockIdx.x * blockDim.x + threadIdx.x;
    if (t >= T_LEN) return;
    const float* row = imp + (size_t)t * NBLK;
    unsigned long long b0 = 0, b1 = 0;
    for (int s = 0; s < NSEL; ++s) {
        float best = -INFINITY; int bi = 0;
        for (int w = 0; w < NBLK; ++w) {
            const bool used = (w < 64) ? ((b0 >> w) & 1ull) : ((b1 >> (w - 64)) & 1ull);
            const float vv = row[w];
            if (!used && vv > best) { best = vv; bi = w; }
        }
        if (bi < 64) b0 |= 1ull << bi; else b1 |= 1ull << (bi - 64);
    }
    selbits[2 * t] = b0; selbits[2 * t + 1] = b1;
}

__global__ __launch_bounds__(256) void fine_att(const float* __restrict__ q,
                                                const unsigned short* __restrict__ kb,
                                                const unsigned short* __restrict__ vb,
                                                const unsigned long long* __restrict__ selbits,
                                                float* __restrict__ out) {
    const int t = blockIdx.x, h = blockIdx.y, tid = threadIdx.x;
    const int lane = tid & 63, wave = tid >> 6;
    __shared__ float qs[128];
    __shared__ float sc[17 * 16];
    __shared__ int blks[17];
    __shared__ int nb_s;
    __shared__ float red[4];
    __shared__ float4 pv4[256];
    if (tid < 128) qs[tid] = q[((size_t)h * T_LEN + t) * 128 + tid];
    if (tid == 0) {
        unsigned long long b0 = selbits[2 * t], b1 = selbits[2 * t + 1];
        const int cur = t >> 4;
        const bool curin = (cur < 64) ? ((b0 >> cur) & 1ull) : ((b1 >> (cur - 64)) & 1ull);
        int nb = 0;
        while (b0) { const int w = __ffsll(b0) - 1; b0 &= b0 - 1; blks[nb++] = w; }
        while (b1) { const int w = __ffsll(b1) - 1; b1 &= b1 - 1; blks[nb++] = w + 64; }
        if (!curin) blks[nb++] = cur;
        nb_s = nb;
    }
    __syncthreads();
    const int ns = nb_s * 16;
    const int grp = tid & 7, key0 = tid >> 3;
    float qreg[16];
#pragma unroll
    for (int u = 0; u < 4; ++u)
        *(float4*)&qreg[u * 4] = *(const float4*)&qs[grp * 16 + u * 4];
    for (int s = key0; s < ns; s += 32) {
        const int j = blks[s >> 4] * 16 + (s & 15);
        float sum = 0.f;
        if (j <= t) {
            const unsigned* kr = (const unsigned*)(kb + ((size_t)h * T_LEN + j) * 128 + grp * 16);
            const uint4 p0 = *(const uint4*)kr;
            const uint4 p1 = *(const uint4*)(kr + 4);
            const unsigned uu[8] = {p0.x, p0.y, p0.z, p0.w, p1.x, p1.y, p1.z, p1.w};
#pragma unroll
            for (int u = 0; u < 8; ++u) {
                const float2 kf = bfpair(uu[u]);
                sum += kf.x * qreg[u * 2] + kf.y * qreg[u * 2 + 1];
            }
        }
        sum += __shfl_xor(sum, 1); sum += __shfl_xor(sum, 2); sum += __shfl_xor(sum, 4);
        if (grp == 0) sc[s] = (j <= t) ? sum * SCALE : -INFINITY;
    }
    __syncthreads();
    float lm = -INFINITY;
    for (int s = tid; s < ns; s += 256) lm = fmaxf(lm, sc[s]);
#pragma unroll
    for (int off = 32; off; off >>= 1) lm = fmaxf(lm, __shfl_xor(lm, off));
    if (lane == 0) red[wave] = lm;
    __syncthreads();
    const float mx = fmaxf(fmaxf(red[0], red[1]), fmaxf(red[2], red[3]));
    __syncthreads();
    float ls = 0.f;
    for (int s = tid; s < ns; s += 256) { const float e = __expf(sc[s] - mx); sc[s] = e; ls += e; }
#pragma unroll
    for (int off = 32; off; off >>= 1) ls += __shfl_xor(ls, off);
    if (lane == 0) red[wave] = ls;
    __syncthreads();
    const float inv = 1.f / (red[0] + red[1] + red[2] + red[3]);
    // PV: 8 key-groups x 32 d-slices, bf16 V
    const int g = tid >> 5, d4 = tid & 31;
    float4 a4 = make_float4(0.f, 0.f, 0.f, 0.f);
    for (int s = g; s < ns; s += 8) {
        const int j = blks[s >> 4] * 16 + (s & 15);
        const float p = sc[s];
        const ushort4 vv = *(const ushort4*)(vb + ((size_t)h * T_LEN + j) * 128 + d4 * 4);
        a4.x += p * bf2f(vv.x); a4.y += p * bf2f(vv.y);
        a4.z += p * bf2f(vv.z); a4.w += p * bf2f(vv.w);
    }
    pv4[tid] = a4;
    __syncthreads();
    if (tid < 128) {
        const float* pf = (const float*)pv4;
        float o = 0.f;
#pragma unroll
        for (int g2 = 0; g2 < 8; ++g2) o += pf[g2 * 128 + tid];
        out[((size_t)h * T_LEN + t) * 128 + tid] = o * inv;
    }
}

__global__ __launch_bounds__(256) void slide_att(const float* __restrict__ q,
                                                 const unsigned short* __restrict__ kb,
                                                 const unsigned short* __restrict__ vb,
                                                 float* __restrict__ out) {
    const int t = blockIdx.x, h = blockIdx.y, tid = threadIdx.x;
    const int lane = tid & 63, wave = tid >> 6;
    __shared__ float qs[128];
    __shared__ float sc[WIN];
    __shared__ float red[4];
    __shared__ float4 pv4[256];
    if (tid < 128) qs[tid] = q[((size_t)h * T_LEN + t) * 128 + tid];
    __syncthreads();
    const int j0 = max(0, t - (WIN - 1));
    const int ns = t - j0 + 1;
    const int grp = tid & 7, key0 = tid >> 3;
    float qreg[16];
#pragma unroll
    for (int u = 0; u < 4; ++u)
        *(float4*)&qreg[u * 4] = *(const float4*)&qs[grp * 16 + u * 4];
    for (int s = key0; s < ns; s += 32) {
        const unsigned* kr = (const unsigned*)(kb + ((size_t)h * T_LEN + j0 + s) * 128 + grp * 16);
        const uint4 p0 = *(const uint4*)kr;
        const uint4 p1 = *(const uint4*)(kr + 4);
        const unsigned uu[8] = {p0.x, p0.y, p0.z, p0.w, p1.x, p1.y, p1.z, p1.w};
        float sum = 0.f;
#pragma unroll
        for (int u = 0; u < 8; ++u) {
            const float2 kf = bfpair(uu[u]);
            sum += kf.x * qreg[u * 2] + kf.y * qreg[u * 2 + 1];
        }
        sum += __shfl_xor(sum, 1); sum += __shfl_xor(sum, 2); sum += __shfl_xor(sum, 4);
        if (grp == 0) sc[s] = sum * SCALE;
    }
    __syncthreads();
    float lm = (tid < ns) ? sc[tid] : -INFINITY;
#pragma unroll
    for (int off = 32; off; off >>= 1) lm = fmaxf(lm, __shfl_xor(lm, off));
    if (lane == 0) red[wave] = lm;
    __syncthreads();
    const float mx = fmaxf(fmaxf(red[0], red[1]), fmaxf(red[2], red[3]));
    __syncthreads();
    float e = 0.f;
    if (tid < ns) { e = __expf(sc[tid] - mx); sc[tid] = e; }
#pragma unroll
    for (int off = 32; off; off >>= 1) e += __shfl_xor(e, off);
    if (lane == 0) red[wave] = e;
    __syncthreads();
    const float inv = 1.f / (red[0] + red[1] + red[2] + red[3]);
    const int g = tid >> 5, d4 = tid & 31;
    float4 a4 = make_float4(0.f, 0.f, 0.f, 0.f);
    for (int s = g; s < ns; s += 8) {
        const float p = sc[s];
        const ushort4 vv = *(const ushort4*)(vb + ((size_t)h * T_LEN + j0 + s) * 128 + d4 * 4);
        a4.x += p * bf2f(vv.x); a4.y += p * bf2f(vv.y);
        a4.z += p * bf2f(vv.z); a4.w += p * bf2f(vv.w);
    }
    pv4[tid] = a4;
    __syncthreads();
    if (tid < 128) {
        const float* pf = (const float*)pv4;
        float o = 0.f;
#pragma unroll
        for (int g2 = 0; g2 < 8; ++g2) o += pf[g2 * 128 + tid];
        out[((size_t)h * T_LEN + t) * 128 + tid] = o * inv;
    }
}

__global__ __launch_bounds__(256) void strat_kern(const float* __restrict__ x,
                                                  const float* __restrict__ w,
                                                  const float* __restrict__ b,
                                                  float* __restrict__ strat) {
    const int t = blockIdx.x, tid = threadIdx.x;
    const int lane = tid & 63, wave = tid >> 6;
    __shared__ float xs[1024];
    for (int c = tid; c < 1024; c += 256) xs[c] = x[(size_t)t * 1024 + c];
    __syncthreads();
    for (int i = wave; i < 24; i += 4) {
        const float* wr = w + (size_t)i * 1024;
        float s = 0.f;
#pragma unroll
        for (int u = 0; u < 4; ++u) {
            const int c = u * 256 + lane * 4;
            const float4 wv = *reinterpret_cast<const float4*>(wr + c);
            const float4 xv = *reinterpret_cast<const float4*>(&xs[c]);
            s += wv.x * xv.x + wv.y * xv.y + wv.z * xv.z + wv.w * xv.w;
        }
#pragma unroll
        for (int off = 32; off; off >>= 1) s += __shfl_xor(s, off);
        if (lane == 0)
            strat[t * 24 + i] = 1.f / (1.f + __expf(-(s + b[i])));
    }
}

__global__ __launch_bounds__(256) void combine_kern(const float* __restrict__ strat,
                                                    const float* __restrict__ comp,
                                                    const float* __restrict__ fine,
                                                    const float* __restrict__ slide,
                                                    unsigned short* __restrict__ mixb) {
    const int t = blockIdx.x, tid = threadIdx.x;
    const int hh = tid >> 5, d0 = (tid & 31) * 4;
    const float* st = strat + t * 24 + hh * 3;
    const size_t idx = (((size_t)hh * T_LEN + t) * 128 + d0) / 4;
    const float4 c4 = ((const float4*)comp)[idx];
    const float4 f4 = ((const float4*)fine)[idx];
    const float4 s4 = ((const float4*)slide)[idx];
    ushort4 o;
    o.x = bfbits(st[0] * c4.x + st[1] * f4.x + st[2] * s4.x);
    o.y = bfbits(st[0] * c4.y + st[1] * f4.y + st[2] * s4.y);
    o.z = bfbits(st[0] * c4.z + st[1] * f4.z + st[2] * s4.z);
    o.w = bfbits(st[0] * c4.w + st[1] * f4.w + st[2] * s4.w);
    ((ushort4*)mixb)[(size_t)t * 256 + tid] = o;
}

extern "C" void kernel_launch(void* const* d_in, const int* in_sizes, int n_in,
                              void* d_out, int out_size, void* d_ws, size_t ws_size,
                              hipStream_t stream) {
    const float* x        = (const float*)d_in[0];
    const float* qkv_w    = (const float*)d_in[1];
    const float* lambdas  = (const float*)d_in[2];
    const float* c_proj_w = (const float*)d_in[3];
    const float* k_fc_w   = (const float*)d_in[4];
    const float* k_pj_w   = (const float*)d_in[5];
    const float* v_fc_w   = (const float*)d_in[6];
    const float* v_pj_w   = (const float*)d_in[7];
    const float* mem_kv   = (const float*)d_in[8];
    const float* k_pos    = (const float*)d_in[9];
    const float* v_pos    = (const float*)d_in[10];
    const float* strat_w  = (const float*)d_in[11];
    const float* strat_b  = (const float*)d_in[12];
    float* out = (float*)d_out;

    char* ws = (char*)d_ws;
    size_t off = 0;
    auto alloc = [&](size_t bytes) -> void* {
        void* p = ws + off;
        off += (bytes + 255) & ~(size_t)255;
        return p;
    };

    const size_t MB_HID = (size_t)1024 * 8192 * 2;      // 16.78 MB (bf16 hidden)
    const size_t MB_FCW = (size_t)8192 * 2048 * 2;      // 33.55 MB (bf16 fc weight)

    // region A (33.6 MB): buf_qkv f32 -> (hid_hi | hid_lo) -> (hidden_v | mixb)
    char* A = (char*)alloc(2 * MB_HID);
    float* buf_qkv = (float*)A;                               // 25.2 MB, dead after prep
    unsigned short* hid_hi = (unsigned short*)A;              // fc-k out, dead after pj-k
    unsigned short* hid_lo = (unsigned short*)(A + MB_HID);
    unsigned short* hidden_v = (unsigned short*)A;            // fc-v out
    unsigned short* mixb = (unsigned short*)(A + MB_HID);     // combine out

    // region B (67.1 MB): (kfcw_hi | kfcw_lo) -> (wfc_b | fine+slide+partials+wpj_b+wcp_b)
    char* B = (char*)alloc(2 * MB_FCW);
    unsigned short* kfcw_hi = (unsigned short*)B;             // dead after fc-k
    unsigned short* kfcw_lo = (unsigned short*)(B + MB_FCW);
    unsigned short* wfc_b = (unsigned short*)B;               // v_fc_w bf16 (after fc-k)
    char* B2 = B + MB_FCW;
    float* fine  = (float*)B2;                                // 8.39 MB
    float* slide = (float*)(B2 + 8388608);                    // 8.39 MB
    float* partials = (float*)(B2 + 2 * 8388608);             // 4.19 MB
    unsigned short* wpj_b = (unsigned short*)(B2 + 2 * 8388608 + 4194304);  // 2.1 MB
    unsigned short* wcp_b = (unsigned short*)(B2 + 2 * 8388608 + 4194304 + 2097152);

    // region D (21 MB): (x_hi|x_lo|qw_hi|qw_lo) -> (kpjw_hi|kpjw_lo)
    char* D = (char*)alloc((size_t)2048 * 1024 * 4 + (size_t)3072 * 1024 * 4);
    unsigned short* x_hi = (unsigned short*)D;                          // 4.19 MB
    unsigned short* x_lo = (unsigned short*)(D + 4194304);
    unsigned short* qw_hi = (unsigned short*)(D + 2 * 4194304);         // 6.29 MB
    unsigned short* qw_lo = (unsigned short*)(D + 2 * 4194304 + 6291456);
    unsigned short* kpjw_hi = (unsigned short*)D;             // after qkv
    unsigned short* kpjw_lo = (unsigned short*)(D + 2097152);

    // persistent
    float* q = (float*)alloc((size_t)NHEAD * T_LEN * 128 * 4);
    float* k = (float*)alloc((size_t)NHEAD * T_LEN * 128 * 4);
    unsigned short* kb = (unsigned short*)alloc((size_t)NHEAD * T_LEN * 128 * 2);
    unsigned short* vb = (unsigned short*)alloc((size_t)NHEAD * T_LEN * 128 * 2);
    char* KC = (char*)alloc((size_t)1024 * 2048 * 4);         // kc pair; comp aliases after fc-k
    unsigned short* kc_hi = (unsigned short*)KC;
    unsigned short* kc_lo = (unsigned short*)(KC + 4194304);
    float* comp = (float*)KC;
    unsigned short* vc = (unsigned short*)alloc((size_t)1024 * 2048 * 2);
    float* csim = (float*)alloc((size_t)NHEAD * T_LEN * NJ * 4);
    float* imp  = (float*)alloc((size_t)T_LEN * NBLK * 4);
    float* strat = (float*)alloc((size_t)T_LEN * 24 * 4);
    float* ckb = (float*)alloc((size_t)1024 * 128 * 4);
    float* cvb = (float*)alloc((size_t)1024 * 128 * 4);
    float* ck  = (float*)alloc((size_t)NHEAD * NJ * 128 * 4);
    unsigned short* cv_bf = (unsigned short*)alloc((size_t)NHEAD * NJ * 128 * 2);
    unsigned long long* selbits = (unsigned long long*)alloc((size_t)T_LEN * 2 * 8);

    // 0. splits for qkv
    split_pair<<<2048, 256, 0, stream>>>(x, x_hi, x_lo, 2048 * 1024 / 4);
    split_pair<<<3072, 256, 0, stream>>>(qkv_w, qw_hi, qw_lo, 3072 * 1024 / 4);

    // 1. QKV projection (bf16x3 MFMA, ~fp32 accurate)
    gemm_mfma3<0, 0><<<dim3(3072 / 128, T_LEN / 128, 1), 256, 0, stream>>>(
        x_hi, x_lo, qw_hi, qw_lo, buf_qkv, nullptr, nullptr, T_LEN, 3072, 1024, 1024);

    // 2. rms + rotary + v-scale -> q,k f32 + kb,vb bf16
    prep_qkv<<<dim3(T_LEN, NHEAD), 128, 0, stream>>>(buf_qkv, lambdas, q, k, kb, vb);

    // 3. k-branch weight splits (D region free after qkv; B region)
    split_pair<<<16384, 256, 0, stream>>>(k_fc_w, kfcw_hi, kfcw_lo, 8192 * 2048 / 4);
    split_pair<<<1024, 256, 0, stream>>>(k_pj_w, kpjw_hi, kpjw_lo, 128 * 8192 / 4);

    // 4. compress-MLP inputs (kc hi/lo from f32 k, vc from bf16 vb)
    build_cin<<<(NHEAD * NBLK * BS * DHEAD / 4 + 255) / 256, 256, 0, stream>>>(
        k, vb, k_pos, v_pos, kc_hi, kc_lo, vc);

    // 5. fc-k (bf16x3, relu^2, split-pair output)
    gemm_mfma3<1, 1><<<dim3(8192 / 128, 1024 / 128, 1), 256, 0, stream>>>(
        kc_hi, kc_lo, kfcw_hi, kfcw_lo, nullptr, hid_hi, hid_lo, 1024, 8192, 2048, 2048);

    // 6. pj-k (bf16x3, split-K=8) + reduce
    gemm_mfma3<0, 0><<<dim3(1, 1024 / 128, 8), 256, 0, stream>>>(
        hid_hi, hid_lo, kpjw_hi, kpjw_lo, partials, nullptr, nullptr, 1024, 128, 8192, 1024);
    reduce8<<<(1024 * 128 + 255) / 256, 256, 0, stream>>>(partials, ckb, 1024 * 128);

    // 7. v-branch weight casts (B region free after fc-k)
    cast_bf16<<<(8192 * 2048 / 4 + 255) / 256, 256, 0, stream>>>(v_fc_w, wfc_b, 8192 * 2048 / 4);
    cast_bf16<<<(128 * 8192 / 4 + 255) / 256, 256, 0, stream>>>(v_pj_w, wpj_b, 128 * 8192 / 4);
    cast_bf16<<<(1024 * 1024 / 4 + 255) / 256, 256, 0, stream>>>(c_proj_w, wcp_b, 1024 * 1024 / 4);

    // 8. v-branch MLP (plain bf16 MFMA)
    gemm_mfma<1, unsigned short><<<dim3(8192 / 128, 1024 / 128, 1), 256, 0, stream>>>(
        vc, wfc_b, hidden_v, 1024, 8192, 2048, 2048);
    gemm_mfma<0, float><<<dim3(1, 1024 / 128, 8), 256, 0, stream>>>(
        hidden_v, wpj_b, partials, 1024, 128, 8192, 1024);
    reduce8<<<(1024 * 128 + 255) / 256, 256, 0, stream>>>(partials, cvb, 1024 * 128);

    // 9. assemble ck (f32) / cv (bf16)
    scatter_ckcv<<<(NHEAD * NJ * DHEAD + 255) / 256, 256, 0, stream>>>(
        ckb, cvb, mem_kv, ck, cv_bf);

    // 10. fused compressed attention
    comp_att<<<dim3(T_LEN, NHEAD), 256, 0, stream>>>(q, ck, cv_bf, csim, comp);

    // 11. importance + top-k
    imp_kern<<<(T_LEN * NBLK + 255) / 256, 256, 0, stream>>>(csim, imp);
    topk_kern<<<(T_LEN + 255) / 256, 256, 0, stream>>>(imp, selbits);

    // 12. fine + sliding attention (bf16 K/V)
    fine_att<<<dim3(T_LEN, NHEAD), 256, 0, stream>>>(q, kb, vb, selbits, fine);
    slide_att<<<dim3(T_LEN, NHEAD), 256, 0, stream>>>(q, kb, vb, slide);

    // 13. strategy gates + combine
    strat_kern<<<T_LEN, 256, 0, stream>>>(x, strat_w, strat_b, strat);
    combine_kern<<<T_LEN, 256, 0, stream>>>(strat, comp, fine, slide, mixb);

    // 14. output projection (plain bf16 MFMA)
    gemm_mfma<0, float><<<dim3(1024 / 128, T_LEN / 128, 1), 256, 0, stream>>>(
        mixb, wcp_b, out, T_LEN, 1024, 1024, 1024);
}